// Round 2
// baseline (4551.487 us; speedup 1.0000x reference)
//
#include <hip/hip_runtime.h>
#include <hip/hip_bf16.h>

#define TPB 256

constexpr int Bx = 8, Cc = 64, Nn = 207, Tin = 54, Kb = 8;
constexpr int LP = 52, NP = Nn * LP;     // time padded 50->52, flattened node*time positions
constexpr int L50 = 50, Tout = 48;
constexpr int Ee = 512, Pn = 12;
constexpr float EPSF = 1e-5f;

// ---------------- workspace layout (floats) ----------------
constexpr size_t O_RESID = 0;                                   // [B][64][207][54]
constexpr size_t O_LNTM  = O_RESID + (size_t)Bx*Cc*Nn*Tin;
constexpr size_t O_LNTR  = O_LNTM  + (size_t)Bx*Cc*Nn;
constexpr size_t O_LNSM  = O_LNTR  + (size_t)Bx*Cc*Nn;
constexpr size_t O_LNSR  = O_LNSM  + (size_t)Bx*Cc*Tin;
constexpr size_t O_XCAT  = O_LNSR  + (size_t)Bx*Cc*Tin;         // [B][192][207][54]; later reused as RA [B][128][NP]
constexpr size_t O_RB    = O_XCAT  + (size_t)Bx*192*Nn*Tin;     // [B][128][NP]
constexpr size_t O_H     = O_RB    + (size_t)Bx*128*NP;         // [B][64][NP]
constexpr size_t O_GACC  = O_H     + (size_t)Bx*64*NP;          // [B][128][207][48]
constexpr size_t O_GG    = O_GACC  + (size_t)Bx*128*Nn*Tout;    // [B][64][207][48]; later reused as Y
constexpr size_t O_XE    = O_GG    + (size_t)Bx*64*Nn*Tout;     // [B][207][12][512]
constexpr size_t O_WTT   = O_XE    + (size_t)Bx*Nn*Pn*Ee;       // transposed W_time 128*192*3
constexpr size_t O_WTM   = O_WTT   + (size_t)128*192*3;         // transposed W_mlp 128*384*3
constexpr size_t O_BNST  = O_WTM   + (size_t)128*384*3;         // 128

#define FMA4(acc, sA_, vB_) { (acc).x += (sA_)*(vB_).x; (acc).y += (sA_)*(vB_).y; (acc).z += (sA_)*(vB_).z; (acc).w += (sA_)*(vB_).w; }

__device__ __forceinline__ float sigm(float x){ return 1.0f/(1.0f+__expf(-x)); }

// ---------------- residual = W_conv1 @ x + b ----------------
__global__ __launch_bounds__(TPB) void k_residual(const float* __restrict__ x, const float* __restrict__ W,
                                                  const float* __restrict__ bias, float* __restrict__ out){
  int n = blockIdx.x, b = blockIdx.y;
  __shared__ __align__(16) float sX[Cc][Tin];
  __shared__ __align__(16) float sW[Cc*Cc];
  int tid = threadIdx.x;
  for(int i=tid;i<Cc*Tin;i+=TPB){ int c=i/Tin, l=i%Tin; sX[c][l] = x[((size_t)(b*Cc+c)*Nn+n)*Tin+l]; }
  for(int i=tid;i<Cc*Cc;i+=TPB) sW[i]=W[i];
  __syncthreads();
  for(int i=tid;i<Cc*Tin;i+=TPB){
    int o=i/Tin, l=i%Tin; float acc=bias[o];
    #pragma unroll 8
    for(int c=0;c<Cc;c++) acc += sW[o*Cc+c]*sX[c][l];
    out[((size_t)(b*Cc+o)*Nn+n)*Tin+l]=acc;
  }
}

// ---------------- LN stats ----------------
__global__ __launch_bounds__(TPB) void k_lnT(const float* __restrict__ r, float* __restrict__ mean, float* __restrict__ rstd){
  int row = blockIdx.x*TPB + threadIdx.x;
  if(row >= Bx*Cc*Nn) return;
  const float* p = r + (size_t)row*Tin;
  float s=0.f,s2=0.f;
  for(int l=0;l<Tin;l++){ float v=p[l]; s+=v; s2+=v*v; }
  float m=s*(1.f/Tin); float var=s2*(1.f/Tin)-m*m;
  mean[row]=m; rstd[row]=rsqrtf(fmaxf(var,0.f)+EPSF);
}
__global__ __launch_bounds__(TPB) void k_lnS(const float* __restrict__ r, float* __restrict__ mean, float* __restrict__ rstd){
  int row = blockIdx.x*TPB + threadIdx.x;       // (b*Cc+c)*Tin + l
  if(row >= Bx*Cc*Tin) return;
  int l = row % Tin; int bc = row / Tin;
  const float* p = r + (size_t)bc*Nn*Tin + l;
  float s=0.f,s2=0.f;
  for(int n=0;n<Nn;n++){ float v=p[(size_t)n*Tin]; s+=v; s2+=v*v; }
  float m=s*(1.f/Nn); float var=s2*(1.f/Nn)-m*m;
  mean[row]=m; rstd[row]=rsqrtf(fmaxf(var,0.f)+EPSF);
}

// ---------------- xcat = [resid, LN_T, LN_S] ----------------
__global__ __launch_bounds__(TPB) void k_xcat(const float* __restrict__ r, const float* __restrict__ tm, const float* __restrict__ tr,
                                              const float* __restrict__ sm, const float* __restrict__ sr,
                                              const float* __restrict__ gT, const float* __restrict__ bT,
                                              const float* __restrict__ gS, const float* __restrict__ bS,
                                              float* __restrict__ out){
  size_t i = (size_t)blockIdx.x*TPB + threadIdx.x;
  if(i >= (size_t)Bx*192*Nn*Tin) return;
  int l = (int)(i % Tin); size_t r1 = i / Tin; int n = (int)(r1 % Nn); size_t r2 = r1 / Nn;
  int ci = (int)(r2 % 192); int b = (int)(r2 / 192);
  int c = ci & 63; int grp = ci >> 6;
  float v = r[((size_t)(b*Cc+c)*Nn+n)*Tin+l];
  float o;
  if(grp==0) o = v;
  else if(grp==1){ int row=(b*Cc+c)*Nn+n; o = (v-tm[row])*tr[row]*gT[l] + bT[l]; }
  else { int row=(b*Cc+c)*Tin+l; o = (v-sm[row])*sr[row]*gS[n] + bS[n]; }
  out[i]=o;
}

// ---------------- weight transpose: W[o][ci][3] -> WT[(ci*3+kt)*O + o] ----------------
__global__ __launch_bounds__(TPB) void k_wt(const float* __restrict__ W, float* __restrict__ WT, int O, int CI){
  int idx = blockIdx.x*TPB + threadIdx.x;
  int total = O*CI*3;
  if(idx>=total) return;
  int kt = idx%3; int r = idx/3; int ci = r%CI; int o = r/CI;
  WT[(size_t)(ci*3+kt)*O + o] = W[idx];
}

// ---------------- dilated time conv (dil=2) + GLU -> h [B][64][NP] ----------------
__global__ __launch_bounds__(TPB) void k_timeconv(const float* __restrict__ xcat, const float* __restrict__ WT,
                                                  const float* __restrict__ bias, float* __restrict__ h){
  int n = blockIdx.x, b = blockIdx.y;
  __shared__ __align__(16) float sX[192][60];
  __shared__ __align__(16) float sP[128][L50];
  int tid = threadIdx.x;
  for(int i=tid;i<192*60;i+=TPB){ int c=i/60, l=i%60;
    sX[c][l] = (l<Tin) ? xcat[((size_t)(b*192+c)*Nn+n)*Tin+l] : 0.f; }
  __syncthreads();
  int o = tid & 127, half = tid >> 7;
  int t0 = half*28;
  float acc[28];
  #pragma unroll
  for(int j=0;j<28;j++) acc[j]=0.f;
  for(int ci=0;ci<192;ci++){
    float w0 = WT[(size_t)(ci*3+0)*128+o];
    float w1 = WT[(size_t)(ci*3+1)*128+o];
    float w2 = WT[(size_t)(ci*3+2)*128+o];
    float sv[32];
    #pragma unroll
    for(int m=0;m<32;m++) sv[m]=sX[ci][t0+m];
    #pragma unroll
    for(int j=0;j<28;j++) acc[j] += w0*sv[j] + w1*sv[j+2] + w2*sv[j+4];
  }
  float bb = bias[o];
  int nlive = half ? 22 : 28;
  for(int j=0;j<nlive;j++) sP[o][t0+j] = acc[j]+bb;
  __syncthreads();
  for(int i=tid;i<Cc*LP;i+=TPB){
    int c=i/LP, t=i%LP;
    float v = 0.f;
    if(t<L50) v = tanhf(sP[c][t]) * sigm(sP[c+64][t]);
    h[((size_t)b*Cc+c)*NP + (size_t)n*LP + t] = v;
  }
}

// ---------------- gated multi-basis GCN einsum: s = sum_k sigmoid(x@Wq_k)*(x@Wv_k) ----------------
__global__ __launch_bounds__(TPB) void k_gcs(const float* __restrict__ X, const float* __restrict__ wq,
                                             const float* __restrict__ wv, float* __restrict__ S, int D){
  int tile = blockIdx.x, dch = blockIdx.y, b = blockIdx.z;
  int p0 = tile*64, d0c = dch*64;
  __shared__ __align__(16) float sX[64][68];
  __shared__ __align__(16) float sWq[64][64];
  __shared__ __align__(16) float sWv[64][64];
  int tid = threadIdx.x;
  for(int i=tid;i<64*64;i+=TPB){ int c=i>>6, pp=i&63; int p=p0+pp;
    sX[c][pp] = (p<NP) ? X[((size_t)b*64+c)*NP + p] : 0.f; }
  int pg = tid & 15, dg = tid >> 4;
  int pp0 = pg*4, dd0 = dg*4;
  float acc[4][4];
  #pragma unroll
  for(int a=0;a<4;a++){ acc[a][0]=0;acc[a][1]=0;acc[a][2]=0;acc[a][3]=0; }
  for(int k=0;k<Kb;k++){
    __syncthreads();
    for(int i=tid;i<4096;i+=TPB){ int c=i>>6, dd=i&63;
      size_t wo = ((size_t)k*64+c)*D + d0c + dd;
      sWq[c][dd]=wq[wo]; sWv[c][dd]=wv[wo]; }
    __syncthreads();
    float qa[4][4], va[4][4];
    #pragma unroll
    for(int a=0;a<4;a++){ qa[a][0]=0;qa[a][1]=0;qa[a][2]=0;qa[a][3]=0;
                          va[a][0]=0;va[a][1]=0;va[a][2]=0;va[a][3]=0; }
    for(int c=0;c<64;c++){
      float4 x4 = *(const float4*)&sX[c][pp0];
      float4 q4 = *(const float4*)&sWq[c][dd0];
      float4 v4 = *(const float4*)&sWv[c][dd0];
      float xs[4]={x4.x,x4.y,x4.z,x4.w};
      float qs[4]={q4.x,q4.y,q4.z,q4.w};
      float vs[4]={v4.x,v4.y,v4.z,v4.w};
      #pragma unroll
      for(int di=0;di<4;di++)
        #pragma unroll
        for(int pi=0;pi<4;pi++){ qa[di][pi] += qs[di]*xs[pi]; va[di][pi] += vs[di]*xs[pi]; }
    }
    #pragma unroll
    for(int di=0;di<4;di++)
      #pragma unroll
      for(int pi=0;pi<4;pi++) acc[di][pi] += va[di][pi]*sigm(qa[di][pi]);
  }
  #pragma unroll
  for(int di=0;di<4;di++){
    int d = d0c + dd0 + di;
    #pragma unroll
    for(int pi=0;pi<4;pi++){
      int p = p0 + pp0 + pi;
      if(p<NP) S[((size_t)b*D+d)*NP + p] = acc[di][pi];
    }
  }
}

// ---------------- adjacency aggregation: out[b,d,k2,l] = act(sum_n adj[n][k2]*S[b,d,n,l] + bias[d]) ----------------
template<int RELU>
__global__ __launch_bounds__(TPB) void k_agg(const float* __restrict__ S, const float* __restrict__ adj,
                                             const float* __restrict__ bias, float* __restrict__ Out, int D){
  int d = blockIdx.x, b = blockIdx.y;
  __shared__ __align__(16) float sAdj[69][208];
  __shared__ __align__(16) float sSm[69][52];
  int tid = threadIdx.x;
  int kq[3], lq[3], valid[3];
  #pragma unroll
  for(int m=0;m<3;m++){ int mt = tid + m*TPB; valid[m] = (mt<676); kq[m] = mt/13; lq[m] = mt%13; }
  float acc[3][4][4];
  #pragma unroll
  for(int m=0;m<3;m++)
    #pragma unroll
    for(int a=0;a<4;a++){ acc[m][a][0]=0;acc[m][a][1]=0;acc[m][a][2]=0;acc[m][a][3]=0; }
  const float* Sp = S + ((size_t)b*D + d)*NP;
  for(int ch=0; ch<3; ch++){
    int n0 = ch*69;
    __syncthreads();
    for(int i=tid;i<69*208;i+=TPB){ int nn=i/208, k2=i%208;
      sAdj[nn][k2] = (k2<Nn) ? adj[(size_t)(n0+nn)*Nn + k2] : 0.f; }
    for(int i=tid;i<69*52;i+=TPB){ int nn=i/52, l=i%52;
      sSm[nn][l] = Sp[(size_t)(n0+nn)*LP + l]; }
    __syncthreads();
    for(int nn=0;nn<69;nn++){
      #pragma unroll
      for(int m=0;m<3;m++){
        if(!valid[m]) continue;
        float4 a4 = *(const float4*)&sAdj[nn][kq[m]*4];
        float4 s4 = *(const float4*)&sSm[nn][lq[m]*4];
        float as[4]={a4.x,a4.y,a4.z,a4.w};
        float ss[4]={s4.x,s4.y,s4.z,s4.w};
        #pragma unroll
        for(int ki=0;ki<4;ki++)
          #pragma unroll
          for(int li=0;li<4;li++) acc[m][ki][li] += as[ki]*ss[li];
      }
    }
  }
  float bb = bias[d];
  #pragma unroll
  for(int m=0;m<3;m++){
    if(!valid[m]) continue;
    #pragma unroll
    for(int ki=0;ki<4;ki++){
      int k2 = kq[m]*4+ki;
      if(k2>=Nn) continue;
      #pragma unroll
      for(int li=0;li<4;li++){
        int l = lq[m]*4+li;
        float v = acc[m][ki][li] + bb;
        if(RELU) v = fmaxf(v, 0.f);
        Out[(((size_t)b*D+d)*Nn + k2)*LP + l] = v;
      }
    }
  }
}

// ---------------- MLP conv accumulate (dil=1), per layer ----------------
__global__ __launch_bounds__(TPB) void k_mlpacc(const float* __restrict__ Outs, const float* __restrict__ WT,
                                                float* __restrict__ gacc, int layer){
  int n = blockIdx.x, b = blockIdx.y;
  __shared__ __align__(16) float sO[128][52];
  int tid = threadIdx.x;
  for(int i=tid;i<128*52;i+=TPB){ int c=i/52, l=i%52;
    sO[c][l] = Outs[(((size_t)b*128+c)*Nn + n)*LP + l]; }
  __syncthreads();
  int o = tid & 127, half = tid >> 7;
  int t0 = half*24;
  float acc[24];
  #pragma unroll
  for(int j=0;j<24;j++) acc[j]=0.f;
  const float* wt = WT + (size_t)layer*128*3*128;
  for(int ci=0;ci<128;ci++){
    float w0 = wt[(size_t)(ci*3+0)*128+o];
    float w1 = wt[(size_t)(ci*3+1)*128+o];
    float w2 = wt[(size_t)(ci*3+2)*128+o];
    float sv[26];
    #pragma unroll
    for(int m=0;m<26;m++) sv[m]=sO[ci][t0+m];
    #pragma unroll
    for(int j=0;j<24;j++) acc[j] += w0*sv[j] + w1*sv[j+1] + w2*sv[j+2];
  }
  size_t base = (((size_t)b*128+o)*Nn + n)*Tout + t0;
  if(layer==0){ for(int j=0;j<24;j++) gacc[base+j] = acc[j]; }
  else       { for(int j=0;j<24;j++) gacc[base+j] += acc[j]; }
}

// ---------------- GLU over accumulated MLP conv ----------------
__global__ __launch_bounds__(TPB) void k_glu2(const float* __restrict__ gacc, const float* __restrict__ bm, float* __restrict__ gg){
  size_t i = (size_t)blockIdx.x*TPB + threadIdx.x;
  if(i >= (size_t)Bx*Cc*Nn*Tout) return;
  int t = (int)(i % Tout); size_t r = i / Tout; int n = (int)(r % Nn); size_t r2 = r / Nn;
  int c = (int)(r2 % Cc); int b = (int)(r2 / Cc);
  size_t i1 = (((size_t)b*128+c)*Nn+n)*Tout + t;
  size_t i2 = (((size_t)b*128+c+64)*Nn+n)*Tout + t;
  float a = gacc[i1]+bm[c], b2 = gacc[i2]+bm[c+64];
  gg[i] = tanhf(a)*sigm(b2);
}

// ---------------- patch scramble + emb: xe[b, n2*6144 + p2*512 + e] ----------------
__global__ __launch_bounds__(TPB) void k_xe(const float* __restrict__ gg, const float* __restrict__ emb, float* __restrict__ xe){
  size_t i = (size_t)blockIdx.x*TPB + threadIdx.x;
  if(i >= (size_t)Bx*1271808) return;
  int b = (int)(i / 1271808);
  int off = (int)(i % 1271808);
  int c = off / 19872; int r = off % 19872;
  int n = r / 96; int r2 = r % 96;
  int p = r2 >> 3; int j = r2 & 7;
  int t = p*4 + j;
  float v = 0.f;
  if(t < Tout) v = gg[(((size_t)b*Cc+c)*Nn + n)*Tout + t];
  int e = off & 511; int p2 = (off >> 9) % 12;
  xe[i] = v + emb[(size_t)p2*Ee + e];
}

// ---------------- per-row LN helper (rows of 512 in LDS) ----------------
__device__ __forceinline__ void ln_rows(float* buf, const float* __restrict__ g, const float* __restrict__ be, int tid){
  int lane = tid & 63, wv = tid >> 6;
  for(int r = wv; r < 12; r += 4){
    float s=0.f, s2=0.f;
    #pragma unroll
    for(int j=0;j<8;j++){ float v = buf[r*512 + j*64 + lane]; s+=v; s2+=v*v; }
    #pragma unroll
    for(int off=32; off; off>>=1){ s += __shfl_xor(s,off); s2 += __shfl_xor(s2,off); }
    float m = s*(1.f/512.f);
    float rstd = rsqrtf(fmaxf(s2*(1.f/512.f)-m*m, 0.f)+EPSF);
    #pragma unroll
    for(int j=0;j<8;j++){ int e = j*64+lane; float v = buf[r*512+e];
      buf[r*512+e] = (v-m)*rstd*g[e] + be[e]; }
  }
}

__device__ __forceinline__ void qkv_mat(const float* __restrict__ sXE, const float* __restrict__ sW,
                                        const float* __restrict__ bias, float4 out[6], int tid){
  int d0 = (tid&15)*4, hh = (tid>>4)&7, pb = tid>>7;
  float4 b4 = *(const float4*)&bias[d0];
  #pragma unroll
  for(int g=0;g<6;g++) out[g]=b4;
  for(int dp=0; dp<64; dp++){
    float4 w4 = *(const float4*)&sW[dp*64 + d0];
    #pragma unroll
    for(int g=0;g<6;g++){
      float a = sXE[(pb + g*2)*512 + hh*64 + dp];
      FMA4(out[g], a, w4);
    }
  }
}
__device__ __forceinline__ void qkv_store(float* dst, const float4 v[6], int tid){
  int d0 = (tid&15)*4, hh = (tid>>4)&7, pb = tid>>7;
  #pragma unroll
  for(int g=0;g<6;g++) *(float4*)&dst[(pb+g*2)*512 + hh*64 + d0] = v[g];
}

// ---------------- fused per-(b,n) transformer + reprojection + residual add ----------------
__global__ __launch_bounds__(TPB) void k_attn(
    const float* __restrict__ xe, const float* __restrict__ resid,
    const float* __restrict__ Wq, const float* __restrict__ bq,
    const float* __restrict__ Wk, const float* __restrict__ bk,
    const float* __restrict__ Wv, const float* __restrict__ bv,
    const float* __restrict__ Wfc, const float* __restrict__ bfc,
    const float* __restrict__ g1, const float* __restrict__ b1n,
    const float* __restrict__ g2, const float* __restrict__ b2n,
    const float* __restrict__ Wff1, const float* __restrict__ bff1,
    const float* __restrict__ Wff2, const float* __restrict__ bff2,
    const float* __restrict__ Wrp, const float* __restrict__ brp,
    float* __restrict__ y)
{
  int n = blockIdx.x, b = blockIdx.y;
  __shared__ __align__(16) float sXE[6144];
  __shared__ __align__(16) float sA[6144];   // qs -> ao -> ffo/U
  __shared__ __align__(16) float sB[6144];   // ks -> fc/M -> Wrp
  __shared__ __align__(16) float sC[6144];   // W staging -> vs -> ffmid -> Odat
  __shared__ __align__(16) float sS[1152];
  int tid = threadIdx.x;
  const size_t xeb = ((size_t)b*Nn + n)*6144;
  for(int i=tid;i<6144;i+=TPB) sXE[i] = xe[xeb+i];
  for(int i=tid;i<4096;i+=TPB) sC[i] = Wv[i];
  __syncthreads();
  float4 vreg[6];
  qkv_mat(sXE, sC, bv, vreg, tid);
  __syncthreads();
  for(int i=tid;i<4096;i+=TPB) sC[i] = Wq[i];
  __syncthreads();
  { float4 qv[6]; qkv_mat(sXE, sC, bq, qv, tid); qkv_store(sA, qv, tid); }
  __syncthreads();
  for(int i=tid;i<4096;i+=TPB) sC[i] = Wk[i];
  __syncthreads();
  { float4 kv[6]; qkv_mat(sXE, sC, bk, kv, tid); qkv_store(sB, kv, tid); }
  __syncthreads();
  qkv_store(sC, vreg, tid);
  __syncthreads();
  // scores [kh][q]
  const float scale = 0.04419417382415922f;   // 1/sqrt(512)
  for(int i=tid;i<1152;i+=TPB){
    int q = i%12, kh = i/12; int h2 = kh&7, k2 = kh>>3;
    const float* qp = &sA[q*512 + h2*64];
    const float* kp = &sB[k2*512 + h2*64];
    float s=0.f;
    #pragma unroll 8
    for(int d=0; d<64; d++) s += qp[d]*kp[d];
    sS[i] = s*scale;
  }
  __syncthreads();
  // softmax over q (per kh)
  if(tid<96){
    float mx=-1e30f;
    for(int q=0;q<12;q++) mx = fmaxf(mx, sS[tid*12+q]);
    float sm=0.f;
    for(int q=0;q<12;q++){ float e = __expf(sS[tid*12+q]-mx); sS[tid*12+q]=e; sm+=e; }
    float inv = 1.f/sm;
    for(int q=0;q<12;q++) sS[tid*12+q] *= inv;
  }
  __syncthreads();
  // ao -> sA
  for(int i=tid;i<6144;i+=TPB){
    int q=i>>9, h2=(i>>6)&7, d=i&63;
    float s=0.f;
    #pragma unroll
    for(int k2=0;k2<12;k2++) s += sS[(k2*8+h2)*12+q]*sC[k2*512+h2*64+d];
    sA[i]=s;
  }
  __syncthreads();
  // fc (+bfc +xe) -> sB
  {
    int e0 = (tid&127)*4, ph = tid>>7;
    float4 acc[6]; float4 b4 = *(const float4*)&bfc[e0];
    #pragma unroll
    for(int g=0;g<6;g++) acc[g]=b4;
    for(int ep=0; ep<512; ep++){
      float4 w4 = *(const float4*)&Wfc[(size_t)ep*512 + e0];
      #pragma unroll
      for(int g=0;g<6;g++){ float a = sA[(ph*6+g)*512 + ep]; FMA4(acc[g], a, w4); }
    }
    #pragma unroll
    for(int g=0;g<6;g++){
      int p = ph*6+g;
      float4 xv = *(const float4*)&sXE[p*512+e0];
      acc[g].x += xv.x; acc[g].y += xv.y; acc[g].z += xv.z; acc[g].w += xv.w;
      *(float4*)&sB[p*512+e0] = acc[g];
    }
  }
  __syncthreads();
  ln_rows(sB, g1, b1n, tid);     // M
  __syncthreads();
  // ff1 -> sC (relu)
  {
    int u0 = (tid&63)*4, pg = tid>>6;
    float4 acc[3]; float4 b4 = *(const float4*)&bff1[u0];
    #pragma unroll
    for(int g=0;g<3;g++) acc[g]=b4;
    for(int e=0;e<512;e++){
      float4 w4 = *(const float4*)&Wff1[(size_t)e*256 + u0];
      #pragma unroll
      for(int g=0;g<3;g++){ float a = sB[(pg*3+g)*512 + e]; FMA4(acc[g], a, w4); }
    }
    #pragma unroll
    for(int g=0;g<3;g++){
      acc[g].x=fmaxf(acc[g].x,0.f); acc[g].y=fmaxf(acc[g].y,0.f);
      acc[g].z=fmaxf(acc[g].z,0.f); acc[g].w=fmaxf(acc[g].w,0.f);
      *(float4*)&sC[(pg*3+g)*256 + u0] = acc[g];
    }
  }
  __syncthreads();
  // ff2 (+bff2 +M) -> sA
  {
    int e0 = (tid&127)*4, ph = tid>>7;
    float4 acc[6]; float4 b4 = *(const float4*)&bff2[e0];
    #pragma unroll
    for(int g=0;g<6;g++) acc[g]=b4;
    for(int u=0;u<256;u++){
      float4 w4 = *(const float4*)&Wff2[(size_t)u*512 + e0];
      #pragma unroll
      for(int g=0;g<6;g++){ float a = sC[(ph*6+g)*256 + u]; FMA4(acc[g], a, w4); }
    }
    #pragma unroll
    for(int g=0;g<6;g++){
      int p = ph*6+g;
      float4 m4 = *(const float4*)&sB[p*512+e0];
      acc[g].x += m4.x; acc[g].y += m4.y; acc[g].z += m4.z; acc[g].w += m4.w;
      *(float4*)&sA[p*512+e0] = acc[g];
    }
  }
  __syncthreads();
  ln_rows(sA, g2, b2n, tid);     // U
  __syncthreads();
  // Odat = U + xe + M -> sC
  for(int i=tid;i<6144;i+=TPB) sC[i] = sA[i] + sXE[i] + sB[i];
  __syncthreads();
  for(int i=tid;i<4608;i+=TPB) sB[i] = Wrp[i];
  __syncthreads();
  // y[b,c,n,t] = Odat(reshape [64][96]) @ Wrp + brp + resid[..., 6+t]
  #pragma unroll
  for(int j=0;j<3;j++){
    int i4 = tid + j*TPB;                 // 768 quads
    int c = i4/12, tq = i4%12; int t0 = tq*4;
    float4 acc = *(const float4*)&brp[t0];
    const float* od = &sC[c*96];
    for(int t96=0;t96<96;t96++){
      float a = od[t96];
      float4 w4 = *(const float4*)&sB[t96*48 + t0];
      FMA4(acc, a, w4);
    }
    size_t rb = (((size_t)b*Cc+c)*Nn + n)*Tin + 6 + t0;
    acc.x += resid[rb+0]; acc.y += resid[rb+1]; acc.z += resid[rb+2]; acc.w += resid[rb+3];
    *(float4*)&y[(((size_t)b*Cc+c)*Nn + n)*Tout + t0] = acc;
  }
}

// ---------------- batchnorm ----------------
__global__ __launch_bounds__(TPB) void k_bnstats(const float* __restrict__ y, float* __restrict__ stats){
  int c = blockIdx.x; int tid = threadIdx.x;
  float s=0.f,s2=0.f;
  const int per = Nn*Tout;   // 9936
  for(int idx=tid; idx<Bx*per; idx+=TPB){
    int b = idx/per, r = idx%per;
    float v = y[((size_t)b*Cc+c)*per + r];
    s+=v; s2+=v*v;
  }
  __shared__ float rs[TPB], rs2[TPB];
  rs[tid]=s; rs2[tid]=s2; __syncthreads();
  for(int off=TPB/2; off; off>>=1){ if(tid<off){ rs[tid]+=rs[tid+off]; rs2[tid]+=rs2[tid+off]; } __syncthreads(); }
  if(tid==0){
    float m = rs[0]/(float)(Bx*per);
    float var = rs2[0]/(float)(Bx*per) - m*m;
    stats[c]=m; stats[64+c]=rsqrtf(fmaxf(var,0.f)+EPSF);
  }
}
__global__ __launch_bounds__(TPB) void k_bnout(const float* __restrict__ y, const float* __restrict__ stats,
                                               const float* __restrict__ gbn, const float* __restrict__ bbn,
                                               float* __restrict__ out){
  size_t i = (size_t)blockIdx.x*TPB + threadIdx.x;
  if(i >= (size_t)Bx*Cc*Nn*Tout) return;
  int c = (int)((i/(Nn*Tout))%Cc);
  out[i] = (y[i]-stats[c])*stats[64+c]*gbn[c] + bbn[c];
}

// ---------------- launch ----------------
extern "C" void kernel_launch(void* const* d_in, const int* in_sizes, int n_in,
                              void* d_out, int out_size, void* d_ws, size_t ws_size,
                              hipStream_t stream) {
  const float* x      = (const float*)d_in[0];
  const float* adj    = (const float*)d_in[1];
  const float* Wconv1 = (const float*)d_in[2];
  const float* bconv1 = (const float*)d_in[3];
  const float* gT     = (const float*)d_in[4];
  const float* bT     = (const float*)d_in[5];
  const float* gS     = (const float*)d_in[6];
  const float* bS     = (const float*)d_in[7];
  const float* Wtime  = (const float*)d_in[8];
  const float* btime  = (const float*)d_in[9];
  const float* wq1    = (const float*)d_in[10];
  const float* wv1    = (const float*)d_in[11];
  const float* bias1  = (const float*)d_in[12];
  const float* wq2    = (const float*)d_in[13];
  const float* wv2    = (const float*)d_in[14];
  const float* bias2  = (const float*)d_in[15];
  const float* Wmlp   = (const float*)d_in[16];
  const float* bmlp   = (const float*)d_in[17];
  const float* embT   = (const float*)d_in[18];
  const float* Wq     = (const float*)d_in[19];
  const float* bq     = (const float*)d_in[20];
  const float* Wk     = (const float*)d_in[21];
  const float* bk     = (const float*)d_in[22];
  const float* Wv     = (const float*)d_in[23];
  const float* bv     = (const float*)d_in[24];
  const float* Wfc    = (const float*)d_in[25];
  const float* bfc    = (const float*)d_in[26];
  const float* g1     = (const float*)d_in[27];
  const float* b1n    = (const float*)d_in[28];
  const float* g2     = (const float*)d_in[29];
  const float* b2n    = (const float*)d_in[30];
  const float* Wff1   = (const float*)d_in[31];
  const float* bff1   = (const float*)d_in[32];
  const float* Wff2   = (const float*)d_in[33];
  const float* bff2   = (const float*)d_in[34];
  const float* Wrp    = (const float*)d_in[35];
  const float* brp    = (const float*)d_in[36];
  const float* gbn    = (const float*)d_in[37];
  const float* bbn    = (const float*)d_in[38];

  float* ws = (float*)d_ws;
  float* RESID = ws + O_RESID;
  float* LNTM  = ws + O_LNTM;
  float* LNTR  = ws + O_LNTR;
  float* LNSM  = ws + O_LNSM;
  float* LNSR  = ws + O_LNSR;
  float* XCAT  = ws + O_XCAT;
  float* RA    = ws + O_XCAT;    // overlays XCAT after it is consumed
  float* RB    = ws + O_RB;
  float* H     = ws + O_H;
  float* GACC  = ws + O_GACC;
  float* GG    = ws + O_GG;
  float* Y     = ws + O_GG;      // overlays GG after xe built
  float* XE    = ws + O_XE;
  float* WTT   = ws + O_WTT;
  float* WTM   = ws + O_WTM;
  float* BNST  = ws + O_BNST;

  k_residual<<<dim3(Nn,Bx),TPB,0,stream>>>(x, Wconv1, bconv1, RESID);
  k_lnT<<<(Bx*Cc*Nn)/TPB,TPB,0,stream>>>(RESID, LNTM, LNTR);
  k_lnS<<<(Bx*Cc*Tin)/TPB,TPB,0,stream>>>(RESID, LNSM, LNSR);
  k_xcat<<<(Bx*192*Nn*Tin)/TPB,TPB,0,stream>>>(RESID, LNTM, LNTR, LNSM, LNSR, gT,bT,gS,bS, XCAT);
  k_wt<<<(128*192*3+TPB-1)/TPB,TPB,0,stream>>>(Wtime, WTT, 128, 192);
  k_wt<<<(128*384*3+TPB-1)/TPB,TPB,0,stream>>>(Wmlp,  WTM, 128, 384);
  k_timeconv<<<dim3(Nn,Bx),TPB,0,stream>>>(XCAT, WTT, btime, H);

  const int NTILE = (NP+63)/64;   // 169
  for(int i=0;i<3;i++){
    k_gcs<<<dim3(NTILE,1,Bx),TPB,0,stream>>>(H,  wq1+(size_t)i*Kb*64*64,  wv1+(size_t)i*Kb*64*64,  RA, 64);
    k_agg<1><<<dim3(64,Bx),TPB,0,stream>>>(RA, adj+(size_t)i*Nn*Nn, bias1+(size_t)i*64,  RB, 64);
    k_gcs<<<dim3(NTILE,2,Bx),TPB,0,stream>>>(RB, wq2+(size_t)i*Kb*64*128, wv2+(size_t)i*Kb*64*128, RA, 128);
    k_agg<0><<<dim3(128,Bx),TPB,0,stream>>>(RA, adj+(size_t)i*Nn*Nn, bias2+(size_t)i*128, RB, 128);
    k_mlpacc<<<dim3(Nn,Bx),TPB,0,stream>>>(RB, WTM, GACC, i);
  }
  k_glu2<<<(Bx*Cc*Nn*Tout)/TPB,TPB,0,stream>>>(GACC, bmlp, GG);
  k_xe<<<(Bx*1271808)/TPB,TPB,0,stream>>>(GG, embT, XE);
  k_attn<<<dim3(Nn,Bx),TPB,0,stream>>>(XE, RESID, Wq,bq,Wk,bk,Wv,bv,Wfc,bfc,g1,b1n,g2,b2n,
                                       Wff1,bff1,Wff2,bff2,Wrp,brp, Y);
  k_bnstats<<<64,TPB,0,stream>>>(Y, BNST);
  k_bnout<<<(Bx*Cc*Nn*Tout)/TPB,TPB,0,stream>>>(Y, BNST, gbn, bbn, (float*)d_out);
}

// Round 3
// 4194.585 us; speedup vs baseline: 1.0851x; 1.0851x over previous
//
#include <hip/hip_runtime.h>
#include <hip/hip_bf16.h>

#define TPB 256

constexpr int Bx = 8, Cc = 64, Nn = 207, Tin = 54, Kb = 8;
constexpr int LP = 52, NP = Nn * LP;     // time padded 50->52, flattened node*time positions
constexpr int L50 = 50, Tout = 48;
constexpr int Ee = 512, Pn = 12;
constexpr float EPSF = 1e-5f;
constexpr int SRD = 516;                 // padded row stride for 512-wide LDS rows (bank-conflict break)

// ---------------- workspace layout (floats) ----------------
constexpr size_t O_RESID = 0;                                   // [B][64][207][54]
constexpr size_t O_LNTM  = O_RESID + (size_t)Bx*Cc*Nn*Tin;
constexpr size_t O_LNTR  = O_LNTM  + (size_t)Bx*Cc*Nn;
constexpr size_t O_LNSM  = O_LNTR  + (size_t)Bx*Cc*Nn;
constexpr size_t O_LNSR  = O_LNSM  + (size_t)Bx*Cc*Tin;
constexpr size_t O_XCAT  = O_LNSR  + (size_t)Bx*Cc*Tin;         // [B][192][207][54]; later reused as RA [B][128][NP]
constexpr size_t O_RB    = O_XCAT  + (size_t)Bx*192*Nn*Tin;     // [B][128][NP]
constexpr size_t O_H     = O_RB    + (size_t)Bx*128*NP;         // [B][64][NP]
constexpr size_t O_GACC  = O_H     + (size_t)Bx*64*NP;          // [B][128][207][48]
constexpr size_t O_GG    = O_GACC  + (size_t)Bx*128*Nn*Tout;    // [B][64][207][48]; later reused as Y
constexpr size_t O_XE    = O_GG    + (size_t)Bx*64*Nn*Tout;     // [B][207][12][512]
constexpr size_t O_WTT   = O_XE    + (size_t)Bx*Nn*Pn*Ee;       // transposed W_time 128*192*3
constexpr size_t O_WTM   = O_WTT   + (size_t)128*192*3;         // transposed W_mlp 128*384*3
constexpr size_t O_BNST  = O_WTM   + (size_t)128*384*3;         // 128

#define FMA4(acc, sA_, vB_) { (acc).x += (sA_)*(vB_).x; (acc).y += (sA_)*(vB_).y; (acc).z += (sA_)*(vB_).z; (acc).w += (sA_)*(vB_).w; }

__device__ __forceinline__ float sigm(float x){ return 1.0f/(1.0f+__expf(-x)); }

// ---------------- residual = W_conv1 @ x + b ----------------
__global__ __launch_bounds__(TPB) void k_residual(const float* __restrict__ x, const float* __restrict__ W,
                                                  const float* __restrict__ bias, float* __restrict__ out){
  int n = blockIdx.x, b = blockIdx.y;
  __shared__ __align__(16) float sX[Cc][Tin];
  __shared__ __align__(16) float sW[Cc*Cc];
  int tid = threadIdx.x;
  for(int i=tid;i<Cc*Tin;i+=TPB){ int c=i/Tin, l=i%Tin; sX[c][l] = x[((size_t)(b*Cc+c)*Nn+n)*Tin+l]; }
  for(int i=tid;i<Cc*Cc;i+=TPB) sW[i]=W[i];
  __syncthreads();
  for(int i=tid;i<Cc*Tin;i+=TPB){
    int o=i/Tin, l=i%Tin; float acc=bias[o];
    #pragma unroll 8
    for(int c=0;c<Cc;c++) acc += sW[o*Cc+c]*sX[c][l];
    out[((size_t)(b*Cc+o)*Nn+n)*Tin+l]=acc;
  }
}

// ---------------- LN stats ----------------
__global__ __launch_bounds__(TPB) void k_lnT(const float* __restrict__ r, float* __restrict__ mean, float* __restrict__ rstd){
  int row = blockIdx.x*TPB + threadIdx.x;
  if(row >= Bx*Cc*Nn) return;
  const float* p = r + (size_t)row*Tin;
  float s=0.f,s2=0.f;
  for(int l=0;l<Tin;l++){ float v=p[l]; s+=v; s2+=v*v; }
  float m=s*(1.f/Tin); float var=s2*(1.f/Tin)-m*m;
  mean[row]=m; rstd[row]=rsqrtf(fmaxf(var,0.f)+EPSF);
}
__global__ __launch_bounds__(TPB) void k_lnS(const float* __restrict__ r, float* __restrict__ mean, float* __restrict__ rstd){
  int row = blockIdx.x*TPB + threadIdx.x;       // (b*Cc+c)*Tin + l
  if(row >= Bx*Cc*Tin) return;
  int l = row % Tin; int bc = row / Tin;
  const float* p = r + (size_t)bc*Nn*Tin + l;
  float s=0.f,s2=0.f;
  for(int n=0;n<Nn;n++){ float v=p[(size_t)n*Tin]; s+=v; s2+=v*v; }
  float m=s*(1.f/Nn); float var=s2*(1.f/Nn)-m*m;
  mean[row]=m; rstd[row]=rsqrtf(fmaxf(var,0.f)+EPSF);
}

// ---------------- xcat = [resid, LN_T, LN_S] ----------------
__global__ __launch_bounds__(TPB) void k_xcat(const float* __restrict__ r, const float* __restrict__ tm, const float* __restrict__ tr,
                                              const float* __restrict__ sm, const float* __restrict__ sr,
                                              const float* __restrict__ gT, const float* __restrict__ bT,
                                              const float* __restrict__ gS, const float* __restrict__ bS,
                                              float* __restrict__ out){
  size_t i = (size_t)blockIdx.x*TPB + threadIdx.x;
  if(i >= (size_t)Bx*192*Nn*Tin) return;
  int l = (int)(i % Tin); size_t r1 = i / Tin; int n = (int)(r1 % Nn); size_t r2 = r1 / Nn;
  int ci = (int)(r2 % 192); int b = (int)(r2 / 192);
  int c = ci & 63; int grp = ci >> 6;
  float v = r[((size_t)(b*Cc+c)*Nn+n)*Tin+l];
  float o;
  if(grp==0) o = v;
  else if(grp==1){ int row=(b*Cc+c)*Nn+n; o = (v-tm[row])*tr[row]*gT[l] + bT[l]; }
  else { int row=(b*Cc+c)*Tin+l; o = (v-sm[row])*sr[row]*gS[n] + bS[n]; }
  out[i]=o;
}

// ---------------- weight transpose: W[o][ci][3] -> WT[(ci*3+kt)*O + o] ----------------
__global__ __launch_bounds__(TPB) void k_wt(const float* __restrict__ W, float* __restrict__ WT, int O, int CI){
  int idx = blockIdx.x*TPB + threadIdx.x;
  int total = O*CI*3;
  if(idx>=total) return;
  int kt = idx%3; int r = idx/3; int ci = r%CI; int o = r/CI;
  WT[(size_t)(ci*3+kt)*O + o] = W[idx];
}

// ---------------- dilated time conv (dil=2) + GLU -> h [B][64][NP] ----------------
__global__ __launch_bounds__(TPB) void k_timeconv(const float* __restrict__ xcat, const float* __restrict__ WT,
                                                  const float* __restrict__ bias, float* __restrict__ h){
  int n = blockIdx.x, b = blockIdx.y;
  __shared__ __align__(16) float sX[192][60];
  __shared__ __align__(16) float sP[128][L50];
  int tid = threadIdx.x;
  for(int i=tid;i<192*60;i+=TPB){ int c=i/60, l=i%60;
    sX[c][l] = (l<Tin) ? xcat[((size_t)(b*192+c)*Nn+n)*Tin+l] : 0.f; }
  __syncthreads();
  int o = tid & 127, half = tid >> 7;
  int t0 = half*28;
  float acc[28];
  #pragma unroll
  for(int j=0;j<28;j++) acc[j]=0.f;
  for(int ci=0;ci<192;ci++){
    float w0 = WT[(size_t)(ci*3+0)*128+o];
    float w1 = WT[(size_t)(ci*3+1)*128+o];
    float w2 = WT[(size_t)(ci*3+2)*128+o];
    float sv[32];
    #pragma unroll
    for(int m=0;m<32;m++) sv[m]=sX[ci][t0+m];
    #pragma unroll
    for(int j=0;j<28;j++) acc[j] += w0*sv[j] + w1*sv[j+2] + w2*sv[j+4];
  }
  float bb = bias[o];
  int nlive = half ? 22 : 28;
  for(int j=0;j<nlive;j++) sP[o][t0+j] = acc[j]+bb;
  __syncthreads();
  for(int i=tid;i<Cc*LP;i+=TPB){
    int c=i/LP, t=i%LP;
    float v = 0.f;
    if(t<L50) v = tanhf(sP[c][t]) * sigm(sP[c+64][t]);
    h[((size_t)b*Cc+c)*NP + (size_t)n*LP + t] = v;
  }
}

// ---------------- gated multi-basis GCN einsum: s = sum_k sigmoid(x@Wq_k)*(x@Wv_k) ----------------
__global__ __launch_bounds__(TPB) void k_gcs(const float* __restrict__ X, const float* __restrict__ wq,
                                             const float* __restrict__ wv, float* __restrict__ S, int D){
  int tile = blockIdx.x, dch = blockIdx.y, b = blockIdx.z;
  int p0 = tile*64, d0c = dch*64;
  __shared__ __align__(16) float sX[64][68];
  __shared__ __align__(16) float sWq[64][64];
  __shared__ __align__(16) float sWv[64][64];
  int tid = threadIdx.x;
  for(int i=tid;i<64*64;i+=TPB){ int c=i>>6, pp=i&63; int p=p0+pp;
    sX[c][pp] = (p<NP) ? X[((size_t)b*64+c)*NP + p] : 0.f; }
  int pg = tid & 15, dg = tid >> 4;
  int pp0 = pg*4, dd0 = dg*4;
  float acc[4][4];
  #pragma unroll
  for(int a=0;a<4;a++){ acc[a][0]=0;acc[a][1]=0;acc[a][2]=0;acc[a][3]=0; }
  for(int k=0;k<Kb;k++){
    __syncthreads();
    for(int i=tid;i<4096;i+=TPB){ int c=i>>6, dd=i&63;
      size_t wo = ((size_t)k*64+c)*D + d0c + dd;
      sWq[c][dd]=wq[wo]; sWv[c][dd]=wv[wo]; }
    __syncthreads();
    float qa[4][4], va[4][4];
    #pragma unroll
    for(int a=0;a<4;a++){ qa[a][0]=0;qa[a][1]=0;qa[a][2]=0;qa[a][3]=0;
                          va[a][0]=0;va[a][1]=0;va[a][2]=0;va[a][3]=0; }
    for(int c=0;c<64;c++){
      float4 x4 = *(const float4*)&sX[c][pp0];
      float4 q4 = *(const float4*)&sWq[c][dd0];
      float4 v4 = *(const float4*)&sWv[c][dd0];
      float xs[4]={x4.x,x4.y,x4.z,x4.w};
      float qs[4]={q4.x,q4.y,q4.z,q4.w};
      float vs[4]={v4.x,v4.y,v4.z,v4.w};
      #pragma unroll
      for(int di=0;di<4;di++)
        #pragma unroll
        for(int pi=0;pi<4;pi++){ qa[di][pi] += qs[di]*xs[pi]; va[di][pi] += vs[di]*xs[pi]; }
    }
    #pragma unroll
    for(int di=0;di<4;di++)
      #pragma unroll
      for(int pi=0;pi<4;pi++) acc[di][pi] += va[di][pi]*sigm(qa[di][pi]);
  }
  #pragma unroll
  for(int di=0;di<4;di++){
    int d = d0c + dd0 + di;
    #pragma unroll
    for(int pi=0;pi<4;pi++){
      int p = p0 + pp0 + pi;
      if(p<NP) S[((size_t)b*D+d)*NP + p] = acc[di][pi];
    }
  }
}

// ---------------- adjacency aggregation: out[b,d,k2,l] = act(sum_n adj[n][k2]*S[b,d,n,l] + bias[d]) ----------------
template<int RELU>
__global__ __launch_bounds__(TPB) void k_agg(const float* __restrict__ S, const float* __restrict__ adj,
                                             const float* __restrict__ bias, float* __restrict__ Out, int D){
  int d = blockIdx.x, b = blockIdx.y;
  __shared__ __align__(16) float sAdj[69][208];
  __shared__ __align__(16) float sSm[69][52];
  int tid = threadIdx.x;
  int kq[3], lq[3], valid[3];
  #pragma unroll
  for(int m=0;m<3;m++){ int mt = tid + m*TPB; valid[m] = (mt<676); kq[m] = mt/13; lq[m] = mt%13; }
  float acc[3][4][4];
  #pragma unroll
  for(int m=0;m<3;m++)
    #pragma unroll
    for(int a=0;a<4;a++){ acc[m][a][0]=0;acc[m][a][1]=0;acc[m][a][2]=0;acc[m][a][3]=0; }
  const float* Sp = S + ((size_t)b*D + d)*NP;
  for(int ch=0; ch<3; ch++){
    int n0 = ch*69;
    __syncthreads();
    for(int i=tid;i<69*208;i+=TPB){ int nn=i/208, k2=i%208;
      sAdj[nn][k2] = (k2<Nn) ? adj[(size_t)(n0+nn)*Nn + k2] : 0.f; }
    for(int i=tid;i<69*52;i+=TPB){ int nn=i/52, l=i%52;
      sSm[nn][l] = Sp[(size_t)(n0+nn)*LP + l]; }
    __syncthreads();
    for(int nn=0;nn<69;nn++){
      #pragma unroll
      for(int m=0;m<3;m++){
        if(!valid[m]) continue;
        float4 a4 = *(const float4*)&sAdj[nn][kq[m]*4];
        float4 s4 = *(const float4*)&sSm[nn][lq[m]*4];
        float as[4]={a4.x,a4.y,a4.z,a4.w};
        float ss[4]={s4.x,s4.y,s4.z,s4.w};
        #pragma unroll
        for(int ki=0;ki<4;ki++)
          #pragma unroll
          for(int li=0;li<4;li++) acc[m][ki][li] += as[ki]*ss[li];
      }
    }
  }
  float bb = bias[d];
  #pragma unroll
  for(int m=0;m<3;m++){
    if(!valid[m]) continue;
    #pragma unroll
    for(int ki=0;ki<4;ki++){
      int k2 = kq[m]*4+ki;
      if(k2>=Nn) continue;
      #pragma unroll
      for(int li=0;li<4;li++){
        int l = lq[m]*4+li;
        float v = acc[m][ki][li] + bb;
        if(RELU) v = fmaxf(v, 0.f);
        Out[(((size_t)b*D+d)*Nn + k2)*LP + l] = v;
      }
    }
  }
}

// ---------------- MLP conv accumulate (dil=1), per layer ----------------
__global__ __launch_bounds__(TPB) void k_mlpacc(const float* __restrict__ Outs, const float* __restrict__ WT,
                                                float* __restrict__ gacc, int layer){
  int n = blockIdx.x, b = blockIdx.y;
  __shared__ __align__(16) float sO[128][52];
  int tid = threadIdx.x;
  for(int i=tid;i<128*52;i+=TPB){ int c=i/52, l=i%52;
    sO[c][l] = Outs[(((size_t)b*128+c)*Nn + n)*LP + l]; }
  __syncthreads();
  int o = tid & 127, half = tid >> 7;
  int t0 = half*24;
  float acc[24];
  #pragma unroll
  for(int j=0;j<24;j++) acc[j]=0.f;
  const float* wt = WT + (size_t)layer*128*3*128;
  for(int ci=0;ci<128;ci++){
    float w0 = wt[(size_t)(ci*3+0)*128+o];
    float w1 = wt[(size_t)(ci*3+1)*128+o];
    float w2 = wt[(size_t)(ci*3+2)*128+o];
    float sv[26];
    #pragma unroll
    for(int m=0;m<26;m++) sv[m]=sO[ci][t0+m];
    #pragma unroll
    for(int j=0;j<24;j++) acc[j] += w0*sv[j] + w1*sv[j+1] + w2*sv[j+2];
  }
  size_t base = (((size_t)b*128+o)*Nn + n)*Tout + t0;
  if(layer==0){ for(int j=0;j<24;j++) gacc[base+j] = acc[j]; }
  else       { for(int j=0;j<24;j++) gacc[base+j] += acc[j]; }
}

// ---------------- GLU over accumulated MLP conv ----------------
__global__ __launch_bounds__(TPB) void k_glu2(const float* __restrict__ gacc, const float* __restrict__ bm, float* __restrict__ gg){
  size_t i = (size_t)blockIdx.x*TPB + threadIdx.x;
  if(i >= (size_t)Bx*Cc*Nn*Tout) return;
  int t = (int)(i % Tout); size_t r = i / Tout; int n = (int)(r % Nn); size_t r2 = r / Nn;
  int c = (int)(r2 % Cc); int b = (int)(r2 / Cc);
  size_t i1 = (((size_t)b*128+c)*Nn+n)*Tout + t;
  size_t i2 = (((size_t)b*128+c+64)*Nn+n)*Tout + t;
  float a = gacc[i1]+bm[c], b2 = gacc[i2]+bm[c+64];
  gg[i] = tanhf(a)*sigm(b2);
}

// ---------------- patch scramble + emb: xe[b, n2*6144 + p2*512 + e] ----------------
__global__ __launch_bounds__(TPB) void k_xe(const float* __restrict__ gg, const float* __restrict__ emb, float* __restrict__ xe){
  size_t i = (size_t)blockIdx.x*TPB + threadIdx.x;
  if(i >= (size_t)Bx*1271808) return;
  int b = (int)(i / 1271808);
  int off = (int)(i % 1271808);
  int c = off / 19872; int r = off % 19872;
  int n = r / 96; int r2 = r % 96;
  int p = r2 >> 3; int j = r2 & 7;
  int t = p*4 + j;
  float v = 0.f;
  if(t < Tout) v = gg[(((size_t)b*Cc+c)*Nn + n)*Tout + t];
  int e = off & 511; int p2 = (off >> 9) % 12;
  xe[i] = v + emb[(size_t)p2*Ee + e];
}

// ---------------- per-row LN helper (rows of 512, stride SRD, in LDS) ----------------
__device__ __forceinline__ void ln_rows(float* buf, const float* __restrict__ g, const float* __restrict__ be, int tid){
  int lane = tid & 63, wv = tid >> 6;
  for(int r = wv; r < 12; r += 4){
    float s=0.f, s2=0.f;
    #pragma unroll
    for(int j=0;j<8;j++){ float v = buf[r*SRD + j*64 + lane]; s+=v; s2+=v*v; }
    #pragma unroll
    for(int off=32; off; off>>=1){ s += __shfl_xor(s,off); s2 += __shfl_xor(s2,off); }
    float m = s*(1.f/512.f);
    float rstd = rsqrtf(fmaxf(s2*(1.f/512.f)-m*m, 0.f)+EPSF);
    #pragma unroll
    for(int j=0;j<8;j++){ int e = j*64+lane; float v = buf[r*SRD+e];
      buf[r*SRD+e] = (v-m)*rstd*g[e] + be[e]; }
  }
}

// fused QKV: one pass over xe (in LDS, stride SRD), weights from global (L2-resident)
__device__ __forceinline__ void qkv_fused(const float* __restrict__ U,
    const float* __restrict__ Wq, const float* __restrict__ bq,
    const float* __restrict__ Wk, const float* __restrict__ bk,
    const float* __restrict__ Wv, const float* __restrict__ bv,
    float4 q[6], float4 k[6], float4 v[6], int tid){
  int d0 = (tid&15)*4, hh = (tid>>4)&7, pb = tid>>7;
  float4 bq4 = *(const float4*)&bq[d0];
  float4 bk4 = *(const float4*)&bk[d0];
  float4 bv4 = *(const float4*)&bv[d0];
  #pragma unroll
  for(int g=0;g<6;g++){ q[g]=bq4; k[g]=bk4; v[g]=bv4; }
  for(int dp=0; dp<64; dp++){
    float4 wq4 = *(const float4*)&Wq[dp*64 + d0];
    float4 wk4 = *(const float4*)&Wk[dp*64 + d0];
    float4 wv4 = *(const float4*)&Wv[dp*64 + d0];
    #pragma unroll
    for(int g=0;g<6;g++){
      float a = U[(pb + g*2)*SRD + hh*64 + dp];
      FMA4(q[g], a, wq4);
      FMA4(k[g], a, wk4);
      FMA4(v[g], a, wv4);
    }
  }
}
__device__ __forceinline__ void qkv_store(float* dst, const float4 v[6], int tid){
  int d0 = (tid&15)*4, hh = (tid>>4)&7, pb = tid>>7;
  #pragma unroll
  for(int g=0;g<6;g++) *(float4*)&dst[(pb+g*2)*SRD + hh*64 + d0] = v[g];
}

// ---------------- fused per-(b,n) transformer + reprojection + residual add ----------------
// LDS: 2x6192 + 1160 = 54176 B -> 3 blocks/CU (was 102912 B -> 1 block/CU)
__global__ __launch_bounds__(TPB,3) void k_attn(
    const float* __restrict__ xe, const float* __restrict__ resid,
    const float* __restrict__ Wq, const float* __restrict__ bq,
    const float* __restrict__ Wk, const float* __restrict__ bk,
    const float* __restrict__ Wv, const float* __restrict__ bv,
    const float* __restrict__ Wfc, const float* __restrict__ bfc,
    const float* __restrict__ g1, const float* __restrict__ b1n,
    const float* __restrict__ g2, const float* __restrict__ b2n,
    const float* __restrict__ Wff1, const float* __restrict__ bff1,
    const float* __restrict__ Wff2, const float* __restrict__ bff2,
    const float* __restrict__ Wrp, const float* __restrict__ brp,
    float* __restrict__ y)
{
  int n = blockIdx.x, b = blockIdx.y;
  __shared__ __align__(16) float U0[12*SRD];
  __shared__ __align__(16) float U1[12*SRD];
  __shared__ __align__(16) float sS[1160];
  int tid = threadIdx.x;
  const float* __restrict__ xeg = xe + ((size_t)b*Nn + n)*6144;

  // xe -> U0 (strided rows)
  for(int i4=tid;i4<1536;i4+=TPB){
    int row = i4>>7, col4 = (i4&127)*4;
    *(float4*)&U0[row*SRD+col4] = *(const float4*)&xeg[row*512+col4];
  }
  __syncthreads();
  float4 qreg[6], kreg[6], vreg[6];
  qkv_fused(U0, Wq,bq, Wk,bk, Wv,bv, qreg,kreg,vreg, tid);
  __syncthreads();                 // all xe reads complete
  qkv_store(U1, qreg, tid);        // qs
  qkv_store(U0, kreg, tid);        // ks (overwrites xe copy)
  __syncthreads();
  // scores [kh][q]
  const float scale = 0.04419417382415922f;   // 1/sqrt(512)
  for(int i=tid;i<1152;i+=TPB){
    int q = i%12, kh = i/12; int h2 = kh&7, k2 = kh>>3;
    const float* qp = &U1[q*SRD + h2*64];
    const float* kp = &U0[k2*SRD + h2*64];
    float s=0.f;
    #pragma unroll
    for(int d4=0; d4<16; d4++){
      float4 a4 = *(const float4*)&qp[d4*4];
      float4 b4 = *(const float4*)&kp[d4*4];
      s += a4.x*b4.x + a4.y*b4.y + a4.z*b4.z + a4.w*b4.w;
    }
    sS[i] = s*scale;
  }
  __syncthreads();                 // scores done reading qs/ks
  qkv_store(U1, vreg, tid);        // vs (overwrites qs)
  // softmax over q (per kh) -- concurrent with v-store
  if(tid<96){
    float mx=-1e30f;
    for(int q=0;q<12;q++) mx = fmaxf(mx, sS[tid*12+q]);
    float sm=0.f;
    for(int q=0;q<12;q++){ float e = __expf(sS[tid*12+q]-mx); sS[tid*12+q]=e; sm+=e; }
    float inv = 1.f/sm;
    for(int q=0;q<12;q++) sS[tid*12+q] *= inv;
  }
  __syncthreads();
  // ao -> U0 (ks dead)
  for(int i=tid;i<6144;i+=TPB){
    int q=i>>9, h2=(i>>6)&7, d=i&63;
    float s=0.f;
    #pragma unroll
    for(int k2=0;k2<12;k2++) s += sS[(k2*8+h2)*12+q]*U1[k2*SRD+h2*64+d];
    U0[q*SRD+(i&511)]=s;
  }
  __syncthreads();
  // fc (+bfc +xe[global]) -> U1 (vs dead)
  {
    int e0 = (tid&127)*4, ph = tid>>7;
    float4 acc[6]; float4 b4 = *(const float4*)&bfc[e0];
    #pragma unroll
    for(int g=0;g<6;g++) acc[g]=b4;
    for(int ep=0; ep<512; ep++){
      float4 w4 = *(const float4*)&Wfc[(size_t)ep*512 + e0];
      #pragma unroll
      for(int g=0;g<6;g++){ float a = U0[(ph*6+g)*SRD + ep]; FMA4(acc[g], a, w4); }
    }
    #pragma unroll
    for(int g=0;g<6;g++){
      int p = ph*6+g;
      float4 xv = *(const float4*)&xeg[p*512+e0];
      acc[g].x += xv.x; acc[g].y += xv.y; acc[g].z += xv.z; acc[g].w += xv.w;
      *(float4*)&U1[p*SRD+e0] = acc[g];
    }
  }
  __syncthreads();
  ln_rows(U1, g1, b1n, tid);     // M in U1
  __syncthreads();
  // ff1 -> U0[0:3072] (relu), ao dead
  {
    int u0 = (tid&63)*4, pg = tid>>6;
    float4 acc[3]; float4 b4 = *(const float4*)&bff1[u0];
    #pragma unroll
    for(int g=0;g<3;g++) acc[g]=b4;
    for(int e=0;e<512;e++){
      float4 w4 = *(const float4*)&Wff1[(size_t)e*256 + u0];
      #pragma unroll
      for(int g=0;g<3;g++){ float a = U1[(pg*3+g)*SRD + e]; FMA4(acc[g], a, w4); }
    }
    #pragma unroll
    for(int g=0;g<3;g++){
      acc[g].x=fmaxf(acc[g].x,0.f); acc[g].y=fmaxf(acc[g].y,0.f);
      acc[g].z=fmaxf(acc[g].z,0.f); acc[g].w=fmaxf(acc[g].w,0.f);
      *(float4*)&U0[(pg*3+g)*256 + u0] = acc[g];
    }
  }
  __syncthreads();
  // ff2 (+bff2 +M) -> regs -> U0 (U)
  {
    int e0 = (tid&127)*4, ph = tid>>7;
    float4 acc[6]; float4 b4 = *(const float4*)&bff2[e0];
    #pragma unroll
    for(int g=0;g<6;g++) acc[g]=b4;
    for(int u=0;u<256;u++){
      float4 w4 = *(const float4*)&Wff2[(size_t)u*512 + e0];
      #pragma unroll
      for(int g=0;g<6;g++){ float a = U0[(ph*6+g)*256 + u]; FMA4(acc[g], a, w4); }
    }
    #pragma unroll
    for(int g=0;g<6;g++){
      int p = ph*6+g;
      float4 m4 = *(const float4*)&U1[p*SRD+e0];
      acc[g].x += m4.x; acc[g].y += m4.y; acc[g].z += m4.z; acc[g].w += m4.w;
    }
    __syncthreads();             // all mid reads done before overwrite
    #pragma unroll
    for(int g=0;g<6;g++){
      int p = ph*6+g;
      *(float4*)&U0[p*SRD+e0] = acc[g];
    }
  }
  __syncthreads();
  ln_rows(U0, g2, b2n, tid);     // U in U0
  __syncthreads();
  // Odat = U + M + xe(global) -> U1 in place
  for(int i4=tid;i4<1536;i4+=TPB){
    int row = i4>>7, col4 = (i4&127)*4; int a = row*SRD+col4;
    float4 uu = *(const float4*)&U0[a];
    float4 mm = *(const float4*)&U1[a];
    float4 xx = *(const float4*)&xeg[row*512+col4];
    mm.x += uu.x+xx.x; mm.y += uu.y+xx.y; mm.z += uu.z+xx.z; mm.w += uu.w+xx.w;
    *(float4*)&U1[a] = mm;
  }
  __syncthreads();
  // y[b,c,n,t] = Odat(reshape [64][96]) @ Wrp + brp + resid[..., 6+t]
  #pragma unroll
  for(int j=0;j<3;j++){
    int i4 = tid + j*TPB;                 // 768 quads
    int c = i4/12, tq = i4%12; int t0 = tq*4;
    float4 acc = *(const float4*)&brp[t0];
    for(int t96=0;t96<96;t96++){
      int f = c*96 + t96;
      float a = U1[(f>>9)*SRD + (f&511)];
      float4 w4 = *(const float4*)&Wrp[t96*48 + t0];
      FMA4(acc, a, w4);
    }
    size_t rb = (((size_t)b*Cc+c)*Nn + n)*Tin + 6 + t0;
    acc.x += resid[rb+0]; acc.y += resid[rb+1]; acc.z += resid[rb+2]; acc.w += resid[rb+3];
    *(float4*)&y[(((size_t)b*Cc+c)*Nn + n)*Tout + t0] = acc;
  }
}

// ---------------- batchnorm ----------------
__global__ __launch_bounds__(TPB) void k_bnstats(const float* __restrict__ y, float* __restrict__ stats){
  int c = blockIdx.x; int tid = threadIdx.x;
  float s=0.f,s2=0.f;
  const int per = Nn*Tout;   // 9936
  for(int idx=tid; idx<Bx*per; idx+=TPB){
    int b = idx/per, r = idx%per;
    float v = y[((size_t)b*Cc+c)*per + r];
    s+=v; s2+=v*v;
  }
  __shared__ float rs[TPB], rs2[TPB];
  rs[tid]=s; rs2[tid]=s2; __syncthreads();
  for(int off=TPB/2; off; off>>=1){ if(tid<off){ rs[tid]+=rs[tid+off]; rs2[tid]+=rs2[tid+off]; } __syncthreads(); }
  if(tid==0){
    float m = rs[0]/(float)(Bx*per);
    float var = rs2[0]/(float)(Bx*per) - m*m;
    stats[c]=m; stats[64+c]=rsqrtf(fmaxf(var,0.f)+EPSF);
  }
}
__global__ __launch_bounds__(TPB) void k_bnout(const float* __restrict__ y, const float* __restrict__ stats,
                                               const float* __restrict__ gbn, const float* __restrict__ bbn,
                                               float* __restrict__ out){
  size_t i = (size_t)blockIdx.x*TPB + threadIdx.x;
  if(i >= (size_t)Bx*Cc*Nn*Tout) return;
  int c = (int)((i/(Nn*Tout))%Cc);
  out[i] = (y[i]-stats[c])*stats[64+c]*gbn[c] + bbn[c];
}

// ---------------- launch ----------------
extern "C" void kernel_launch(void* const* d_in, const int* in_sizes, int n_in,
                              void* d_out, int out_size, void* d_ws, size_t ws_size,
                              hipStream_t stream) {
  const float* x      = (const float*)d_in[0];
  const float* adj    = (const float*)d_in[1];
  const float* Wconv1 = (const float*)d_in[2];
  const float* bconv1 = (const float*)d_in[3];
  const float* gT     = (const float*)d_in[4];
  const float* bT     = (const float*)d_in[5];
  const float* gS     = (const float*)d_in[6];
  const float* bS     = (const float*)d_in[7];
  const float* Wtime  = (const float*)d_in[8];
  const float* btime  = (const float*)d_in[9];
  const float* wq1    = (const float*)d_in[10];
  const float* wv1    = (const float*)d_in[11];
  const float* bias1  = (const float*)d_in[12];
  const float* wq2    = (const float*)d_in[13];
  const float* wv2    = (const float*)d_in[14];
  const float* bias2  = (const float*)d_in[15];
  const float* Wmlp   = (const float*)d_in[16];
  const float* bmlp   = (const float*)d_in[17];
  const float* embT   = (const float*)d_in[18];
  const float* Wq     = (const float*)d_in[19];
  const float* bq     = (const float*)d_in[20];
  const float* Wk     = (const float*)d_in[21];
  const float* bk     = (const float*)d_in[22];
  const float* Wv     = (const float*)d_in[23];
  const float* bv     = (const float*)d_in[24];
  const float* Wfc    = (const float*)d_in[25];
  const float* bfc    = (const float*)d_in[26];
  const float* g1     = (const float*)d_in[27];
  const float* b1n    = (const float*)d_in[28];
  const float* g2     = (const float*)d_in[29];
  const float* b2n    = (const float*)d_in[30];
  const float* Wff1   = (const float*)d_in[31];
  const float* bff1   = (const float*)d_in[32];
  const float* Wff2   = (const float*)d_in[33];
  const float* bff2   = (const float*)d_in[34];
  const float* Wrp    = (const float*)d_in[35];
  const float* brp    = (const float*)d_in[36];
  const float* gbn    = (const float*)d_in[37];
  const float* bbn    = (const float*)d_in[38];

  float* ws = (float*)d_ws;
  float* RESID = ws + O_RESID;
  float* LNTM  = ws + O_LNTM;
  float* LNTR  = ws + O_LNTR;
  float* LNSM  = ws + O_LNSM;
  float* LNSR  = ws + O_LNSR;
  float* XCAT  = ws + O_XCAT;
  float* RA    = ws + O_XCAT;    // overlays XCAT after it is consumed
  float* RB    = ws + O_RB;
  float* H     = ws + O_H;
  float* GACC  = ws + O_GACC;
  float* GG    = ws + O_GG;
  float* Y     = ws + O_GG;      // overlays GG after xe built
  float* XE    = ws + O_XE;
  float* WTT   = ws + O_WTT;
  float* WTM   = ws + O_WTM;
  float* BNST  = ws + O_BNST;

  k_residual<<<dim3(Nn,Bx),TPB,0,stream>>>(x, Wconv1, bconv1, RESID);
  k_lnT<<<(Bx*Cc*Nn)/TPB,TPB,0,stream>>>(RESID, LNTM, LNTR);
  k_lnS<<<(Bx*Cc*Tin)/TPB,TPB,0,stream>>>(RESID, LNSM, LNSR);
  k_xcat<<<(Bx*192*Nn*Tin)/TPB,TPB,0,stream>>>(RESID, LNTM, LNTR, LNSM, LNSR, gT,bT,gS,bS, XCAT);
  k_wt<<<(128*192*3+TPB-1)/TPB,TPB,0,stream>>>(Wtime, WTT, 128, 192);
  k_wt<<<(128*384*3+TPB-1)/TPB,TPB,0,stream>>>(Wmlp,  WTM, 128, 384);
  k_timeconv<<<dim3(Nn,Bx),TPB,0,stream>>>(XCAT, WTT, btime, H);

  const int NTILE = (NP+63)/64;   // 169
  for(int i=0;i<3;i++){
    k_gcs<<<dim3(NTILE,1,Bx),TPB,0,stream>>>(H,  wq1+(size_t)i*Kb*64*64,  wv1+(size_t)i*Kb*64*64,  RA, 64);
    k_agg<1><<<dim3(64,Bx),TPB,0,stream>>>(RA, adj+(size_t)i*Nn*Nn, bias1+(size_t)i*64,  RB, 64);
    k_gcs<<<dim3(NTILE,2,Bx),TPB,0,stream>>>(RB, wq2+(size_t)i*Kb*64*128, wv2+(size_t)i*Kb*64*128, RA, 128);
    k_agg<0><<<dim3(128,Bx),TPB,0,stream>>>(RA, adj+(size_t)i*Nn*Nn, bias2+(size_t)i*128, RB, 128);
    k_mlpacc<<<dim3(Nn,Bx),TPB,0,stream>>>(RB, WTM, GACC, i);
  }
  k_glu2<<<(Bx*Cc*Nn*Tout)/TPB,TPB,0,stream>>>(GACC, bmlp, GG);
  k_xe<<<(Bx*1271808)/TPB,TPB,0,stream>>>(GG, embT, XE);
  k_attn<<<dim3(Nn,Bx),TPB,0,stream>>>(XE, RESID, Wq,bq,Wk,bk,Wv,bv,Wfc,bfc,g1,b1n,g2,b2n,
                                       Wff1,bff1,Wff2,bff2,Wrp,brp, Y);
  k_bnstats<<<64,TPB,0,stream>>>(Y, BNST);
  k_bnout<<<(Bx*Cc*Nn*Tout)/TPB,TPB,0,stream>>>(Y, BNST, gbn, bbn, (float*)d_out);
}

// Round 5
// 2984.282 us; speedup vs baseline: 1.5252x; 1.4056x over previous
//
#include <hip/hip_runtime.h>
#include <hip/hip_bf16.h>

#define TPB 256

constexpr int Bx = 8, Cc = 64, Nn = 207, Tin = 54, Kb = 8;
constexpr int LP = 52, NP = Nn * LP;     // time padded 50->52, flattened node*time positions
constexpr int NPa = 10816;               // NP rounded up to 169*64 for MFMA tiles
constexpr int L50 = 50, Tout = 48;
constexpr int Ee = 512, Pn = 12;
constexpr float EPSF = 1e-5f;
constexpr int SRD = 516;                 // padded row stride for 512-wide LDS rows (bank-conflict break)

// ---------------- workspace layout (floats) ----------------
// ws_size is 256 MiB = 67,108,864 floats; proven-safe peak usage = 65,350,784 floats.
constexpr size_t O_RESID = 0;                                   // [B][64][207][54]
constexpr size_t O_LNTM  = O_RESID + (size_t)Bx*Cc*Nn*Tin;
constexpr size_t O_LNTR  = O_LNTM  + (size_t)Bx*Cc*Nn;
constexpr size_t O_LNSM  = O_LNTR  + (size_t)Bx*Cc*Nn;
constexpr size_t O_LNSR  = O_LNSM  + (size_t)Bx*Cc*Tin;
constexpr size_t O_XCAT  = O_LNSR  + (size_t)Bx*Cc*Tin;         // [B][192][207][54]; later reused as RA [B][128][NP] + bf16 tail
constexpr size_t O_RB    = O_XCAT  + (size_t)Bx*192*Nn*Tin;     // [B][128][NP]
constexpr size_t O_H     = O_RB    + (size_t)Bx*128*NP;         // [B][64][NP]
constexpr size_t O_GACC  = O_H     + (size_t)Bx*64*NP;          // [B][128][207][48]
constexpr size_t O_GG    = O_GACC  + (size_t)Bx*128*Nn*Tout;    // [B][64][207][48]; later reused as Y
constexpr size_t O_XE    = O_GG    + (size_t)Bx*64*Nn*Tout;     // [B][207][12][512]
constexpr size_t O_WTT   = O_XE    + (size_t)Bx*Nn*Pn*Ee;       // transposed W_time 128*192*3
constexpr size_t O_WTM   = O_WTT   + (size_t)128*192*3;         // transposed W_mlp 128*384*3
constexpr size_t O_BNST  = O_WTM   + (size_t)128*384*3;         // 128
// bf16 buffers aliased into the dead tail of XCAT (XCAT dead after timeconv; RA uses first Bx*128*NP floats)
constexpr size_t O_HT    = O_XCAT + (size_t)Bx*128*NP;          // ushort[Bx][NPa][64]
constexpr size_t O_WQ1B  = O_HT   + (size_t)Bx*NPa*64/2;        // ushort[24][64][64]
constexpr size_t O_WV1B  = O_WQ1B + (size_t)24*64*64/2;
constexpr size_t O_WQ2B  = O_WV1B + (size_t)24*64*64/2;         // ushort[24][128][64]
constexpr size_t O_WV2B  = O_WQ2B + (size_t)24*128*64/2;
constexpr size_t O_RBT   = O_WV2B + (size_t)24*128*64/2;        // ushort[Bx][NPa][64]; ends at O_XCAT+16,855,040 < O_XCAT+17,169,408

#define FMA4(acc, sA_, vB_) { (acc).x += (sA_)*(vB_).x; (acc).y += (sA_)*(vB_).y; (acc).z += (sA_)*(vB_).z; (acc).w += (sA_)*(vB_).w; }

typedef __attribute__((ext_vector_type(8))) short bf16x8;
typedef __attribute__((ext_vector_type(4))) float f32x4;

__device__ __forceinline__ float sigm(float x){ return 1.0f/(1.0f+__expf(-x)); }
__device__ __forceinline__ ushort f2bf(float x){ __hip_bfloat16 h = __float2bfloat16(x); return *(ushort*)&h; }

// ---------------- residual = W_conv1 @ x + b ----------------
__global__ __launch_bounds__(TPB) void k_residual(const float* __restrict__ x, const float* __restrict__ W,
                                                  const float* __restrict__ bias, float* __restrict__ out){
  int n = blockIdx.x, b = blockIdx.y;
  __shared__ __align__(16) float sX[Cc][Tin];
  __shared__ __align__(16) float sW[Cc*Cc];
  int tid = threadIdx.x;
  for(int i=tid;i<Cc*Tin;i+=TPB){ int c=i/Tin, l=i%Tin; sX[c][l] = x[((size_t)(b*Cc+c)*Nn+n)*Tin+l]; }
  for(int i=tid;i<Cc*Cc;i+=TPB) sW[i]=W[i];
  __syncthreads();
  for(int i=tid;i<Cc*Tin;i+=TPB){
    int o=i/Tin, l=i%Tin; float acc=bias[o];
    #pragma unroll 8
    for(int c=0;c<Cc;c++) acc += sW[o*Cc+c]*sX[c][l];
    out[((size_t)(b*Cc+o)*Nn+n)*Tin+l]=acc;
  }
}

// ---------------- LN stats ----------------
__global__ __launch_bounds__(TPB) void k_lnT(const float* __restrict__ r, float* __restrict__ mean, float* __restrict__ rstd){
  int row = blockIdx.x*TPB + threadIdx.x;
  if(row >= Bx*Cc*Nn) return;
  const float* p = r + (size_t)row*Tin;
  float s=0.f,s2=0.f;
  for(int l=0;l<Tin;l++){ float v=p[l]; s+=v; s2+=v*v; }
  float m=s*(1.f/Tin); float var=s2*(1.f/Tin)-m*m;
  mean[row]=m; rstd[row]=rsqrtf(fmaxf(var,0.f)+EPSF);
}
__global__ __launch_bounds__(TPB) void k_lnS(const float* __restrict__ r, float* __restrict__ mean, float* __restrict__ rstd){
  int row = blockIdx.x*TPB + threadIdx.x;       // (b*Cc+c)*Tin + l
  if(row >= Bx*Cc*Tin) return;
  int l = row % Tin; int bc = row / Tin;
  const float* p = r + (size_t)bc*Nn*Tin + l;
  float s=0.f,s2=0.f;
  for(int n=0;n<Nn;n++){ float v=p[(size_t)n*Tin]; s+=v; s2+=v*v; }
  float m=s*(1.f/Nn); float var=s2*(1.f/Nn)-m*m;
  mean[row]=m; rstd[row]=rsqrtf(fmaxf(var,0.f)+EPSF);
}

// ---------------- xcat = [resid, LN_T, LN_S] ----------------
__global__ __launch_bounds__(TPB) void k_xcat(const float* __restrict__ r, const float* __restrict__ tm, const float* __restrict__ tr,
                                              const float* __restrict__ sm, const float* __restrict__ sr,
                                              const float* __restrict__ gT, const float* __restrict__ bT,
                                              const float* __restrict__ gS, const float* __restrict__ bS,
                                              float* __restrict__ out){
  size_t i = (size_t)blockIdx.x*TPB + threadIdx.x;
  if(i >= (size_t)Bx*192*Nn*Tin) return;
  int l = (int)(i % Tin); size_t r1 = i / Tin; int n = (int)(r1 % Nn); size_t r2 = r1 / Nn;
  int ci = (int)(r2 % 192); int b = (int)(r2 / 192);
  int c = ci & 63; int grp = ci >> 6;
  float v = r[((size_t)(b*Cc+c)*Nn+n)*Tin+l];
  float o;
  if(grp==0) o = v;
  else if(grp==1){ int row=(b*Cc+c)*Nn+n; o = (v-tm[row])*tr[row]*gT[l] + bT[l]; }
  else { int row=(b*Cc+c)*Tin+l; o = (v-sm[row])*sr[row]*gS[n] + bS[n]; }
  out[i]=o;
}

// ---------------- weight transpose: W[o][ci][3] -> WT[(ci*3+kt)*O + o] ----------------
__global__ __launch_bounds__(TPB) void k_wt(const float* __restrict__ W, float* __restrict__ WT, int O, int CI){
  int idx = blockIdx.x*TPB + threadIdx.x;
  int total = O*CI*3;
  if(idx>=total) return;
  int kt = idx%3; int r = idx/3; int ci = r%CI; int o = r/CI;
  WT[(size_t)(ci*3+kt)*O + o] = W[idx];
}

// ---------------- gcn weight convert: W[slk][C][D] f32 -> WT[slk][D][C] bf16 ----------------
__global__ __launch_bounds__(TPB) void k_wcvt(const float* __restrict__ W, ushort* __restrict__ WT,
                                              int SLK, int C, int D){
  int i = blockIdx.x*TPB + threadIdx.x;
  if(i >= SLK*C*D) return;
  int d = i % D; int r = i / D; int c = r % C; int slk = r / C;
  WT[((size_t)slk*D + d)*C + c] = f2bf(W[i]);
}

// ---------------- activation transpose+convert: X f32 [b][C][NP] -> XT bf16 [b][NPa][C] ----------------
template<int C>
__global__ __launch_bounds__(TPB) void k_t2bf(const float* __restrict__ X, ushort* __restrict__ XT){
  int p0 = blockIdx.x*64, b = blockIdx.y;
  int tid = threadIdx.x;
  __shared__ __align__(16) float sT[64][65];
  for(int cc=0; cc<C; cc+=64){
    if(cc) __syncthreads();
    for(int i=tid;i<4096;i+=TPB){ int c=i>>6, col=i&63; int p=p0+col;
      sT[c][col] = (p<NP) ? X[((size_t)(b*C+cc+c))*NP + p] : 0.f; }
    __syncthreads();
    for(int i=tid;i<512;i+=TPB){
      int row=i>>3, c8=(i&7)<<3;
      ushort u[8];
      #pragma unroll
      for(int j=0;j<8;j++) u[j] = f2bf(sT[c8+j][row]);
      *(uint4*)&XT[((size_t)b*NPa + p0 + row)*C + cc + c8] = *(uint4*)u;
    }
  }
}

// ---------------- dilated time conv (dil=2) + GLU -> h [B][64][NP] ----------------
__global__ __launch_bounds__(TPB) void k_timeconv(const float* __restrict__ xcat, const float* __restrict__ WT,
                                                  const float* __restrict__ bias, float* __restrict__ h){
  int n = blockIdx.x, b = blockIdx.y;
  __shared__ __align__(16) float sX[192][60];
  __shared__ __align__(16) float sP[128][L50];
  int tid = threadIdx.x;
  for(int i=tid;i<192*60;i+=TPB){ int c=i/60, l=i%60;
    sX[c][l] = (l<Tin) ? xcat[((size_t)(b*192+c)*Nn+n)*Tin+l] : 0.f; }
  __syncthreads();
  int o = tid & 127, half = tid >> 7;
  int t0 = half*28;
  float acc[28];
  #pragma unroll
  for(int j=0;j<28;j++) acc[j]=0.f;
  for(int ci=0;ci<192;ci++){
    float w0 = WT[(size_t)(ci*3+0)*128+o];
    float w1 = WT[(size_t)(ci*3+1)*128+o];
    float w2 = WT[(size_t)(ci*3+2)*128+o];
    float sv[32];
    #pragma unroll
    for(int m=0;m<32;m++) sv[m]=sX[ci][t0+m];
    #pragma unroll
    for(int j=0;j<28;j++) acc[j] += w0*sv[j] + w1*sv[j+2] + w2*sv[j+4];
  }
  float bb = bias[o];
  int nlive = half ? 22 : 28;
  for(int j=0;j<nlive;j++) sP[o][t0+j] = acc[j]+bb;
  __syncthreads();
  for(int i=tid;i<Cc*LP;i+=TPB){
    int c=i/LP, t=i%LP;
    float v = 0.f;
    if(t<L50) v = tanhf(sP[c][t]) * sigm(sP[c+64][t]);
    h[((size_t)b*Cc+c)*NP + (size_t)n*LP + t] = v;
  }
}

// ---------------- gated multi-basis GCN einsum via MFMA ----------------
// S[b,d,p] = sum_k sigmoid(q_k[d,p]) * v_k[d,p],  q_k = Wq_k^T X, v_k = Wv_k^T X
// XT: bf16 [b][NPa][64] (X^T, zero-padded rows); wqT/wvT: bf16 [8][D][64] (W^T). Input C=64 always.
template<int D>
__global__ __launch_bounds__(TPB) void k_gcs_mfma(const ushort* __restrict__ XT,
    const ushort* __restrict__ wqT, const ushort* __restrict__ wvT,
    float* __restrict__ S){
  int p0 = blockIdx.x*64;
  int b = blockIdx.z;
  int tid = threadIdx.x;
  int lane = tid & 63;
  int d0 = blockIdx.y*64 + ((tid>>6)<<4);      // wave -> 16-wide d strip
  __shared__ __align__(16) ushort sX[64*64];   // [p][c], XOR-swizzled (c8 ^ (row&7)<<3)
  for(int i=tid;i<512;i+=TPB){
    int row=i>>3, c8=(i&7)<<3;
    uint4 v = *(const uint4*)&XT[((size_t)b*NPa + p0 + row)*64 + c8];
    *(uint4*)&sX[row*64 + (c8 ^ ((row&7)<<3))] = v;
  }
  __syncthreads();
  int r15 = lane & 15, hi = lane >> 4;
  // B fragments (X), independent of basis k: [pt][kk]
  bf16x8 bf[4][2];
  #pragma unroll
  for(int pt=0;pt<4;pt++){
    int row = pt*16 + r15;
    int sw = (row&7)<<3;
    int cu0 = hi*8;
    bf[pt][0] = *(const bf16x8*)&sX[row*64 + (cu0 ^ sw)];
    bf[pt][1] = *(const bf16x8*)&sX[row*64 + ((cu0+32) ^ sw)];
  }
  f32x4 acc[4];
  #pragma unroll
  for(int pt=0;pt<4;pt++){ acc[pt][0]=0.f; acc[pt][1]=0.f; acc[pt][2]=0.f; acc[pt][3]=0.f; }
  const ushort* wqp = wqT + ((size_t)(d0 + r15))*64 + hi*8;
  const ushort* wvp = wvT + ((size_t)(d0 + r15))*64 + hi*8;
  for(int k=0;k<Kb;k++){
    bf16x8 aq0 = *(const bf16x8*)&wqp[0];
    bf16x8 aq1 = *(const bf16x8*)&wqp[32];
    bf16x8 av0 = *(const bf16x8*)&wvp[0];
    bf16x8 av1 = *(const bf16x8*)&wvp[32];
    wqp += (size_t)D*64; wvp += (size_t)D*64;
    #pragma unroll
    for(int pt=0;pt<4;pt++){
      f32x4 q; q[0]=0.f;q[1]=0.f;q[2]=0.f;q[3]=0.f;
      f32x4 v; v[0]=0.f;v[1]=0.f;v[2]=0.f;v[3]=0.f;
      q = __builtin_amdgcn_mfma_f32_16x16x32_bf16(aq0, bf[pt][0], q, 0,0,0);
      q = __builtin_amdgcn_mfma_f32_16x16x32_bf16(aq1, bf[pt][1], q, 0,0,0);
      v = __builtin_amdgcn_mfma_f32_16x16x32_bf16(av0, bf[pt][0], v, 0,0,0);
      v = __builtin_amdgcn_mfma_f32_16x16x32_bf16(av1, bf[pt][1], v, 0,0,0);
      #pragma unroll
      for(int i=0;i<4;i++) acc[pt][i] += v[i]*sigm(q[i]);
    }
  }
  #pragma unroll
  for(int pt=0;pt<4;pt++){
    int p = p0 + pt*16 + r15;
    if(p < NP){
      #pragma unroll
      for(int i=0;i<4;i++){
        int d = d0 + hi*4 + i;
        S[((size_t)b*D + d)*NP + p] = acc[pt][i];
      }
    }
  }
}

// ---------------- adjacency aggregation: out[b,d,k2,l] = act(sum_n adj[n][k2]*S[b,d,n,l] + bias[d]) ----------------
template<int RELU>
__global__ __launch_bounds__(TPB) void k_agg(const float* __restrict__ S, const float* __restrict__ adj,
                                             const float* __restrict__ bias, float* __restrict__ Out, int D){
  int d = blockIdx.x, b = blockIdx.y;
  __shared__ __align__(16) float sAdj[69][208];
  __shared__ __align__(16) float sSm[69][52];
  int tid = threadIdx.x;
  int kq[3], lq[3], valid[3];
  #pragma unroll
  for(int m=0;m<3;m++){ int mt = tid + m*TPB; valid[m] = (mt<676); kq[m] = mt/13; lq[m] = mt%13; }
  float acc[3][4][4];
  #pragma unroll
  for(int m=0;m<3;m++)
    #pragma unroll
    for(int a=0;a<4;a++){ acc[m][a][0]=0;acc[m][a][1]=0;acc[m][a][2]=0;acc[m][a][3]=0; }
  const float* Sp = S + ((size_t)b*D + d)*NP;
  for(int ch=0; ch<3; ch++){
    int n0 = ch*69;
    __syncthreads();
    for(int i=tid;i<69*208;i+=TPB){ int nn=i/208, k2=i%208;
      sAdj[nn][k2] = (k2<Nn) ? adj[(size_t)(n0+nn)*Nn + k2] : 0.f; }
    for(int i=tid;i<69*52;i+=TPB){ int nn=i/52, l=i%52;
      sSm[nn][l] = Sp[(size_t)(n0+nn)*LP + l]; }
    __syncthreads();
    for(int nn=0;nn<69;nn++){
      #pragma unroll
      for(int m=0;m<3;m++){
        if(!valid[m]) continue;
        float4 a4 = *(const float4*)&sAdj[nn][kq[m]*4];
        float4 s4 = *(const float4*)&sSm[nn][lq[m]*4];
        float as[4]={a4.x,a4.y,a4.z,a4.w};
        float ss[4]={s4.x,s4.y,s4.z,s4.w};
        #pragma unroll
        for(int ki=0;ki<4;ki++)
          #pragma unroll
          for(int li=0;li<4;li++) acc[m][ki][li] += as[ki]*ss[li];
      }
    }
  }
  float bb = bias[d];
  #pragma unroll
  for(int m=0;m<3;m++){
    if(!valid[m]) continue;
    #pragma unroll
    for(int ki=0;ki<4;ki++){
      int k2 = kq[m]*4+ki;
      if(k2>=Nn) continue;
      #pragma unroll
      for(int li=0;li<4;li++){
        int l = lq[m]*4+li;
        float v = acc[m][ki][li] + bb;
        if(RELU) v = fmaxf(v, 0.f);
        Out[(((size_t)b*D+d)*Nn + k2)*LP + l] = v;
      }
    }
  }
}

// ---------------- MLP conv accumulate (dil=1), per layer ----------------
__global__ __launch_bounds__(TPB) void k_mlpacc(const float* __restrict__ Outs, const float* __restrict__ WT,
                                                float* __restrict__ gacc, int layer){
  int n = blockIdx.x, b = blockIdx.y;
  __shared__ __align__(16) float sO[128][52];
  int tid = threadIdx.x;
  for(int i=tid;i<128*52;i+=TPB){ int c=i/52, l=i%52;
    sO[c][l] = Outs[(((size_t)b*128+c)*Nn + n)*LP + l]; }
  __syncthreads();
  int o = tid & 127, half = tid >> 7;
  int t0 = half*24;
  float acc[24];
  #pragma unroll
  for(int j=0;j<24;j++) acc[j]=0.f;
  const float* wt = WT + (size_t)layer*128*3*128;
  for(int ci=0;ci<128;ci++){
    float w0 = wt[(size_t)(ci*3+0)*128+o];
    float w1 = wt[(size_t)(ci*3+1)*128+o];
    float w2 = wt[(size_t)(ci*3+2)*128+o];
    float sv[26];
    #pragma unroll
    for(int m=0;m<26;m++) sv[m]=sO[ci][t0+m];
    #pragma unroll
    for(int j=0;j<24;j++) acc[j] += w0*sv[j] + w1*sv[j+1] + w2*sv[j+2];
  }
  size_t base = (((size_t)b*128+o)*Nn + n)*Tout + t0;
  if(layer==0){ for(int j=0;j<24;j++) gacc[base+j] = acc[j]; }
  else       { for(int j=0;j<24;j++) gacc[base+j] += acc[j]; }
}

// ---------------- GLU over accumulated MLP conv ----------------
__global__ __launch_bounds__(TPB) void k_glu2(const float* __restrict__ gacc, const float* __restrict__ bm, float* __restrict__ gg){
  size_t i = (size_t)blockIdx.x*TPB + threadIdx.x;
  if(i >= (size_t)Bx*Cc*Nn*Tout) return;
  int t = (int)(i % Tout); size_t r = i / Tout; int n = (int)(r % Nn); size_t r2 = r / Nn;
  int c = (int)(r2 % Cc); int b = (int)(r2 / Cc);
  size_t i1 = (((size_t)b*128+c)*Nn+n)*Tout + t;
  size_t i2 = (((size_t)b*128+c+64)*Nn+n)*Tout + t;
  float a = gacc[i1]+bm[c], b2 = gacc[i2]+bm[c+64];
  gg[i] = tanhf(a)*sigm(b2);
}

// ---------------- patch scramble + emb: xe[b, n2*6144 + p2*512 + e] ----------------
__global__ __launch_bounds__(TPB) void k_xe(const float* __restrict__ gg, const float* __restrict__ emb, float* __restrict__ xe){
  size_t i = (size_t)blockIdx.x*TPB + threadIdx.x;
  if(i >= (size_t)Bx*1271808) return;
  int b = (int)(i / 1271808);
  int off = (int)(i % 1271808);
  int c = off / 19872; int r = off % 19872;
  int n = r / 96; int r2 = r % 96;
  int p = r2 >> 3; int j = r2 & 7;
  int t = p*4 + j;
  float v = 0.f;
  if(t < Tout) v = gg[(((size_t)b*Cc+c)*Nn + n)*Tout + t];
  int e = off & 511; int p2 = (off >> 9) % 12;
  xe[i] = v + emb[(size_t)p2*Ee + e];
}

// ---------------- per-row LN helper (rows of 512, stride SRD, in LDS) ----------------
__device__ __forceinline__ void ln_rows(float* buf, const float* __restrict__ g, const float* __restrict__ be, int tid){
  int lane = tid & 63, wv = tid >> 6;
  for(int r = wv; r < 12; r += 4){
    float s=0.f, s2=0.f;
    #pragma unroll
    for(int j=0;j<8;j++){ float v = buf[r*SRD + j*64 + lane]; s+=v; s2+=v*v; }
    #pragma unroll
    for(int off=32; off; off>>=1){ s += __shfl_xor(s,off); s2 += __shfl_xor(s2,off); }
    float m = s*(1.f/512.f);
    float rstd = rsqrtf(fmaxf(s2*(1.f/512.f)-m*m, 0.f)+EPSF);
    #pragma unroll
    for(int j=0;j<8;j++){ int e = j*64+lane; float v = buf[r*SRD+e];
      buf[r*SRD+e] = (v-m)*rstd*g[e] + be[e]; }
  }
}

// fused QKV: one pass over xe (in LDS, stride SRD), weights from global (L2-resident)
__device__ __forceinline__ void qkv_fused(const float* __restrict__ U,
    const float* __restrict__ Wq, const float* __restrict__ bq,
    const float* __restrict__ Wk, const float* __restrict__ bk,
    const float* __restrict__ Wv, const float* __restrict__ bv,
    float4 q[6], float4 k[6], float4 v[6], int tid){
  int d0 = (tid&15)*4, hh = (tid>>4)&7, pb = tid>>7;
  float4 bq4 = *(const float4*)&bq[d0];
  float4 bk4 = *(const float4*)&bk[d0];
  float4 bv4 = *(const float4*)&bv[d0];
  #pragma unroll
  for(int g=0;g<6;g++){ q[g]=bq4; k[g]=bk4; v[g]=bv4; }
  for(int dp=0; dp<64; dp++){
    float4 wq4 = *(const float4*)&Wq[dp*64 + d0];
    float4 wk4 = *(const float4*)&Wk[dp*64 + d0];
    float4 wv4 = *(const float4*)&Wv[dp*64 + d0];
    #pragma unroll
    for(int g=0;g<6;g++){
      float a = U[(pb + g*2)*SRD + hh*64 + dp];
      FMA4(q[g], a, wq4);
      FMA4(k[g], a, wk4);
      FMA4(v[g], a, wv4);
    }
  }
}
__device__ __forceinline__ void qkv_store(float* dst, const float4 v[6], int tid){
  int d0 = (tid&15)*4, hh = (tid>>4)&7, pb = tid>>7;
  #pragma unroll
  for(int g=0;g<6;g++) *(float4*)&dst[(pb+g*2)*SRD + hh*64 + d0] = v[g];
}

// ---------------- fused per-(b,n) transformer + reprojection + residual add ----------------
__global__ __launch_bounds__(TPB,3) void k_attn(
    const float* __restrict__ xe, const float* __restrict__ resid,
    const float* __restrict__ Wq, const float* __restrict__ bq,
    const float* __restrict__ Wk, const float* __restrict__ bk,
    const float* __restrict__ Wv, const float* __restrict__ bv,
    const float* __restrict__ Wfc, const float* __restrict__ bfc,
    const float* __restrict__ g1, const float* __restrict__ b1n,
    const float* __restrict__ g2, const float* __restrict__ b2n,
    const float* __restrict__ Wff1, const float* __restrict__ bff1,
    const float* __restrict__ Wff2, const float* __restrict__ bff2,
    const float* __restrict__ Wrp, const float* __restrict__ brp,
    float* __restrict__ y)
{
  int n = blockIdx.x, b = blockIdx.y;
  __shared__ __align__(16) float U0[12*SRD];
  __shared__ __align__(16) float U1[12*SRD];
  __shared__ __align__(16) float sS[1160];
  int tid = threadIdx.x;
  const float* __restrict__ xeg = xe + ((size_t)b*Nn + n)*6144;

  for(int i4=tid;i4<1536;i4+=TPB){
    int row = i4>>7, col4 = (i4&127)*4;
    *(float4*)&U0[row*SRD+col4] = *(const float4*)&xeg[row*512+col4];
  }
  __syncthreads();
  float4 qreg[6], kreg[6], vreg[6];
  qkv_fused(U0, Wq,bq, Wk,bk, Wv,bv, qreg,kreg,vreg, tid);
  __syncthreads();
  qkv_store(U1, qreg, tid);        // qs
  qkv_store(U0, kreg, tid);        // ks
  __syncthreads();
  const float scale = 0.04419417382415922f;   // 1/sqrt(512)
  for(int i=tid;i<1152;i+=TPB){
    int q = i%12, kh = i/12; int h2 = kh&7, k2 = kh>>3;
    const float* qp = &U1[q*SRD + h2*64];
    const float* kp = &U0[k2*SRD + h2*64];
    float s=0.f;
    #pragma unroll
    for(int d4=0; d4<16; d4++){
      float4 a4 = *(const float4*)&qp[d4*4];
      float4 b4 = *(const float4*)&kp[d4*4];
      s += a4.x*b4.x + a4.y*b4.y + a4.z*b4.z + a4.w*b4.w;
    }
    sS[i] = s*scale;
  }
  __syncthreads();
  qkv_store(U1, vreg, tid);        // vs
  if(tid<96){
    float mx=-1e30f;
    for(int q=0;q<12;q++) mx = fmaxf(mx, sS[tid*12+q]);
    float sm=0.f;
    for(int q=0;q<12;q++){ float e = __expf(sS[tid*12+q]-mx); sS[tid*12+q]=e; sm+=e; }
    float inv = 1.f/sm;
    for(int q=0;q<12;q++) sS[tid*12+q] *= inv;
  }
  __syncthreads();
  for(int i=tid;i<6144;i+=TPB){
    int q=i>>9, h2=(i>>6)&7, d=i&63;
    float s=0.f;
    #pragma unroll
    for(int k2=0;k2<12;k2++) s += sS[(k2*8+h2)*12+q]*U1[k2*SRD+h2*64+d];
    U0[q*SRD+(i&511)]=s;
  }
  __syncthreads();
  {
    int e0 = (tid&127)*4, ph = tid>>7;
    float4 acc[6]; float4 b4 = *(const float4*)&bfc[e0];
    #pragma unroll
    for(int g=0;g<6;g++) acc[g]=b4;
    for(int ep=0; ep<512; ep++){
      float4 w4 = *(const float4*)&Wfc[(size_t)ep*512 + e0];
      #pragma unroll
      for(int g=0;g<6;g++){ float a = U0[(ph*6+g)*SRD + ep]; FMA4(acc[g], a, w4); }
    }
    #pragma unroll
    for(int g=0;g<6;g++){
      int p = ph*6+g;
      float4 xv = *(const float4*)&xeg[p*512+e0];
      acc[g].x += xv.x; acc[g].y += xv.y; acc[g].z += xv.z; acc[g].w += xv.w;
      *(float4*)&U1[p*SRD+e0] = acc[g];
    }
  }
  __syncthreads();
  ln_rows(U1, g1, b1n, tid);     // M in U1
  __syncthreads();
  {
    int u0 = (tid&63)*4, pg = tid>>6;
    float4 acc[3]; float4 b4 = *(const float4*)&bff1[u0];
    #pragma unroll
    for(int g=0;g<3;g++) acc[g]=b4;
    for(int e=0;e<512;e++){
      float4 w4 = *(const float4*)&Wff1[(size_t)e*256 + u0];
      #pragma unroll
      for(int g=0;g<3;g++){ float a = U1[(pg*3+g)*SRD + e]; FMA4(acc[g], a, w4); }
    }
    #pragma unroll
    for(int g=0;g<3;g++){
      acc[g].x=fmaxf(acc[g].x,0.f); acc[g].y=fmaxf(acc[g].y,0.f);
      acc[g].z=fmaxf(acc[g].z,0.f); acc[g].w=fmaxf(acc[g].w,0.f);
      *(float4*)&U0[(pg*3+g)*256 + u0] = acc[g];
    }
  }
  __syncthreads();
  {
    int e0 = (tid&127)*4, ph = tid>>7;
    float4 acc[6]; float4 b4 = *(const float4*)&bff2[e0];
    #pragma unroll
    for(int g=0;g<6;g++) acc[g]=b4;
    for(int u=0;u<256;u++){
      float4 w4 = *(const float4*)&Wff2[(size_t)u*512 + e0];
      #pragma unroll
      for(int g=0;g<6;g++){ float a = U0[(ph*6+g)*256 + u]; FMA4(acc[g], a, w4); }
    }
    #pragma unroll
    for(int g=0;g<6;g++){
      int p = ph*6+g;
      float4 m4 = *(const float4*)&U1[p*SRD+e0];
      acc[g].x += m4.x; acc[g].y += m4.y; acc[g].z += m4.z; acc[g].w += m4.w;
    }
    __syncthreads();
    #pragma unroll
    for(int g=0;g<6;g++){
      int p = ph*6+g;
      *(float4*)&U0[p*SRD+e0] = acc[g];
    }
  }
  __syncthreads();
  ln_rows(U0, g2, b2n, tid);     // U in U0
  __syncthreads();
  for(int i4=tid;i4<1536;i4+=TPB){
    int row = i4>>7, col4 = (i4&127)*4; int a = row*SRD+col4;
    float4 uu = *(const float4*)&U0[a];
    float4 mm = *(const float4*)&U1[a];
    float4 xx = *(const float4*)&xeg[row*512+col4];
    mm.x += uu.x+xx.x; mm.y += uu.y+xx.y; mm.z += uu.z+xx.z; mm.w += uu.w+xx.w;
    *(float4*)&U1[a] = mm;
  }
  __syncthreads();
  #pragma unroll
  for(int j=0;j<3;j++){
    int i4 = tid + j*TPB;
    int c = i4/12, tq = i4%12; int t0 = tq*4;
    float4 acc = *(const float4*)&brp[t0];
    for(int t96=0;t96<96;t96++){
      int f = c*96 + t96;
      float a = U1[(f>>9)*SRD + (f&511)];
      float4 w4 = *(const float4*)&Wrp[t96*48 + t0];
      FMA4(acc, a, w4);
    }
    size_t rb = (((size_t)b*Cc+c)*Nn + n)*Tin + 6 + t0;
    acc.x += resid[rb+0]; acc.y += resid[rb+1]; acc.z += resid[rb+2]; acc.w += resid[rb+3];
    *(float4*)&y[(((size_t)b*Cc+c)*Nn + n)*Tout + t0] = acc;
  }
}

// ---------------- batchnorm ----------------
__global__ __launch_bounds__(TPB) void k_bnstats(const float* __restrict__ y, float* __restrict__ stats){
  int c = blockIdx.x; int tid = threadIdx.x;
  float s=0.f,s2=0.f;
  const int per = Nn*Tout;   // 9936
  for(int idx=tid; idx<Bx*per; idx+=TPB){
    int b = idx/per, r = idx%per;
    float v = y[((size_t)b*Cc+c)*per + r];
    s+=v; s2+=v*v;
  }
  __shared__ float rs[TPB], rs2[TPB];
  rs[tid]=s; rs2[tid]=s2; __syncthreads();
  for(int off=TPB/2; off; off>>=1){ if(tid<off){ rs[tid]+=rs[tid+off]; rs2[tid]+=rs2[tid+off]; } __syncthreads(); }
  if(tid==0){
    float m = rs[0]/(float)(Bx*per);
    float var = rs2[0]/(float)(Bx*per) - m*m;
    stats[c]=m; stats[64+c]=rsqrtf(fmaxf(var,0.f)+EPSF);
  }
}
__global__ __launch_bounds__(TPB) void k_bnout(const float* __restrict__ y, const float* __restrict__ stats,
                                               const float* __restrict__ gbn, const float* __restrict__ bbn,
                                               float* __restrict__ out){
  size_t i = (size_t)blockIdx.x*TPB + threadIdx.x;
  if(i >= (size_t)Bx*Cc*Nn*Tout) return;
  int c = (int)((i/(Nn*Tout))%Cc);
  out[i] = (y[i]-stats[c])*stats[64+c]*gbn[c] + bbn[c];
}

// ---------------- launch ----------------
extern "C" void kernel_launch(void* const* d_in, const int* in_sizes, int n_in,
                              void* d_out, int out_size, void* d_ws, size_t ws_size,
                              hipStream_t stream) {
  const float* x      = (const float*)d_in[0];
  const float* adj    = (const float*)d_in[1];
  const float* Wconv1 = (const float*)d_in[2];
  const float* bconv1 = (const float*)d_in[3];
  const float* gT     = (const float*)d_in[4];
  const float* bT     = (const float*)d_in[5];
  const float* gS     = (const float*)d_in[6];
  const float* bS     = (const float*)d_in[7];
  const float* Wtime  = (const float*)d_in[8];
  const float* btime  = (const float*)d_in[9];
  const float* wq1    = (const float*)d_in[10];
  const float* wv1    = (const float*)d_in[11];
  const float* bias1  = (const float*)d_in[12];
  const float* wq2    = (const float*)d_in[13];
  const float* wv2    = (const float*)d_in[14];
  const float* bias2  = (const float*)d_in[15];
  const float* Wmlp   = (const float*)d_in[16];
  const float* bmlp   = (const float*)d_in[17];
  const float* embT   = (const float*)d_in[18];
  const float* Wq     = (const float*)d_in[19];
  const float* bq     = (const float*)d_in[20];
  const float* Wk     = (const float*)d_in[21];
  const float* bk     = (const float*)d_in[22];
  const float* Wv     = (const float*)d_in[23];
  const float* bv     = (const float*)d_in[24];
  const float* Wfc    = (const float*)d_in[25];
  const float* bfc    = (const float*)d_in[26];
  const float* g1     = (const float*)d_in[27];
  const float* b1n    = (const float*)d_in[28];
  const float* g2     = (const float*)d_in[29];
  const float* b2n    = (const float*)d_in[30];
  const float* Wff1   = (const float*)d_in[31];
  const float* bff1   = (const float*)d_in[32];
  const float* Wff2   = (const float*)d_in[33];
  const float* bff2   = (const float*)d_in[34];
  const float* Wrp    = (const float*)d_in[35];
  const float* brp    = (const float*)d_in[36];
  const float* gbn    = (const float*)d_in[37];
  const float* bbn    = (const float*)d_in[38];

  float* ws = (float*)d_ws;
  float* RESID = ws + O_RESID;
  float* LNTM  = ws + O_LNTM;
  float* LNTR  = ws + O_LNTR;
  float* LNSM  = ws + O_LNSM;
  float* LNSR  = ws + O_LNSR;
  float* XCAT  = ws + O_XCAT;
  float* RA    = ws + O_XCAT;    // overlays XCAT after it is consumed
  float* RB    = ws + O_RB;
  float* H     = ws + O_H;
  float* GACC  = ws + O_GACC;
  float* GG    = ws + O_GG;
  float* Y     = ws + O_GG;      // overlays GG after xe built
  float* XE    = ws + O_XE;
  float* WTT   = ws + O_WTT;
  float* WTM   = ws + O_WTM;
  float* BNST  = ws + O_BNST;
  ushort* HT   = (ushort*)(ws + O_HT);
  ushort* WQ1B = (ushort*)(ws + O_WQ1B);
  ushort* WV1B = (ushort*)(ws + O_WV1B);
  ushort* WQ2B = (ushort*)(ws + O_WQ2B);
  ushort* WV2B = (ushort*)(ws + O_WV2B);
  ushort* RBT  = (ushort*)(ws + O_RBT);

  k_residual<<<dim3(Nn,Bx),TPB,0,stream>>>(x, Wconv1, bconv1, RESID);
  k_lnT<<<(Bx*Cc*Nn)/TPB,TPB,0,stream>>>(RESID, LNTM, LNTR);
  k_lnS<<<(Bx*Cc*Tin)/TPB,TPB,0,stream>>>(RESID, LNSM, LNSR);
  k_xcat<<<(Bx*192*Nn*Tin)/TPB,TPB,0,stream>>>(RESID, LNTM, LNTR, LNSM, LNSR, gT,bT,gS,bS, XCAT);
  k_wt<<<(128*192*3+TPB-1)/TPB,TPB,0,stream>>>(Wtime, WTT, 128, 192);
  k_wt<<<(128*384*3+TPB-1)/TPB,TPB,0,stream>>>(Wmlp,  WTM, 128, 384);
  k_timeconv<<<dim3(Nn,Bx),TPB,0,stream>>>(XCAT, WTT, btime, H);

  // bf16 weight converts (into dead XCAT tail -- must be after timeconv)
  k_wcvt<<<(24*64*64+TPB-1)/TPB,TPB,0,stream>>>(wq1, WQ1B, 24, 64, 64);
  k_wcvt<<<(24*64*64+TPB-1)/TPB,TPB,0,stream>>>(wv1, WV1B, 24, 64, 64);
  k_wcvt<<<(24*64*128+TPB-1)/TPB,TPB,0,stream>>>(wq2, WQ2B, 24, 64, 128);
  k_wcvt<<<(24*64*128+TPB-1)/TPB,TPB,0,stream>>>(wv2, WV2B, 24, 64, 128);
  k_t2bf<64><<<dim3(169,Bx),TPB,0,stream>>>(H, HT);

  for(int i=0;i<3;i++){
    k_gcs_mfma<64><<<dim3(169,1,Bx),TPB,0,stream>>>(HT, WQ1B+(size_t)i*8*64*64, WV1B+(size_t)i*8*64*64, RA);
    k_agg<1><<<dim3(64,Bx),TPB,0,stream>>>(RA, adj+(size_t)i*Nn*Nn, bias1+(size_t)i*64,  RB, 64);
    k_t2bf<64><<<dim3(169,Bx),TPB,0,stream>>>(RB, RBT);
    k_gcs_mfma<128><<<dim3(169,2,Bx),TPB,0,stream>>>(RBT, WQ2B+(size_t)i*8*128*64, WV2B+(size_t)i*8*128*64, RA);
    k_agg<0><<<dim3(128,Bx),TPB,0,stream>>>(RA, adj+(size_t)i*Nn*Nn, bias2+(size_t)i*128, RB, 128);
    k_mlpacc<<<dim3(Nn,Bx),TPB,0,stream>>>(RB, WTM, GACC, i);
  }
  k_glu2<<<(Bx*Cc*Nn*Tout)/TPB,TPB,0,stream>>>(GACC, bmlp, GG);
  k_xe<<<(Bx*1271808)/TPB,TPB,0,stream>>>(GG, embT, XE);
  k_attn<<<dim3(Nn,Bx),TPB,0,stream>>>(XE, RESID, Wq,bq,Wk,bk,Wv,bv,Wfc,bfc,g1,b1n,g2,b2n,
                                       Wff1,bff1,Wff2,bff2,Wrp,brp, Y);
  k_bnstats<<<64,TPB,0,stream>>>(Y, BNST);
  k_bnout<<<(Bx*Cc*Nn*Tout)/TPB,TPB,0,stream>>>(Y, BNST, gbn, bbn, (float*)d_out);
}

// Round 6
// 2754.281 us; speedup vs baseline: 1.6525x; 1.0835x over previous
//
#include <hip/hip_runtime.h>
#include <hip/hip_bf16.h>

#define TPB 256

constexpr int Bx = 8, Cc = 64, Nn = 207, Tin = 54, Kb = 8;
constexpr int LP = 52, NP = Nn * LP;     // time padded 50->52, flattened node*time positions
constexpr int NPa = 10816;               // NP rounded up to 169*64 for MFMA tiles
constexpr int L50 = 50, Tout = 48;
constexpr int Ee = 512, Pn = 12;
constexpr float EPSF = 1e-5f;
constexpr int SRDF = 520;                // padded row stride for 512-wide f32 LDS rows

// ---------------- workspace layout (floats) ----------------
// ws_size is 256 MiB = 67,108,864 floats; proven-safe peak usage = 65,350,784 floats.
constexpr size_t O_RESID = 0;                                   // [B][64][207][54]
constexpr size_t O_LNTM  = O_RESID + (size_t)Bx*Cc*Nn*Tin;
constexpr size_t O_LNTR  = O_LNTM  + (size_t)Bx*Cc*Nn;
constexpr size_t O_LNSM  = O_LNTR  + (size_t)Bx*Cc*Nn;
constexpr size_t O_LNSR  = O_LNSM  + (size_t)Bx*Cc*Tin;
constexpr size_t O_XCAT  = O_LNSR  + (size_t)Bx*Cc*Tin;         // [B][192][207][54]; later reused as RA + bf16 tail
constexpr size_t O_RB    = O_XCAT  + (size_t)Bx*192*Nn*Tin;     // [B][128][NP]
constexpr size_t O_H     = O_RB    + (size_t)Bx*128*NP;         // [B][64][NP]
constexpr size_t O_GACC  = O_H     + (size_t)Bx*64*NP;          // [B][128][207][48]
constexpr size_t O_GG    = O_GACC  + (size_t)Bx*128*Nn*Tout;    // [B][64][207][48]; later reused as Y
constexpr size_t O_XE    = O_GG    + (size_t)Bx*64*Nn*Tout;     // [B][207][12][512]
constexpr size_t O_WTT   = O_XE    + (size_t)Bx*Nn*Pn*Ee;       // transposed W_time 128*192*3
constexpr size_t O_WTM   = O_WTT   + (size_t)128*192*3;         // transposed W_mlp 128*384*3
constexpr size_t O_BNST  = O_WTM   + (size_t)128*384*3;         // 128
// bf16 buffers aliased into the dead tail of XCAT (XCAT dead after timeconv; RA uses first Bx*128*NP floats)
constexpr size_t O_HT    = O_XCAT + (size_t)Bx*128*NP;          // ushort[Bx][NPa][64]
constexpr size_t O_WQ1B  = O_HT   + (size_t)Bx*NPa*64/2;        // ushort[24][64][64]
constexpr size_t O_WV1B  = O_WQ1B + (size_t)24*64*64/2;
constexpr size_t O_WQ2B  = O_WV1B + (size_t)24*64*64/2;         // ushort[24][128][64]
constexpr size_t O_WV2B  = O_WQ2B + (size_t)24*128*64/2;
constexpr size_t O_RBT   = O_WV2B + (size_t)24*128*64/2;        // ushort[Bx][NPa][64]
// attn bf16 transposed weights (also in XCAT tail; total ends at O_XCAT+17,123,328 < O_XCAT+17,169,408)
constexpr size_t O_WQT   = O_RBT  + (size_t)Bx*NPa*64/2;        // ushort[64][64]
constexpr size_t O_WKT   = O_WQT  + 2048;
constexpr size_t O_WVT   = O_WKT  + 2048;
constexpr size_t O_WFCT  = O_WVT  + 2048;                       // ushort[512][512]
constexpr size_t O_WF1T  = O_WFCT + 131072;                     // ushort[256][512]
constexpr size_t O_WF2T  = O_WF1T + 65536;                      // ushort[512][256]

#define FMA4(acc, sA_, vB_) { (acc).x += (sA_)*(vB_).x; (acc).y += (sA_)*(vB_).y; (acc).z += (sA_)*(vB_).z; (acc).w += (sA_)*(vB_).w; }

typedef __attribute__((ext_vector_type(8))) short bf16x8;
typedef __attribute__((ext_vector_type(4))) float f32x4;

__device__ __forceinline__ float sigm(float x){ return 1.0f/(1.0f+__expf(-x)); }
__device__ __forceinline__ ushort f2bf(float x){ __hip_bfloat16 h = __float2bfloat16(x); return *(ushort*)&h; }

// ---------------- residual = W_conv1 @ x + b ----------------
__global__ __launch_bounds__(TPB) void k_residual(const float* __restrict__ x, const float* __restrict__ W,
                                                  const float* __restrict__ bias, float* __restrict__ out){
  int n = blockIdx.x, b = blockIdx.y;
  __shared__ __align__(16) float sX[Cc][Tin];
  __shared__ __align__(16) float sW[Cc*Cc];
  int tid = threadIdx.x;
  for(int i=tid;i<Cc*Tin;i+=TPB){ int c=i/Tin, l=i%Tin; sX[c][l] = x[((size_t)(b*Cc+c)*Nn+n)*Tin+l]; }
  for(int i=tid;i<Cc*Cc;i+=TPB) sW[i]=W[i];
  __syncthreads();
  for(int i=tid;i<Cc*Tin;i+=TPB){
    int o=i/Tin, l=i%Tin; float acc=bias[o];
    #pragma unroll 8
    for(int c=0;c<Cc;c++) acc += sW[o*Cc+c]*sX[c][l];
    out[((size_t)(b*Cc+o)*Nn+n)*Tin+l]=acc;
  }
}

// ---------------- LN stats ----------------
__global__ __launch_bounds__(TPB) void k_lnT(const float* __restrict__ r, float* __restrict__ mean, float* __restrict__ rstd){
  int row = blockIdx.x*TPB + threadIdx.x;
  if(row >= Bx*Cc*Nn) return;
  const float* p = r + (size_t)row*Tin;
  float s=0.f,s2=0.f;
  for(int l=0;l<Tin;l++){ float v=p[l]; s+=v; s2+=v*v; }
  float m=s*(1.f/Tin); float var=s2*(1.f/Tin)-m*m;
  mean[row]=m; rstd[row]=rsqrtf(fmaxf(var,0.f)+EPSF);
}
__global__ __launch_bounds__(TPB) void k_lnS(const float* __restrict__ r, float* __restrict__ mean, float* __restrict__ rstd){
  int row = blockIdx.x*TPB + threadIdx.x;       // (b*Cc+c)*Tin + l
  if(row >= Bx*Cc*Tin) return;
  int l = row % Tin; int bc = row / Tin;
  const float* p = r + (size_t)bc*Nn*Tin + l;
  float s=0.f,s2=0.f;
  for(int n=0;n<Nn;n++){ float v=p[(size_t)n*Tin]; s+=v; s2+=v*v; }
  float m=s*(1.f/Nn); float var=s2*(1.f/Nn)-m*m;
  mean[row]=m; rstd[row]=rsqrtf(fmaxf(var,0.f)+EPSF);
}

// ---------------- xcat = [resid, LN_T, LN_S] ----------------
__global__ __launch_bounds__(TPB) void k_xcat(const float* __restrict__ r, const float* __restrict__ tm, const float* __restrict__ tr,
                                              const float* __restrict__ sm, const float* __restrict__ sr,
                                              const float* __restrict__ gT, const float* __restrict__ bT,
                                              const float* __restrict__ gS, const float* __restrict__ bS,
                                              float* __restrict__ out){
  size_t i = (size_t)blockIdx.x*TPB + threadIdx.x;
  if(i >= (size_t)Bx*192*Nn*Tin) return;
  int l = (int)(i % Tin); size_t r1 = i / Tin; int n = (int)(r1 % Nn); size_t r2 = r1 / Nn;
  int ci = (int)(r2 % 192); int b = (int)(r2 / 192);
  int c = ci & 63; int grp = ci >> 6;
  float v = r[((size_t)(b*Cc+c)*Nn+n)*Tin+l];
  float o;
  if(grp==0) o = v;
  else if(grp==1){ int row=(b*Cc+c)*Nn+n; o = (v-tm[row])*tr[row]*gT[l] + bT[l]; }
  else { int row=(b*Cc+c)*Tin+l; o = (v-sm[row])*sr[row]*gS[n] + bS[n]; }
  out[i]=o;
}

// ---------------- weight transpose: W[o][ci][3] -> WT[(ci*3+kt)*O + o] ----------------
__global__ __launch_bounds__(TPB) void k_wt(const float* __restrict__ W, float* __restrict__ WT, int O, int CI){
  int idx = blockIdx.x*TPB + threadIdx.x;
  int total = O*CI*3;
  if(idx>=total) return;
  int kt = idx%3; int r = idx/3; int ci = r%CI; int o = r/CI;
  WT[(size_t)(ci*3+kt)*O + o] = W[idx];
}

// ---------------- gcn weight convert: W[slk][C][D] f32 -> WT[slk][D][C] bf16 ----------------
__global__ __launch_bounds__(TPB) void k_wcvt(const float* __restrict__ W, ushort* __restrict__ WT,
                                              int SLK, int C, int D){
  int i = blockIdx.x*TPB + threadIdx.x;
  if(i >= SLK*C*D) return;
  int d = i % D; int r = i / D; int c = r % C; int slk = r / C;
  WT[((size_t)slk*D + d)*C + c] = f2bf(W[i]);
}

// ---------------- generic transpose convert: W f32 [R][C] -> WT bf16 [C][R] ----------------
__global__ __launch_bounds__(TPB) void k_wtr(const float* __restrict__ W, ushort* __restrict__ WT, int R, int C){
  int i = blockIdx.x*TPB + threadIdx.x;
  if(i >= R*C) return;
  int c = i % C, r = i / C;
  WT[(size_t)c*R + r] = f2bf(W[i]);
}

// ---------------- activation transpose+convert: X f32 [b][C][NP] -> XT bf16 [b][NPa][C] ----------------
template<int C>
__global__ __launch_bounds__(TPB) void k_t2bf(const float* __restrict__ X, ushort* __restrict__ XT){
  int p0 = blockIdx.x*64, b = blockIdx.y;
  int tid = threadIdx.x;
  __shared__ __align__(16) float sT[64][65];
  for(int cc=0; cc<C; cc+=64){
    if(cc) __syncthreads();
    for(int i=tid;i<4096;i+=TPB){ int c=i>>6, col=i&63; int p=p0+col;
      sT[c][col] = (p<NP) ? X[((size_t)(b*C+cc+c))*NP + p] : 0.f; }
    __syncthreads();
    for(int i=tid;i<512;i+=TPB){
      int row=i>>3, c8=(i&7)<<3;
      ushort u[8];
      #pragma unroll
      for(int j=0;j<8;j++) u[j] = f2bf(sT[c8+j][row]);
      *(uint4*)&XT[((size_t)b*NPa + p0 + row)*C + cc + c8] = *(uint4*)u;
    }
  }
}

// ---------------- dilated time conv (dil=2) + GLU -> h [B][64][NP] ----------------
__global__ __launch_bounds__(TPB) void k_timeconv(const float* __restrict__ xcat, const float* __restrict__ WT,
                                                  const float* __restrict__ bias, float* __restrict__ h){
  int n = blockIdx.x, b = blockIdx.y;
  __shared__ __align__(16) float sX[192][60];
  __shared__ __align__(16) float sP[128][L50];
  int tid = threadIdx.x;
  for(int i=tid;i<192*60;i+=TPB){ int c=i/60, l=i%60;
    sX[c][l] = (l<Tin) ? xcat[((size_t)(b*192+c)*Nn+n)*Tin+l] : 0.f; }
  __syncthreads();
  int o = tid & 127, half = tid >> 7;
  int t0 = half*28;
  float acc[28];
  #pragma unroll
  for(int j=0;j<28;j++) acc[j]=0.f;
  for(int ci=0;ci<192;ci++){
    float w0 = WT[(size_t)(ci*3+0)*128+o];
    float w1 = WT[(size_t)(ci*3+1)*128+o];
    float w2 = WT[(size_t)(ci*3+2)*128+o];
    float sv[32];
    #pragma unroll
    for(int m=0;m<32;m++) sv[m]=sX[ci][t0+m];
    #pragma unroll
    for(int j=0;j<28;j++) acc[j] += w0*sv[j] + w1*sv[j+2] + w2*sv[j+4];
  }
  float bb = bias[o];
  int nlive = half ? 22 : 28;
  for(int j=0;j<nlive;j++) sP[o][t0+j] = acc[j]+bb;
  __syncthreads();
  for(int i=tid;i<Cc*LP;i+=TPB){
    int c=i/LP, t=i%LP;
    float v = 0.f;
    if(t<L50) v = tanhf(sP[c][t]) * sigm(sP[c+64][t]);
    h[((size_t)b*Cc+c)*NP + (size_t)n*LP + t] = v;
  }
}

// ---------------- gated multi-basis GCN einsum via MFMA ----------------
template<int D>
__global__ __launch_bounds__(TPB) void k_gcs_mfma(const ushort* __restrict__ XT,
    const ushort* __restrict__ wqT, const ushort* __restrict__ wvT,
    float* __restrict__ S){
  int p0 = blockIdx.x*64;
  int b = blockIdx.z;
  int tid = threadIdx.x;
  int lane = tid & 63;
  int d0 = blockIdx.y*64 + ((tid>>6)<<4);      // wave -> 16-wide d strip
  __shared__ __align__(16) ushort sX[64*64];   // [p][c], XOR-swizzled (c8 ^ (row&7)<<3)
  for(int i=tid;i<512;i+=TPB){
    int row=i>>3, c8=(i&7)<<3;
    uint4 v = *(const uint4*)&XT[((size_t)b*NPa + p0 + row)*64 + c8];
    *(uint4*)&sX[row*64 + (c8 ^ ((row&7)<<3))] = v;
  }
  __syncthreads();
  int r15 = lane & 15, hi = lane >> 4;
  bf16x8 bf[4][2];
  #pragma unroll
  for(int pt=0;pt<4;pt++){
    int row = pt*16 + r15;
    int sw = (row&7)<<3;
    int cu0 = hi*8;
    bf[pt][0] = *(const bf16x8*)&sX[row*64 + (cu0 ^ sw)];
    bf[pt][1] = *(const bf16x8*)&sX[row*64 + ((cu0+32) ^ sw)];
  }
  f32x4 acc[4];
  #pragma unroll
  for(int pt=0;pt<4;pt++){ acc[pt][0]=0.f; acc[pt][1]=0.f; acc[pt][2]=0.f; acc[pt][3]=0.f; }
  const ushort* wqp = wqT + ((size_t)(d0 + r15))*64 + hi*8;
  const ushort* wvp = wvT + ((size_t)(d0 + r15))*64 + hi*8;
  for(int k=0;k<Kb;k++){
    bf16x8 aq0 = *(const bf16x8*)&wqp[0];
    bf16x8 aq1 = *(const bf16x8*)&wqp[32];
    bf16x8 av0 = *(const bf16x8*)&wvp[0];
    bf16x8 av1 = *(const bf16x8*)&wvp[32];
    wqp += (size_t)D*64; wvp += (size_t)D*64;
    #pragma unroll
    for(int pt=0;pt<4;pt++){
      f32x4 q; q[0]=0.f;q[1]=0.f;q[2]=0.f;q[3]=0.f;
      f32x4 v; v[0]=0.f;v[1]=0.f;v[2]=0.f;v[3]=0.f;
      q = __builtin_amdgcn_mfma_f32_16x16x32_bf16(aq0, bf[pt][0], q, 0,0,0);
      q = __builtin_amdgcn_mfma_f32_16x16x32_bf16(aq1, bf[pt][1], q, 0,0,0);
      v = __builtin_amdgcn_mfma_f32_16x16x32_bf16(av0, bf[pt][0], v, 0,0,0);
      v = __builtin_amdgcn_mfma_f32_16x16x32_bf16(av1, bf[pt][1], v, 0,0,0);
      #pragma unroll
      for(int i=0;i<4;i++) acc[pt][i] += v[i]*sigm(q[i]);
    }
  }
  #pragma unroll
  for(int pt=0;pt<4;pt++){
    int p = p0 + pt*16 + r15;
    if(p < NP){
      #pragma unroll
      for(int i=0;i<4;i++){
        int d = d0 + hi*4 + i;
        S[((size_t)b*D + d)*NP + p] = acc[pt][i];
      }
    }
  }
}

// ---------------- adjacency aggregation ----------------
template<int RELU>
__global__ __launch_bounds__(TPB) void k_agg(const float* __restrict__ S, const float* __restrict__ adj,
                                             const float* __restrict__ bias, float* __restrict__ Out, int D){
  int d = blockIdx.x, b = blockIdx.y;
  __shared__ __align__(16) float sAdj[69][208];
  __shared__ __align__(16) float sSm[69][52];
  int tid = threadIdx.x;
  int kq[3], lq[3], valid[3];
  #pragma unroll
  for(int m=0;m<3;m++){ int mt = tid + m*TPB; valid[m] = (mt<676); kq[m] = mt/13; lq[m] = mt%13; }
  float acc[3][4][4];
  #pragma unroll
  for(int m=0;m<3;m++)
    #pragma unroll
    for(int a=0;a<4;a++){ acc[m][a][0]=0;acc[m][a][1]=0;acc[m][a][2]=0;acc[m][a][3]=0; }
  const float* Sp = S + ((size_t)b*D + d)*NP;
  for(int ch=0; ch<3; ch++){
    int n0 = ch*69;
    __syncthreads();
    for(int i=tid;i<69*208;i+=TPB){ int nn=i/208, k2=i%208;
      sAdj[nn][k2] = (k2<Nn) ? adj[(size_t)(n0+nn)*Nn + k2] : 0.f; }
    for(int i=tid;i<69*52;i+=TPB){ int nn=i/52, l=i%52;
      sSm[nn][l] = Sp[(size_t)(n0+nn)*LP + l]; }
    __syncthreads();
    for(int nn=0;nn<69;nn++){
      #pragma unroll
      for(int m=0;m<3;m++){
        if(!valid[m]) continue;
        float4 a4 = *(const float4*)&sAdj[nn][kq[m]*4];
        float4 s4 = *(const float4*)&sSm[nn][lq[m]*4];
        float as[4]={a4.x,a4.y,a4.z,a4.w};
        float ss[4]={s4.x,s4.y,s4.z,s4.w};
        #pragma unroll
        for(int ki=0;ki<4;ki++)
          #pragma unroll
          for(int li=0;li<4;li++) acc[m][ki][li] += as[ki]*ss[li];
      }
    }
  }
  float bb = bias[d];
  #pragma unroll
  for(int m=0;m<3;m++){
    if(!valid[m]) continue;
    #pragma unroll
    for(int ki=0;ki<4;ki++){
      int k2 = kq[m]*4+ki;
      if(k2>=Nn) continue;
      #pragma unroll
      for(int li=0;li<4;li++){
        int l = lq[m]*4+li;
        float v = acc[m][ki][li] + bb;
        if(RELU) v = fmaxf(v, 0.f);
        Out[(((size_t)b*D+d)*Nn + k2)*LP + l] = v;
      }
    }
  }
}

// ---------------- MLP conv accumulate (dil=1), per layer ----------------
__global__ __launch_bounds__(TPB) void k_mlpacc(const float* __restrict__ Outs, const float* __restrict__ WT,
                                                float* __restrict__ gacc, int layer){
  int n = blockIdx.x, b = blockIdx.y;
  __shared__ __align__(16) float sO[128][52];
  int tid = threadIdx.x;
  for(int i=tid;i<128*52;i+=TPB){ int c=i/52, l=i%52;
    sO[c][l] = Outs[(((size_t)b*128+c)*Nn + n)*LP + l]; }
  __syncthreads();
  int o = tid & 127, half = tid >> 7;
  int t0 = half*24;
  float acc[24];
  #pragma unroll
  for(int j=0;j<24;j++) acc[j]=0.f;
  const float* wt = WT + (size_t)layer*128*3*128;
  for(int ci=0;ci<128;ci++){
    float w0 = wt[(size_t)(ci*3+0)*128+o];
    float w1 = wt[(size_t)(ci*3+1)*128+o];
    float w2 = wt[(size_t)(ci*3+2)*128+o];
    float sv[26];
    #pragma unroll
    for(int m=0;m<26;m++) sv[m]=sO[ci][t0+m];
    #pragma unroll
    for(int j=0;j<24;j++) acc[j] += w0*sv[j] + w1*sv[j+1] + w2*sv[j+2];
  }
  size_t base = (((size_t)b*128+o)*Nn + n)*Tout + t0;
  if(layer==0){ for(int j=0;j<24;j++) gacc[base+j] = acc[j]; }
  else       { for(int j=0;j<24;j++) gacc[base+j] += acc[j]; }
}

// ---------------- GLU over accumulated MLP conv ----------------
__global__ __launch_bounds__(TPB) void k_glu2(const float* __restrict__ gacc, const float* __restrict__ bm, float* __restrict__ gg){
  size_t i = (size_t)blockIdx.x*TPB + threadIdx.x;
  if(i >= (size_t)Bx*Cc*Nn*Tout) return;
  int t = (int)(i % Tout); size_t r = i / Tout; int n = (int)(r % Nn); size_t r2 = r / Nn;
  int c = (int)(r2 % Cc); int b = (int)(r2 / Cc);
  size_t i1 = (((size_t)b*128+c)*Nn+n)*Tout + t;
  size_t i2 = (((size_t)b*128+c+64)*Nn+n)*Tout + t;
  float a = gacc[i1]+bm[c], b2 = gacc[i2]+bm[c+64];
  gg[i] = tanhf(a)*sigm(b2);
}

// ---------------- patch scramble + emb ----------------
__global__ __launch_bounds__(TPB) void k_xe(const float* __restrict__ gg, const float* __restrict__ emb, float* __restrict__ xe){
  size_t i = (size_t)blockIdx.x*TPB + threadIdx.x;
  if(i >= (size_t)Bx*1271808) return;
  int b = (int)(i / 1271808);
  int off = (int)(i % 1271808);
  int c = off / 19872; int r = off % 19872;
  int n = r / 96; int r2 = r % 96;
  int p = r2 >> 3; int j = r2 & 7;
  int t = p*4 + j;
  float v = 0.f;
  if(t < Tout) v = gg[(((size_t)b*Cc+c)*Nn + n)*Tout + t];
  int e = off & 511; int p2 = (off >> 9) % 12;
  xe[i] = v + emb[(size_t)p2*Ee + e];
}

// ---------------- per-row LN helper (rows of 512, stride SRDF, in LDS) ----------------
__device__ __forceinline__ void ln_rows(float* buf, const float* __restrict__ g, const float* __restrict__ be, int tid){
  int lane = tid & 63, wv = tid >> 6;
  for(int r = wv; r < 12; r += 4){
    float s=0.f, s2=0.f;
    #pragma unroll
    for(int j=0;j<8;j++){ float v = buf[r*SRDF + j*64 + lane]; s+=v; s2+=v*v; }
    #pragma unroll
    for(int off=32; off; off>>=1){ s += __shfl_xor(s,off); s2 += __shfl_xor(s2,off); }
    float m = s*(1.f/512.f);
    float rstd = rsqrtf(fmaxf(s2*(1.f/512.f)-m*m, 0.f)+EPSF);
    #pragma unroll
    for(int j=0;j<8;j++){ int e = j*64+lane; float v = buf[r*SRDF+e];
      buf[r*SRDF+e] = (v-m)*rstd*g[e] + be[e]; }
  }
}

// ---------------- fused per-(b,n) transformer, MFMA GEMM phases ----------------
// LDS: SbX 16KB + Mb 8KB + 2x24.96KB f32 + sS 4.6KB = ~79KB -> 2 blocks/CU
__global__ __launch_bounds__(TPB,2) void k_attn(
    const float* __restrict__ xe, const float* __restrict__ resid,
    const ushort* __restrict__ WqT, const float* __restrict__ bq,
    const ushort* __restrict__ WkT, const float* __restrict__ bk,
    const ushort* __restrict__ WvT, const float* __restrict__ bv,
    const ushort* __restrict__ WfcT, const float* __restrict__ bfc,
    const float* __restrict__ g1, const float* __restrict__ b1n,
    const float* __restrict__ g2, const float* __restrict__ b2n,
    const ushort* __restrict__ Wff1T, const float* __restrict__ bff1,
    const ushort* __restrict__ Wff2T, const float* __restrict__ bff2,
    const float* __restrict__ Wrp, const float* __restrict__ brp,
    float* __restrict__ y)
{
  int n = blockIdx.x, b = blockIdx.y;
  __shared__ __align__(16) ushort SbX[16*512];  // xe bf16 -> ao bf16 -> M bf16 (swizzled A operand)
  __shared__ __align__(16) ushort Mb[16*256];   // ff1 output bf16 (swizzled A operand)
  __shared__ __align__(16) float U0[12*SRDF];   // q -> v -> U(pre/post LN) -> Wrp
  __shared__ __align__(16) float U1[12*SRDF];   // k -> M -> Odat
  __shared__ __align__(16) float sS[1160];
  int tid = threadIdx.x;
  int lane = tid & 63, w = tid >> 6;
  int r15 = lane & 15, hi = lane >> 4;
  const float* __restrict__ xeg = xe + ((size_t)b*Nn + n)*6144;

  // phase 1: xe -> SbX (bf16, 16B-chunk XOR swizzle), rows 12-15 zero; zero Mb rows 12-15
  for(int i=tid;i<1024;i+=TPB){
    int r = i>>6, ch = i&63;
    ushort u[8];
    if(r<12){
      const float* s = &xeg[r*512 + ch*8];
      #pragma unroll
      for(int j=0;j<8;j++) u[j] = f2bf(s[j]);
    } else {
      #pragma unroll
      for(int j=0;j<8;j++) u[j] = 0;
    }
    *(uint4*)&SbX[r*512 + ((ch ^ (r&7))<<3)] = *(uint4*)u;
  }
  for(int i=tid;i<128;i+=TPB){
    int r = 12 + (i>>5), ch = i&31;
    uint4 z; z.x=0;z.y=0;z.z=0;z.w=0;
    *(uint4*)&Mb[r*256 + ch*8] = z;
  }
  __syncthreads();

  // phase 2: QKV MFMA. A = SbX per-head slice; B = W{q,k,v}T[d][dp]. q->U0, k->U1, v->regs.
  f32x4 vfrag[2][4];
  #pragma unroll
  for(int h2=0;h2<2;h2++){
    int head = w*2 + h2;
    bf16x8 a0, a1;
    { int ch0 = head*8 + hi, ch1 = head*8 + 4 + hi;
      a0 = *(const bf16x8*)&SbX[r15*512 + ((ch0 ^ (r15&7))<<3)];
      a1 = *(const bf16x8*)&SbX[r15*512 + ((ch1 ^ (r15&7))<<3)]; }
    #pragma unroll
    for(int nt=0;nt<4;nt++){
      int col = nt*16 + r15;
      float bb = bq[col];
      f32x4 acc; acc[0]=bb;acc[1]=bb;acc[2]=bb;acc[3]=bb;
      acc = __builtin_amdgcn_mfma_f32_16x16x32_bf16(a0, *(const bf16x8*)&WqT[(size_t)col*64 + hi*8], acc, 0,0,0);
      acc = __builtin_amdgcn_mfma_f32_16x16x32_bf16(a1, *(const bf16x8*)&WqT[(size_t)col*64 + 32 + hi*8], acc, 0,0,0);
      #pragma unroll
      for(int i2=0;i2<4;i2++){ int p = hi*4+i2; if(p<12) U0[p*SRDF + head*64 + col] = acc[i2]; }
    }
    #pragma unroll
    for(int nt=0;nt<4;nt++){
      int col = nt*16 + r15;
      float bb = bk[col];
      f32x4 acc; acc[0]=bb;acc[1]=bb;acc[2]=bb;acc[3]=bb;
      acc = __builtin_amdgcn_mfma_f32_16x16x32_bf16(a0, *(const bf16x8*)&WkT[(size_t)col*64 + hi*8], acc, 0,0,0);
      acc = __builtin_amdgcn_mfma_f32_16x16x32_bf16(a1, *(const bf16x8*)&WkT[(size_t)col*64 + 32 + hi*8], acc, 0,0,0);
      #pragma unroll
      for(int i2=0;i2<4;i2++){ int p = hi*4+i2; if(p<12) U1[p*SRDF + head*64 + col] = acc[i2]; }
    }
    #pragma unroll
    for(int nt=0;nt<4;nt++){
      int col = nt*16 + r15;
      float bb = bv[col];
      f32x4 acc; acc[0]=bb;acc[1]=bb;acc[2]=bb;acc[3]=bb;
      acc = __builtin_amdgcn_mfma_f32_16x16x32_bf16(a0, *(const bf16x8*)&WvT[(size_t)col*64 + hi*8], acc, 0,0,0);
      acc = __builtin_amdgcn_mfma_f32_16x16x32_bf16(a1, *(const bf16x8*)&WvT[(size_t)col*64 + 32 + hi*8], acc, 0,0,0);
      vfrag[h2][nt] = acc;
    }
  }
  __syncthreads();

  // phase 3: scores [kh][q] (VALU, f32)
  const float scale = 0.04419417382415922f;   // 1/sqrt(512)
  for(int i=tid;i<1152;i+=TPB){
    int q = i%12, kh = i/12; int h2 = kh&7, k2 = kh>>3;
    const float* qp = &U0[q*SRDF + h2*64];
    const float* kp = &U1[k2*SRDF + h2*64];
    float s=0.f;
    #pragma unroll
    for(int d4=0; d4<16; d4++){
      float4 a4 = *(const float4*)&qp[d4*4];
      float4 b4 = *(const float4*)&kp[d4*4];
      s += a4.x*b4.x + a4.y*b4.y + a4.z*b4.z + a4.w*b4.w;
    }
    sS[i] = s*scale;
  }
  __syncthreads();
  // v-frags -> U0 (q dead); softmax over q (per kh) concurrently
  #pragma unroll
  for(int h2=0;h2<2;h2++){
    int head = w*2 + h2;
    #pragma unroll
    for(int nt=0;nt<4;nt++){
      int col = nt*16 + r15;
      #pragma unroll
      for(int i2=0;i2<4;i2++){ int p = hi*4+i2; if(p<12) U0[p*SRDF + head*64 + col] = vfrag[h2][nt][i2]; }
    }
  }
  if(tid<96){
    float mx=-1e30f;
    for(int q=0;q<12;q++) mx = fmaxf(mx, sS[tid*12+q]);
    float sm=0.f;
    for(int q=0;q<12;q++){ float e = __expf(sS[tid*12+q]-mx); sS[tid*12+q]=e; sm+=e; }
    float inv = 1.f/sm;
    for(int q=0;q<12;q++) sS[tid*12+q] *= inv;
  }
  __syncthreads();

  // phase 4: ao (VALU) -> SbX bf16 swizzled
  for(int i=tid;i<6144;i+=TPB){
    int q=i>>9, h2=(i>>6)&7, d=i&63;
    float s=0.f;
    #pragma unroll
    for(int k2=0;k2<12;k2++) s += sS[(k2*8+h2)*12+q]*U0[k2*SRDF+h2*64+d];
    int kk = i & 511;
    SbX[q*512 + (((kk>>3) ^ (q&7))<<3) + (kk&7)] = f2bf(s);
  }
  __syncthreads();

  // phase 5: fc MFMA (+bfc +xe) -> U1
  {
    f32x4 acc[8];
    #pragma unroll
    for(int nt=0;nt<8;nt++){ float bb = bfc[(w*8+nt)*16 + r15]; acc[nt][0]=bb;acc[nt][1]=bb;acc[nt][2]=bb;acc[nt][3]=bb; }
    for(int ks=0;ks<16;ks++){
      int ch = ks*4 + hi;
      bf16x8 a = *(const bf16x8*)&SbX[r15*512 + ((ch ^ (r15&7))<<3)];
      #pragma unroll
      for(int nt=0;nt<8;nt++){
        int col = (w*8+nt)*16 + r15;
        acc[nt] = __builtin_amdgcn_mfma_f32_16x16x32_bf16(a, *(const bf16x8*)&WfcT[(size_t)col*512 + ks*32 + hi*8], acc[nt], 0,0,0);
      }
    }
    #pragma unroll
    for(int nt=0;nt<8;nt++){
      int col = (w*8+nt)*16 + r15;
      #pragma unroll
      for(int i2=0;i2<4;i2++){ int p = hi*4+i2; if(p<12) U1[p*SRDF + col] = acc[nt][i2] + xeg[p*512 + col]; }
    }
  }
  __syncthreads();
  ln_rows(U1, g1, b1n, tid);     // M in U1
  __syncthreads();

  // phase 6: M -> SbX bf16 swizzled
  for(int i=tid;i<6144;i+=TPB){
    int r=i>>9, kk=i&511;
    SbX[r*512 + (((kk>>3) ^ (r&7))<<3) + (kk&7)] = f2bf(U1[r*SRDF + kk]);
  }
  __syncthreads();

  // phase 7: ff1 MFMA (+bff1, relu) -> Mb bf16 swizzled
  {
    f32x4 acc[4];
    #pragma unroll
    for(int nt=0;nt<4;nt++){ float bb = bff1[(w*4+nt)*16 + r15]; acc[nt][0]=bb;acc[nt][1]=bb;acc[nt][2]=bb;acc[nt][3]=bb; }
    for(int ks=0;ks<16;ks++){
      int ch = ks*4 + hi;
      bf16x8 a = *(const bf16x8*)&SbX[r15*512 + ((ch ^ (r15&7))<<3)];
      #pragma unroll
      for(int nt=0;nt<4;nt++){
        int col = (w*4+nt)*16 + r15;
        acc[nt] = __builtin_amdgcn_mfma_f32_16x16x32_bf16(a, *(const bf16x8*)&Wff1T[(size_t)col*512 + ks*32 + hi*8], acc[nt], 0,0,0);
      }
    }
    #pragma unroll
    for(int nt=0;nt<4;nt++){
      int u = (w*4+nt)*16 + r15;
      #pragma unroll
      for(int i2=0;i2<4;i2++){
        int p = hi*4+i2;
        if(p<12) Mb[p*256 + (((u>>3) ^ (p&7))<<3) + (u&7)] = f2bf(fmaxf(acc[nt][i2], 0.f));
      }
    }
  }
  __syncthreads();

  // phase 8: ff2 MFMA (+bff2 +M) -> U0
  {
    f32x4 acc[8];
    #pragma unroll
    for(int nt=0;nt<8;nt++){ float bb = bff2[(w*8+nt)*16 + r15]; acc[nt][0]=bb;acc[nt][1]=bb;acc[nt][2]=bb;acc[nt][3]=bb; }
    for(int ks=0;ks<8;ks++){
      int ch = ks*4 + hi;
      bf16x8 a = *(const bf16x8*)&Mb[r15*256 + ((ch ^ (r15&7))<<3)];
      #pragma unroll
      for(int nt=0;nt<8;nt++){
        int col = (w*8+nt)*16 + r15;
        acc[nt] = __builtin_amdgcn_mfma_f32_16x16x32_bf16(a, *(const bf16x8*)&Wff2T[(size_t)col*256 + ks*32 + hi*8], acc[nt], 0,0,0);
      }
    }
    #pragma unroll
    for(int nt=0;nt<8;nt++){
      int col = (w*8+nt)*16 + r15;
      #pragma unroll
      for(int i2=0;i2<4;i2++){ int p = hi*4+i2; if(p<12) U0[p*SRDF + col] = acc[nt][i2] + U1[p*SRDF + col]; }
    }
  }
  __syncthreads();
  ln_rows(U0, g2, b2n, tid);     // U in U0
  __syncthreads();

  // Odat = U + M + xe -> U1
  for(int i=tid;i<6144;i+=TPB){
    int r=i>>9, c=i&511;
    U1[r*SRDF+c] = U0[r*SRDF+c] + U1[r*SRDF+c] + xeg[r*512+c];
  }
  __syncthreads();
  // Wrp -> U0 (U dead)
  for(int i=tid;i<4608;i+=TPB) U0[i] = Wrp[i];
  __syncthreads();
  // y = Odat([64][96]) @ Wrp + brp + resid
  #pragma unroll
  for(int j=0;j<3;j++){
    int i4 = tid + j*TPB;
    int c = i4/12, tq = i4%12; int t0 = tq*4;
    float4 acc = *(const float4*)&brp[t0];
    for(int t96=0;t96<96;t96++){
      int f = c*96 + t96;
      float a = U1[(f>>9)*SRDF + (f&511)];
      float4 w4 = *(const float4*)&U0[t96*48 + t0];
      FMA4(acc, a, w4);
    }
    size_t rb = (((size_t)b*Cc+c)*Nn + n)*Tin + 6 + t0;
    acc.x += resid[rb+0]; acc.y += resid[rb+1]; acc.z += resid[rb+2]; acc.w += resid[rb+3];
    *(float4*)&y[(((size_t)b*Cc+c)*Nn + n)*Tout + t0] = acc;
  }
}

// ---------------- batchnorm ----------------
__global__ __launch_bounds__(TPB) void k_bnstats(const float* __restrict__ y, float* __restrict__ stats){
  int c = blockIdx.x; int tid = threadIdx.x;
  float s=0.f,s2=0.f;
  const int per = Nn*Tout;   // 9936
  for(int idx=tid; idx<Bx*per; idx+=TPB){
    int b = idx/per, r = idx%per;
    float v = y[((size_t)b*Cc+c)*per + r];
    s+=v; s2+=v*v;
  }
  __shared__ float rs[TPB], rs2[TPB];
  rs[tid]=s; rs2[tid]=s2; __syncthreads();
  for(int off=TPB/2; off; off>>=1){ if(tid<off){ rs[tid]+=rs[tid+off]; rs2[tid]+=rs2[tid+off]; } __syncthreads(); }
  if(tid==0){
    float m = rs[0]/(float)(Bx*per);
    float var = rs2[0]/(float)(Bx*per) - m*m;
    stats[c]=m; stats[64+c]=rsqrtf(fmaxf(var,0.f)+EPSF);
  }
}
__global__ __launch_bounds__(TPB) void k_bnout(const float* __restrict__ y, const float* __restrict__ stats,
                                               const float* __restrict__ gbn, const float* __restrict__ bbn,
                                               float* __restrict__ out){
  size_t i = (size_t)blockIdx.x*TPB + threadIdx.x;
  if(i >= (size_t)Bx*Cc*Nn*Tout) return;
  int c = (int)((i/(Nn*Tout))%Cc);
  out[i] = (y[i]-stats[c])*stats[64+c]*gbn[c] + bbn[c];
}

// ---------------- launch ----------------
extern "C" void kernel_launch(void* const* d_in, const int* in_sizes, int n_in,
                              void* d_out, int out_size, void* d_ws, size_t ws_size,
                              hipStream_t stream) {
  const float* x      = (const float*)d_in[0];
  const float* adj    = (const float*)d_in[1];
  const float* Wconv1 = (const float*)d_in[2];
  const float* bconv1 = (const float*)d_in[3];
  const float* gT     = (const float*)d_in[4];
  const float* bT     = (const float*)d_in[5];
  const float* gS     = (const float*)d_in[6];
  const float* bS     = (const float*)d_in[7];
  const float* Wtime  = (const float*)d_in[8];
  const float* btime  = (const float*)d_in[9];
  const float* wq1    = (const float*)d_in[10];
  const float* wv1    = (const float*)d_in[11];
  const float* bias1  = (const float*)d_in[12];
  const float* wq2    = (const float*)d_in[13];
  const float* wv2    = (const float*)d_in[14];
  const float* bias2  = (const float*)d_in[15];
  const float* Wmlp   = (const float*)d_in[16];
  const float* bmlp   = (const float*)d_in[17];
  const float* embT   = (const float*)d_in[18];
  const float* Wq     = (const float*)d_in[19];
  const float* bq     = (const float*)d_in[20];
  const float* Wk     = (const float*)d_in[21];
  const float* bk     = (const float*)d_in[22];
  const float* Wv     = (const float*)d_in[23];
  const float* bv     = (const float*)d_in[24];
  const float* Wfc    = (const float*)d_in[25];
  const float* bfc    = (const float*)d_in[26];
  const float* g1     = (const float*)d_in[27];
  const float* b1n    = (const float*)d_in[28];
  const float* g2     = (const float*)d_in[29];
  const float* b2n    = (const float*)d_in[30];
  const float* Wff1   = (const float*)d_in[31];
  const float* bff1   = (const float*)d_in[32];
  const float* Wff2   = (const float*)d_in[33];
  const float* bff2   = (const float*)d_in[34];
  const float* Wrp    = (const float*)d_in[35];
  const float* brp    = (const float*)d_in[36];
  const float* gbn    = (const float*)d_in[37];
  const float* bbn    = (const float*)d_in[38];

  float* ws = (float*)d_ws;
  float* RESID = ws + O_RESID;
  float* LNTM  = ws + O_LNTM;
  float* LNTR  = ws + O_LNTR;
  float* LNSM  = ws + O_LNSM;
  float* LNSR  = ws + O_LNSR;
  float* XCAT  = ws + O_XCAT;
  float* RA    = ws + O_XCAT;    // overlays XCAT after it is consumed
  float* RB    = ws + O_RB;
  float* H     = ws + O_H;
  float* GACC  = ws + O_GACC;
  float* GG    = ws + O_GG;
  float* Y     = ws + O_GG;      // overlays GG after xe built
  float* XE    = ws + O_XE;
  float* WTT   = ws + O_WTT;
  float* WTM   = ws + O_WTM;
  float* BNST  = ws + O_BNST;
  ushort* HT   = (ushort*)(ws + O_HT);
  ushort* WQ1B = (ushort*)(ws + O_WQ1B);
  ushort* WV1B = (ushort*)(ws + O_WV1B);
  ushort* WQ2B = (ushort*)(ws + O_WQ2B);
  ushort* WV2B = (ushort*)(ws + O_WV2B);
  ushort* RBT  = (ushort*)(ws + O_RBT);
  ushort* WQT  = (ushort*)(ws + O_WQT);
  ushort* WKT  = (ushort*)(ws + O_WKT);
  ushort* WVT  = (ushort*)(ws + O_WVT);
  ushort* WFCT = (ushort*)(ws + O_WFCT);
  ushort* WF1T = (ushort*)(ws + O_WF1T);
  ushort* WF2T = (ushort*)(ws + O_WF2T);

  k_residual<<<dim3(Nn,Bx),TPB,0,stream>>>(x, Wconv1, bconv1, RESID);
  k_lnT<<<(Bx*Cc*Nn)/TPB,TPB,0,stream>>>(RESID, LNTM, LNTR);
  k_lnS<<<(Bx*Cc*Tin)/TPB,TPB,0,stream>>>(RESID, LNSM, LNSR);
  k_xcat<<<(Bx*192*Nn*Tin)/TPB,TPB,0,stream>>>(RESID, LNTM, LNTR, LNSM, LNSR, gT,bT,gS,bS, XCAT);
  k_wt<<<(128*192*3+TPB-1)/TPB,TPB,0,stream>>>(Wtime, WTT, 128, 192);
  k_wt<<<(128*384*3+TPB-1)/TPB,TPB,0,stream>>>(Wmlp,  WTM, 128, 384);
  k_timeconv<<<dim3(Nn,Bx),TPB,0,stream>>>(XCAT, WTT, btime, H);

  // bf16 weight converts (into dead XCAT tail -- must be after timeconv)
  k_wcvt<<<(24*64*64+TPB-1)/TPB,TPB,0,stream>>>(wq1, WQ1B, 24, 64, 64);
  k_wcvt<<<(24*64*64+TPB-1)/TPB,TPB,0,stream>>>(wv1, WV1B, 24, 64, 64);
  k_wcvt<<<(24*64*128+TPB-1)/TPB,TPB,0,stream>>>(wq2, WQ2B, 24, 64, 128);
  k_wcvt<<<(24*64*128+TPB-1)/TPB,TPB,0,stream>>>(wv2, WV2B, 24, 64, 128);
  k_wtr<<<(64*64+TPB-1)/TPB,TPB,0,stream>>>(Wq, WQT, 64, 64);
  k_wtr<<<(64*64+TPB-1)/TPB,TPB,0,stream>>>(Wk, WKT, 64, 64);
  k_wtr<<<(64*64+TPB-1)/TPB,TPB,0,stream>>>(Wv, WVT, 64, 64);
  k_wtr<<<(512*512+TPB-1)/TPB,TPB,0,stream>>>(Wfc, WFCT, 512, 512);
  k_wtr<<<(512*256+TPB-1)/TPB,TPB,0,stream>>>(Wff1, WF1T, 512, 256);
  k_wtr<<<(256*512+TPB-1)/TPB,TPB,0,stream>>>(Wff2, WF2T, 256, 512);
  k_t2bf<64><<<dim3(169,Bx),TPB,0,stream>>>(H, HT);

  for(int i=0;i<3;i++){
    k_gcs_mfma<64><<<dim3(169,1,Bx),TPB,0,stream>>>(HT, WQ1B+(size_t)i*8*64*64, WV1B+(size_t)i*8*64*64, RA);
    k_agg<1><<<dim3(64,Bx),TPB,0,stream>>>(RA, adj+(size_t)i*Nn*Nn, bias1+(size_t)i*64,  RB, 64);
    k_t2bf<64><<<dim3(169,Bx),TPB,0,stream>>>(RB, RBT);
    k_gcs_mfma<128><<<dim3(169,2,Bx),TPB,0,stream>>>(RBT, WQ2B+(size_t)i*8*128*64, WV2B+(size_t)i*8*128*64, RA);
    k_agg<0><<<dim3(128,Bx),TPB,0,stream>>>(RA, adj+(size_t)i*Nn*Nn, bias2+(size_t)i*128, RB, 128);
    k_mlpacc<<<dim3(Nn,Bx),TPB,0,stream>>>(RB, WTM, GACC, i);
  }
  k_glu2<<<(Bx*Cc*Nn*Tout)/TPB,TPB,0,stream>>>(GACC, bmlp, GG);
  k_xe<<<(Bx*1271808)/TPB,TPB,0,stream>>>(GG, embT, XE);
  k_attn<<<dim3(Nn,Bx),TPB,0,stream>>>(XE, RESID, WQT,bq, WKT,bk, WVT,bv, WFCT,bfc,
                                       g1,b1n,g2,b2n, WF1T,bff1, WF2T,bff2, Wrp,brp, Y);
  k_bnstats<<<64,TPB,0,stream>>>(Y, BNST);
  k_bnout<<<(Bx*Cc*Nn*Tout)/TPB,TPB,0,stream>>>(Y, BNST, gbn, bbn, (float*)d_out);
}

// Round 7
// 2466.857 us; speedup vs baseline: 1.8451x; 1.1165x over previous
//
#include <hip/hip_runtime.h>
#include <hip/hip_bf16.h>

#define TPB 256

constexpr int Bx = 8, Cc = 64, Nn = 207, Tin = 54, Kb = 8;
constexpr int LP = 52, NP = Nn * LP;     // time padded 50->52, flattened node*time positions
constexpr int NPa = 10816;               // NP rounded up to 169*64 for MFMA tiles
constexpr int L50 = 50, Tout = 48;
constexpr int Ee = 512, Pn = 12;
constexpr float EPSF = 1e-5f;
constexpr int SRDF = 520;                // padded row stride for 512-wide f32 LDS rows

// ---------------- workspace layout (floats) ----------------
// ws_size is 256 MiB = 67,108,864 floats; peak usage below = 65,387,648 floats (proven-safe band).
constexpr size_t O_RESID = 0;                                   // [B][64][207][54]
constexpr size_t O_LNTM  = O_RESID + (size_t)Bx*Cc*Nn*Tin;
constexpr size_t O_LNTR  = O_LNTM  + (size_t)Bx*Cc*Nn;
constexpr size_t O_LNSM  = O_LNTR  + (size_t)Bx*Cc*Nn;
constexpr size_t O_LNSR  = O_LNSM  + (size_t)Bx*Cc*Tin;
constexpr size_t O_XCAT  = O_LNSR  + (size_t)Bx*Cc*Tin;         // [B][192][207][54]; later reused as RA + bf16 tail
constexpr size_t O_RB    = O_XCAT  + (size_t)Bx*192*Nn*Tin;     // [B][128][NP]
constexpr size_t O_H     = O_RB    + (size_t)Bx*128*NP;         // [B][64][NP]
constexpr size_t O_GACC  = O_H     + (size_t)Bx*64*NP;          // [B][128][207][48]
constexpr size_t O_GG    = O_GACC  + (size_t)Bx*128*Nn*Tout;    // [B][64][207][48]; later reused as Y
constexpr size_t O_XE    = O_GG    + (size_t)Bx*64*Nn*Tout;     // [B][207][12][512]
constexpr size_t O_WTT   = O_XE    + (size_t)Bx*Nn*Pn*Ee;       // (unused now) 128*192*3
constexpr size_t O_WTM   = O_WTT   + (size_t)128*192*3;         // transposed W_mlp 128*384*3
constexpr size_t O_BNST  = O_WTM   + (size_t)128*384*3;         // 128
constexpr size_t O_WTB   = O_BNST + 128;                        // ushort[128][576] time-conv bf16 weights (outside XCAT!)
// bf16 buffers aliased into the dead tail of XCAT (XCAT dead after timeconv; RA uses first Bx*128*NP floats)
constexpr size_t O_HT    = O_XCAT + (size_t)Bx*128*NP;          // ushort[Bx][NPa][64]
constexpr size_t O_WQ1B  = O_HT   + (size_t)Bx*NPa*64/2;        // ushort[24][64][64]
constexpr size_t O_WV1B  = O_WQ1B + (size_t)24*64*64/2;
constexpr size_t O_WQ2B  = O_WV1B + (size_t)24*64*64/2;         // ushort[24][128][64]
constexpr size_t O_WV2B  = O_WQ2B + (size_t)24*128*64/2;
constexpr size_t O_RBT   = O_WV2B + (size_t)24*128*64/2;        // ushort[Bx][NPa][64]
constexpr size_t O_WQT   = O_RBT  + (size_t)Bx*NPa*64/2;        // ushort[64][64]
constexpr size_t O_WKT   = O_WQT  + 2048;
constexpr size_t O_WVT   = O_WKT  + 2048;
constexpr size_t O_WFCT  = O_WVT  + 2048;                       // ushort[512][512]
constexpr size_t O_WF1T  = O_WFCT + 131072;                     // ushort[256][512]
constexpr size_t O_WF2T  = O_WF1T + 65536;                      // ushort[512][256]

#define FMA4(acc, sA_, vB_) { (acc).x += (sA_)*(vB_).x; (acc).y += (sA_)*(vB_).y; (acc).z += (sA_)*(vB_).z; (acc).w += (sA_)*(vB_).w; }

typedef __attribute__((ext_vector_type(8))) short bf16x8;
typedef __attribute__((ext_vector_type(4))) float f32x4;

__device__ __forceinline__ float sigm(float x){ return 1.0f/(1.0f+__expf(-x)); }
__device__ __forceinline__ ushort f2bf(float x){ __hip_bfloat16 h = __float2bfloat16(x); return *(ushort*)&h; }

// ---------------- residual = W_conv1 @ x + b ----------------
__global__ __launch_bounds__(TPB) void k_residual(const float* __restrict__ x, const float* __restrict__ W,
                                                  const float* __restrict__ bias, float* __restrict__ out){
  int n = blockIdx.x, b = blockIdx.y;
  __shared__ __align__(16) float sX[Cc][Tin];
  __shared__ __align__(16) float sW[Cc*Cc];
  int tid = threadIdx.x;
  for(int i=tid;i<Cc*Tin;i+=TPB){ int c=i/Tin, l=i%Tin; sX[c][l] = x[((size_t)(b*Cc+c)*Nn+n)*Tin+l]; }
  for(int i=tid;i<Cc*Cc;i+=TPB) sW[i]=W[i];
  __syncthreads();
  for(int i=tid;i<Cc*Tin;i+=TPB){
    int o=i/Tin, l=i%Tin; float acc=bias[o];
    #pragma unroll 8
    for(int c=0;c<Cc;c++) acc += sW[o*Cc+c]*sX[c][l];
    out[((size_t)(b*Cc+o)*Nn+n)*Tin+l]=acc;
  }
}

// ---------------- LN stats ----------------
__global__ __launch_bounds__(TPB) void k_lnT(const float* __restrict__ r, float* __restrict__ mean, float* __restrict__ rstd){
  int row = blockIdx.x*TPB + threadIdx.x;
  if(row >= Bx*Cc*Nn) return;
  const float* p = r + (size_t)row*Tin;
  float s=0.f,s2=0.f;
  for(int l=0;l<Tin;l++){ float v=p[l]; s+=v; s2+=v*v; }
  float m=s*(1.f/Tin); float var=s2*(1.f/Tin)-m*m;
  mean[row]=m; rstd[row]=rsqrtf(fmaxf(var,0.f)+EPSF);
}
__global__ __launch_bounds__(TPB) void k_lnS(const float* __restrict__ r, float* __restrict__ mean, float* __restrict__ rstd){
  int row = blockIdx.x*TPB + threadIdx.x;       // (b*Cc+c)*Tin + l
  if(row >= Bx*Cc*Tin) return;
  int l = row % Tin; int bc = row / Tin;
  const float* p = r + (size_t)bc*Nn*Tin + l;
  float s=0.f,s2=0.f;
  for(int n=0;n<Nn;n++){ float v=p[(size_t)n*Tin]; s+=v; s2+=v*v; }
  float m=s*(1.f/Nn); float var=s2*(1.f/Nn)-m*m;
  mean[row]=m; rstd[row]=rsqrtf(fmaxf(var,0.f)+EPSF);
}

// ---------------- xcat = [resid, LN_T, LN_S] ----------------
__global__ __launch_bounds__(TPB) void k_xcat(const float* __restrict__ r, const float* __restrict__ tm, const float* __restrict__ tr,
                                              const float* __restrict__ sm, const float* __restrict__ sr,
                                              const float* __restrict__ gT, const float* __restrict__ bT,
                                              const float* __restrict__ gS, const float* __restrict__ bS,
                                              float* __restrict__ out){
  size_t i = (size_t)blockIdx.x*TPB + threadIdx.x;
  if(i >= (size_t)Bx*192*Nn*Tin) return;
  int l = (int)(i % Tin); size_t r1 = i / Tin; int n = (int)(r1 % Nn); size_t r2 = r1 / Nn;
  int ci = (int)(r2 % 192); int b = (int)(r2 / 192);
  int c = ci & 63; int grp = ci >> 6;
  float v = r[((size_t)(b*Cc+c)*Nn+n)*Tin+l];
  float o;
  if(grp==0) o = v;
  else if(grp==1){ int row=(b*Cc+c)*Nn+n; o = (v-tm[row])*tr[row]*gT[l] + bT[l]; }
  else { int row=(b*Cc+c)*Tin+l; o = (v-sm[row])*sr[row]*gS[n] + bS[n]; }
  out[i]=o;
}

// ---------------- weight transpose: W[o][ci][3] -> WT[(ci*3+kt)*O + o] (for W_mlp) ----------------
__global__ __launch_bounds__(TPB) void k_wt(const float* __restrict__ W, float* __restrict__ WT, int O, int CI){
  int idx = blockIdx.x*TPB + threadIdx.x;
  int total = O*CI*3;
  if(idx>=total) return;
  int kt = idx%3; int r = idx/3; int ci = r%CI; int o = r/CI;
  WT[(size_t)(ci*3+kt)*O + o] = W[idx];
}

// ---------------- time-conv weight convert: W[o][ci][kt] f32 -> WTb[o][kt*192+ci] bf16 ----------------
__global__ __launch_bounds__(TPB) void k_wtb(const float* __restrict__ W, ushort* __restrict__ WTb){
  int i = blockIdx.x*TPB + threadIdx.x;
  if(i >= 128*576) return;
  int o = i/576, r = i%576, kt = r/192, ci = r%192;
  WTb[i] = f2bf(W[(size_t)(o*192+ci)*3 + kt]);
}

// ---------------- gcn weight convert: W[slk][C][D] f32 -> WT[slk][D][C] bf16 ----------------
__global__ __launch_bounds__(TPB) void k_wcvt(const float* __restrict__ W, ushort* __restrict__ WT,
                                              int SLK, int C, int D){
  int i = blockIdx.x*TPB + threadIdx.x;
  if(i >= SLK*C*D) return;
  int d = i % D; int r = i / D; int c = r % C; int slk = r / C;
  WT[((size_t)slk*D + d)*C + c] = f2bf(W[i]);
}

// ---------------- generic transpose convert: W f32 [R][C] -> WT bf16 [C][R] ----------------
__global__ __launch_bounds__(TPB) void k_wtr(const float* __restrict__ W, ushort* __restrict__ WT, int R, int C){
  int i = blockIdx.x*TPB + threadIdx.x;
  if(i >= R*C) return;
  int c = i % C, r = i / C;
  WT[(size_t)c*R + r] = f2bf(W[i]);
}

// ---------------- activation transpose+convert: X f32 [b][C][NP] -> XT bf16 [b][NPa][C] ----------------
template<int C>
__global__ __launch_bounds__(TPB) void k_t2bf(const float* __restrict__ X, ushort* __restrict__ XT){
  int p0 = blockIdx.x*64, b = blockIdx.y;
  int tid = threadIdx.x;
  __shared__ __align__(16) float sT[64][65];
  for(int cc=0; cc<C; cc+=64){
    if(cc) __syncthreads();
    for(int i=tid;i<4096;i+=TPB){ int c=i>>6, col=i&63; int p=p0+col;
      sT[c][col] = (p<NP) ? X[((size_t)(b*C+cc+c))*NP + p] : 0.f; }
    __syncthreads();
    for(int i=tid;i<512;i+=TPB){
      int row=i>>3, c8=(i&7)<<3;
      ushort u[8];
      #pragma unroll
      for(int j=0;j<8;j++) u[j] = f2bf(sT[c8+j][row]);
      *(uint4*)&XT[((size_t)b*NPa + p0 + row)*C + cc + c8] = *(uint4*)u;
    }
  }
}

// ---------------- dilated time conv (dil=2) + GLU via MFMA -> h [B][64][NP] ----------------
// P[t][o] = sum_k X[ci][t+2kt] * W[o][k], k = kt*192+ci (K=576). M=64 t-rows (50 live), N=128 o-cols.
// Wave w owns o-cols {w*16..+15} and {w*16+64..+79} so the GLU pair (c, c+64) is in-register.
__global__ __launch_bounds__(TPB) void k_timeconv_mfma(const float* __restrict__ xcat,
    const ushort* __restrict__ WTb, const float* __restrict__ bias, float* __restrict__ h){
  int n = blockIdx.x, b = blockIdx.y;
  constexpr int XS = 200;                       // row stride (ushorts): bank step 4 -> 2-way (free)
  __shared__ __align__(16) ushort sXT[68*XS];   // [t=0..67][ci=0..191] bf16, rows 54..67 zero
  int tid = threadIdx.x;
  for(int i=tid; i<14*XS; i+=TPB) sXT[54*XS + i] = 0;
  for(int i=tid; i<192*54; i+=TPB){
    int c = i/54, l = i%54;
    float v = xcat[((size_t)(b*192+c)*Nn + n)*Tin + l];
    sXT[l*XS + c] = f2bf(v);
  }
  __syncthreads();
  int lane = tid & 63, w = tid >> 6;
  int r15 = lane & 15, hi = lane >> 4;
  float b0 = bias[w*16 + r15], b1 = bias[w*16 + 64 + r15];
  f32x4 acc0[4], acc1[4];                       // [ttile]; col = o (r15), rows = t
  #pragma unroll
  for(int tt=0;tt<4;tt++){
    acc0[tt][0]=b0; acc0[tt][1]=b0; acc0[tt][2]=b0; acc0[tt][3]=b0;
    acc1[tt][0]=b1; acc1[tt][1]=b1; acc1[tt][2]=b1; acc1[tt][3]=b1;
  }
  const ushort* wp0 = WTb + (size_t)(w*16 + r15)*576;
  const ushort* wp1 = WTb + (size_t)(w*16 + 64 + r15)*576;
  #pragma unroll 2
  for(int ks=0; ks<18; ks++){
    int k0 = ks*32 + hi*8;
    int kt = k0/192, ci0 = k0 - kt*192;         // 8 consecutive ci, never straddles kt
    bf16x8 bw0 = *(const bf16x8*)&wp0[k0];
    bf16x8 bw1 = *(const bf16x8*)&wp1[k0];
    #pragma unroll
    for(int tt=0;tt<4;tt++){
      bf16x8 ax = *(const bf16x8*)&sXT[(tt*16 + r15 + 2*kt)*XS + ci0];
      acc0[tt] = __builtin_amdgcn_mfma_f32_16x16x32_bf16(ax, bw0, acc0[tt], 0,0,0);
      acc1[tt] = __builtin_amdgcn_mfma_f32_16x16x32_bf16(ax, bw1, acc1[tt], 0,0,0);
    }
  }
  float* hp = h + (size_t)b*Cc*NP + (size_t)n*LP;
  int c = w*16 + r15;
  #pragma unroll
  for(int tt=0;tt<4;tt++){
    int t0 = tt*16 + hi*4;
    #pragma unroll
    for(int i=0;i<4;i++){
      int t = t0 + i;
      if(t < L50) hp[(size_t)c*NP + t] = tanhf(acc0[tt][i])*sigm(acc1[tt][i]);
    }
  }
  if(tid < 128){ int cz = tid >> 1, tz = 50 + (tid & 1); hp[(size_t)cz*NP + tz] = 0.f; }
}

// ---------------- gated multi-basis GCN einsum via MFMA ----------------
template<int D>
__global__ __launch_bounds__(TPB) void k_gcs_mfma(const ushort* __restrict__ XT,
    const ushort* __restrict__ wqT, const ushort* __restrict__ wvT,
    float* __restrict__ S){
  int p0 = blockIdx.x*64;
  int b = blockIdx.z;
  int tid = threadIdx.x;
  int lane = tid & 63;
  int d0 = blockIdx.y*64 + ((tid>>6)<<4);      // wave -> 16-wide d strip
  __shared__ __align__(16) ushort sX[64*64];   // [p][c], XOR-swizzled (c8 ^ (row&7)<<3)
  for(int i=tid;i<512;i+=TPB){
    int row=i>>3, c8=(i&7)<<3;
    uint4 v = *(const uint4*)&XT[((size_t)b*NPa + p0 + row)*64 + c8];
    *(uint4*)&sX[row*64 + (c8 ^ ((row&7)<<3))] = v;
  }
  __syncthreads();
  int r15 = lane & 15, hi = lane >> 4;
  bf16x8 bf[4][2];
  #pragma unroll
  for(int pt=0;pt<4;pt++){
    int row = pt*16 + r15;
    int sw = (row&7)<<3;
    int cu0 = hi*8;
    bf[pt][0] = *(const bf16x8*)&sX[row*64 + (cu0 ^ sw)];
    bf[pt][1] = *(const bf16x8*)&sX[row*64 + ((cu0+32) ^ sw)];
  }
  f32x4 acc[4];
  #pragma unroll
  for(int pt=0;pt<4;pt++){ acc[pt][0]=0.f; acc[pt][1]=0.f; acc[pt][2]=0.f; acc[pt][3]=0.f; }
  const ushort* wqp = wqT + ((size_t)(d0 + r15))*64 + hi*8;
  const ushort* wvp = wvT + ((size_t)(d0 + r15))*64 + hi*8;
  for(int k=0;k<Kb;k++){
    bf16x8 aq0 = *(const bf16x8*)&wqp[0];
    bf16x8 aq1 = *(const bf16x8*)&wqp[32];
    bf16x8 av0 = *(const bf16x8*)&wvp[0];
    bf16x8 av1 = *(const bf16x8*)&wvp[32];
    wqp += (size_t)D*64; wvp += (size_t)D*64;
    #pragma unroll
    for(int pt=0;pt<4;pt++){
      f32x4 q; q[0]=0.f;q[1]=0.f;q[2]=0.f;q[3]=0.f;
      f32x4 v; v[0]=0.f;v[1]=0.f;v[2]=0.f;v[3]=0.f;
      q = __builtin_amdgcn_mfma_f32_16x16x32_bf16(aq0, bf[pt][0], q, 0,0,0);
      q = __builtin_amdgcn_mfma_f32_16x16x32_bf16(aq1, bf[pt][1], q, 0,0,0);
      v = __builtin_amdgcn_mfma_f32_16x16x32_bf16(av0, bf[pt][0], v, 0,0,0);
      v = __builtin_amdgcn_mfma_f32_16x16x32_bf16(av1, bf[pt][1], v, 0,0,0);
      #pragma unroll
      for(int i=0;i<4;i++) acc[pt][i] += v[i]*sigm(q[i]);
    }
  }
  #pragma unroll
  for(int pt=0;pt<4;pt++){
    int p = p0 + pt*16 + r15;
    if(p < NP){
      #pragma unroll
      for(int i=0;i<4;i++){
        int d = d0 + hi*4 + i;
        S[((size_t)b*D + d)*NP + p] = acc[pt][i];
      }
    }
  }
}

// ---------------- adjacency aggregation ----------------
template<int RELU>
__global__ __launch_bounds__(TPB) void k_agg(const float* __restrict__ S, const float* __restrict__ adj,
                                             const float* __restrict__ bias, float* __restrict__ Out, int D){
  int d = blockIdx.x, b = blockIdx.y;
  __shared__ __align__(16) float sAdj[69][208];
  __shared__ __align__(16) float sSm[69][52];
  int tid = threadIdx.x;
  int kq[3], lq[3], valid[3];
  #pragma unroll
  for(int m=0;m<3;m++){ int mt = tid + m*TPB; valid[m] = (mt<676); kq[m] = mt/13; lq[m] = mt%13; }
  float acc[3][4][4];
  #pragma unroll
  for(int m=0;m<3;m++)
    #pragma unroll
    for(int a=0;a<4;a++){ acc[m][a][0]=0;acc[m][a][1]=0;acc[m][a][2]=0;acc[m][a][3]=0; }
  const float* Sp = S + ((size_t)b*D + d)*NP;
  for(int ch=0; ch<3; ch++){
    int n0 = ch*69;
    __syncthreads();
    for(int i=tid;i<69*208;i+=TPB){ int nn=i/208, k2=i%208;
      sAdj[nn][k2] = (k2<Nn) ? adj[(size_t)(n0+nn)*Nn + k2] : 0.f; }
    for(int i=tid;i<69*52;i+=TPB){ int nn=i/52, l=i%52;
      sSm[nn][l] = Sp[(size_t)(n0+nn)*LP + l]; }
    __syncthreads();
    for(int nn=0;nn<69;nn++){
      #pragma unroll
      for(int m=0;m<3;m++){
        if(!valid[m]) continue;
        float4 a4 = *(const float4*)&sAdj[nn][kq[m]*4];
        float4 s4 = *(const float4*)&sSm[nn][lq[m]*4];
        float as[4]={a4.x,a4.y,a4.z,a4.w};
        float ss[4]={s4.x,s4.y,s4.z,s4.w};
        #pragma unroll
        for(int ki=0;ki<4;ki++)
          #pragma unroll
          for(int li=0;li<4;li++) acc[m][ki][li] += as[ki]*ss[li];
      }
    }
  }
  float bb = bias[d];
  #pragma unroll
  for(int m=0;m<3;m++){
    if(!valid[m]) continue;
    #pragma unroll
    for(int ki=0;ki<4;ki++){
      int k2 = kq[m]*4+ki;
      if(k2>=Nn) continue;
      #pragma unroll
      for(int li=0;li<4;li++){
        int l = lq[m]*4+li;
        float v = acc[m][ki][li] + bb;
        if(RELU) v = fmaxf(v, 0.f);
        Out[(((size_t)b*D+d)*Nn + k2)*LP + l] = v;
      }
    }
  }
}

// ---------------- MLP conv accumulate (dil=1), per layer ----------------
__global__ __launch_bounds__(TPB) void k_mlpacc(const float* __restrict__ Outs, const float* __restrict__ WT,
                                                float* __restrict__ gacc, int layer){
  int n = blockIdx.x, b = blockIdx.y;
  __shared__ __align__(16) float sO[128][52];
  int tid = threadIdx.x;
  for(int i=tid;i<128*52;i+=TPB){ int c=i/52, l=i%52;
    sO[c][l] = Outs[(((size_t)b*128+c)*Nn + n)*LP + l]; }
  __syncthreads();
  int o = tid & 127, half = tid >> 7;
  int t0 = half*24;
  float acc[24];
  #pragma unroll
  for(int j=0;j<24;j++) acc[j]=0.f;
  const float* wt = WT + (size_t)layer*128*3*128;
  for(int ci=0;ci<128;ci++){
    float w0 = wt[(size_t)(ci*3+0)*128+o];
    float w1 = wt[(size_t)(ci*3+1)*128+o];
    float w2 = wt[(size_t)(ci*3+2)*128+o];
    float sv[26];
    #pragma unroll
    for(int m=0;m<26;m++) sv[m]=sO[ci][t0+m];
    #pragma unroll
    for(int j=0;j<24;j++) acc[j] += w0*sv[j] + w1*sv[j+1] + w2*sv[j+2];
  }
  size_t base = (((size_t)b*128+o)*Nn + n)*Tout + t0;
  if(layer==0){ for(int j=0;j<24;j++) gacc[base+j] = acc[j]; }
  else       { for(int j=0;j<24;j++) gacc[base+j] += acc[j]; }
}

// ---------------- GLU over accumulated MLP conv ----------------
__global__ __launch_bounds__(TPB) void k_glu2(const float* __restrict__ gacc, const float* __restrict__ bm, float* __restrict__ gg){
  size_t i = (size_t)blockIdx.x*TPB + threadIdx.x;
  if(i >= (size_t)Bx*Cc*Nn*Tout) return;
  int t = (int)(i % Tout); size_t r = i / Tout; int n = (int)(r % Nn); size_t r2 = r / Nn;
  int c = (int)(r2 % Cc); int b = (int)(r2 / Cc);
  size_t i1 = (((size_t)b*128+c)*Nn+n)*Tout + t;
  size_t i2 = (((size_t)b*128+c+64)*Nn+n)*Tout + t;
  float a = gacc[i1]+bm[c], b2 = gacc[i2]+bm[c+64];
  gg[i] = tanhf(a)*sigm(b2);
}

// ---------------- patch scramble + emb ----------------
__global__ __launch_bounds__(TPB) void k_xe(const float* __restrict__ gg, const float* __restrict__ emb, float* __restrict__ xe){
  size_t i = (size_t)blockIdx.x*TPB + threadIdx.x;
  if(i >= (size_t)Bx*1271808) return;
  int b = (int)(i / 1271808);
  int off = (int)(i % 1271808);
  int c = off / 19872; int r = off % 19872;
  int n = r / 96; int r2 = r % 96;
  int p = r2 >> 3; int j = r2 & 7;
  int t = p*4 + j;
  float v = 0.f;
  if(t < Tout) v = gg[(((size_t)b*Cc+c)*Nn + n)*Tout + t];
  int e = off & 511; int p2 = (off >> 9) % 12;
  xe[i] = v + emb[(size_t)p2*Ee + e];
}

// ---------------- per-row LN helper (rows of 512, stride SRDF, in LDS) ----------------
__device__ __forceinline__ void ln_rows(float* buf, const float* __restrict__ g, const float* __restrict__ be, int tid){
  int lane = tid & 63, wv = tid >> 6;
  for(int r = wv; r < 12; r += 4){
    float s=0.f, s2=0.f;
    #pragma unroll
    for(int j=0;j<8;j++){ float v = buf[r*SRDF + j*64 + lane]; s+=v; s2+=v*v; }
    #pragma unroll
    for(int off=32; off; off>>=1){ s += __shfl_xor(s,off); s2 += __shfl_xor(s2,off); }
    float m = s*(1.f/512.f);
    float rstd = rsqrtf(fmaxf(s2*(1.f/512.f)-m*m, 0.f)+EPSF);
    #pragma unroll
    for(int j=0;j<8;j++){ int e = j*64+lane; float v = buf[r*SRDF+e];
      buf[r*SRDF+e] = (v-m)*rstd*g[e] + be[e]; }
  }
}

// ---------------- fused per-(b,n) transformer, MFMA GEMM phases ----------------
__global__ __launch_bounds__(TPB,2) void k_attn(
    const float* __restrict__ xe, const float* __restrict__ resid,
    const ushort* __restrict__ WqT, const float* __restrict__ bq,
    const ushort* __restrict__ WkT, const float* __restrict__ bk,
    const ushort* __restrict__ WvT, const float* __restrict__ bv,
    const ushort* __restrict__ WfcT, const float* __restrict__ bfc,
    const float* __restrict__ g1, const float* __restrict__ b1n,
    const float* __restrict__ g2, const float* __restrict__ b2n,
    const ushort* __restrict__ Wff1T, const float* __restrict__ bff1,
    const ushort* __restrict__ Wff2T, const float* __restrict__ bff2,
    const float* __restrict__ Wrp, const float* __restrict__ brp,
    float* __restrict__ y)
{
  int n = blockIdx.x, b = blockIdx.y;
  __shared__ __align__(16) ushort SbX[16*512];
  __shared__ __align__(16) ushort Mb[16*256];
  __shared__ __align__(16) float U0[12*SRDF];
  __shared__ __align__(16) float U1[12*SRDF];
  __shared__ __align__(16) float sS[1160];
  int tid = threadIdx.x;
  int lane = tid & 63, w = tid >> 6;
  int r15 = lane & 15, hi = lane >> 4;
  const float* __restrict__ xeg = xe + ((size_t)b*Nn + n)*6144;

  for(int i=tid;i<1024;i+=TPB){
    int r = i>>6, ch = i&63;
    ushort u[8];
    if(r<12){
      const float* s = &xeg[r*512 + ch*8];
      #pragma unroll
      for(int j=0;j<8;j++) u[j] = f2bf(s[j]);
    } else {
      #pragma unroll
      for(int j=0;j<8;j++) u[j] = 0;
    }
    *(uint4*)&SbX[r*512 + ((ch ^ (r&7))<<3)] = *(uint4*)u;
  }
  for(int i=tid;i<128;i+=TPB){
    int r = 12 + (i>>5), ch = i&31;
    uint4 z; z.x=0;z.y=0;z.z=0;z.w=0;
    *(uint4*)&Mb[r*256 + ch*8] = z;
  }
  __syncthreads();

  f32x4 vfrag[2][4];
  #pragma unroll
  for(int h2=0;h2<2;h2++){
    int head = w*2 + h2;
    bf16x8 a0, a1;
    { int ch0 = head*8 + hi, ch1 = head*8 + 4 + hi;
      a0 = *(const bf16x8*)&SbX[r15*512 + ((ch0 ^ (r15&7))<<3)];
      a1 = *(const bf16x8*)&SbX[r15*512 + ((ch1 ^ (r15&7))<<3)]; }
    #pragma unroll
    for(int nt=0;nt<4;nt++){
      int col = nt*16 + r15;
      float bb = bq[col];
      f32x4 acc; acc[0]=bb;acc[1]=bb;acc[2]=bb;acc[3]=bb;
      acc = __builtin_amdgcn_mfma_f32_16x16x32_bf16(a0, *(const bf16x8*)&WqT[(size_t)col*64 + hi*8], acc, 0,0,0);
      acc = __builtin_amdgcn_mfma_f32_16x16x32_bf16(a1, *(const bf16x8*)&WqT[(size_t)col*64 + 32 + hi*8], acc, 0,0,0);
      #pragma unroll
      for(int i2=0;i2<4;i2++){ int p = hi*4+i2; if(p<12) U0[p*SRDF + head*64 + col] = acc[i2]; }
    }
    #pragma unroll
    for(int nt=0;nt<4;nt++){
      int col = nt*16 + r15;
      float bb = bk[col];
      f32x4 acc; acc[0]=bb;acc[1]=bb;acc[2]=bb;acc[3]=bb;
      acc = __builtin_amdgcn_mfma_f32_16x16x32_bf16(a0, *(const bf16x8*)&WkT[(size_t)col*64 + hi*8], acc, 0,0,0);
      acc = __builtin_amdgcn_mfma_f32_16x16x32_bf16(a1, *(const bf16x8*)&WkT[(size_t)col*64 + 32 + hi*8], acc, 0,0,0);
      #pragma unroll
      for(int i2=0;i2<4;i2++){ int p = hi*4+i2; if(p<12) U1[p*SRDF + head*64 + col] = acc[i2]; }
    }
    #pragma unroll
    for(int nt=0;nt<4;nt++){
      int col = nt*16 + r15;
      float bb = bv[col];
      f32x4 acc; acc[0]=bb;acc[1]=bb;acc[2]=bb;acc[3]=bb;
      acc = __builtin_amdgcn_mfma_f32_16x16x32_bf16(a0, *(const bf16x8*)&WvT[(size_t)col*64 + hi*8], acc, 0,0,0);
      acc = __builtin_amdgcn_mfma_f32_16x16x32_bf16(a1, *(const bf16x8*)&WvT[(size_t)col*64 + 32 + hi*8], acc, 0,0,0);
      vfrag[h2][nt] = acc;
    }
  }
  __syncthreads();

  const float scale = 0.04419417382415922f;   // 1/sqrt(512)
  for(int i=tid;i<1152;i+=TPB){
    int q = i%12, kh = i/12; int h2 = kh&7, k2 = kh>>3;
    const float* qp = &U0[q*SRDF + h2*64];
    const float* kp = &U1[k2*SRDF + h2*64];
    float s=0.f;
    #pragma unroll
    for(int d4=0; d4<16; d4++){
      float4 a4 = *(const float4*)&qp[d4*4];
      float4 b4 = *(const float4*)&kp[d4*4];
      s += a4.x*b4.x + a4.y*b4.y + a4.z*b4.z + a4.w*b4.w;
    }
    sS[i] = s*scale;
  }
  __syncthreads();
  #pragma unroll
  for(int h2=0;h2<2;h2++){
    int head = w*2 + h2;
    #pragma unroll
    for(int nt=0;nt<4;nt++){
      int col = nt*16 + r15;
      #pragma unroll
      for(int i2=0;i2<4;i2++){ int p = hi*4+i2; if(p<12) U0[p*SRDF + head*64 + col] = vfrag[h2][nt][i2]; }
    }
  }
  if(tid<96){
    float mx=-1e30f;
    for(int q=0;q<12;q++) mx = fmaxf(mx, sS[tid*12+q]);
    float sm=0.f;
    for(int q=0;q<12;q++){ float e = __expf(sS[tid*12+q]-mx); sS[tid*12+q]=e; sm+=e; }
    float inv = 1.f/sm;
    for(int q=0;q<12;q++) sS[tid*12+q] *= inv;
  }
  __syncthreads();

  for(int i=tid;i<6144;i+=TPB){
    int q=i>>9, h2=(i>>6)&7, d=i&63;
    float s=0.f;
    #pragma unroll
    for(int k2=0;k2<12;k2++) s += sS[(k2*8+h2)*12+q]*U0[k2*SRDF+h2*64+d];
    int kk = i & 511;
    SbX[q*512 + (((kk>>3) ^ (q&7))<<3) + (kk&7)] = f2bf(s);
  }
  __syncthreads();

  {
    f32x4 acc[8];
    #pragma unroll
    for(int nt=0;nt<8;nt++){ float bb = bfc[(w*8+nt)*16 + r15]; acc[nt][0]=bb;acc[nt][1]=bb;acc[nt][2]=bb;acc[nt][3]=bb; }
    for(int ks=0;ks<16;ks++){
      int ch = ks*4 + hi;
      bf16x8 a = *(const bf16x8*)&SbX[r15*512 + ((ch ^ (r15&7))<<3)];
      #pragma unroll
      for(int nt=0;nt<8;nt++){
        int col = (w*8+nt)*16 + r15;
        acc[nt] = __builtin_amdgcn_mfma_f32_16x16x32_bf16(a, *(const bf16x8*)&WfcT[(size_t)col*512 + ks*32 + hi*8], acc[nt], 0,0,0);
      }
    }
    #pragma unroll
    for(int nt=0;nt<8;nt++){
      int col = (w*8+nt)*16 + r15;
      #pragma unroll
      for(int i2=0;i2<4;i2++){ int p = hi*4+i2; if(p<12) U1[p*SRDF + col] = acc[nt][i2] + xeg[p*512 + col]; }
    }
  }
  __syncthreads();
  ln_rows(U1, g1, b1n, tid);     // M in U1
  __syncthreads();

  for(int i=tid;i<6144;i+=TPB){
    int r=i>>9, kk=i&511;
    SbX[r*512 + (((kk>>3) ^ (r&7))<<3) + (kk&7)] = f2bf(U1[r*SRDF + kk]);
  }
  __syncthreads();

  {
    f32x4 acc[4];
    #pragma unroll
    for(int nt=0;nt<4;nt++){ float bb = bff1[(w*4+nt)*16 + r15]; acc[nt][0]=bb;acc[nt][1]=bb;acc[nt][2]=bb;acc[nt][3]=bb; }
    for(int ks=0;ks<16;ks++){
      int ch = ks*4 + hi;
      bf16x8 a = *(const bf16x8*)&SbX[r15*512 + ((ch ^ (r15&7))<<3)];
      #pragma unroll
      for(int nt=0;nt<4;nt++){
        int col = (w*4+nt)*16 + r15;
        acc[nt] = __builtin_amdgcn_mfma_f32_16x16x32_bf16(a, *(const bf16x8*)&Wff1T[(size_t)col*512 + ks*32 + hi*8], acc[nt], 0,0,0);
      }
    }
    #pragma unroll
    for(int nt=0;nt<4;nt++){
      int u = (w*4+nt)*16 + r15;
      #pragma unroll
      for(int i2=0;i2<4;i2++){
        int p = hi*4+i2;
        if(p<12) Mb[p*256 + (((u>>3) ^ (p&7))<<3) + (u&7)] = f2bf(fmaxf(acc[nt][i2], 0.f));
      }
    }
  }
  __syncthreads();

  {
    f32x4 acc[8];
    #pragma unroll
    for(int nt=0;nt<8;nt++){ float bb = bff2[(w*8+nt)*16 + r15]; acc[nt][0]=bb;acc[nt][1]=bb;acc[nt][2]=bb;acc[nt][3]=bb; }
    for(int ks=0;ks<8;ks++){
      int ch = ks*4 + hi;
      bf16x8 a = *(const bf16x8*)&Mb[r15*256 + ((ch ^ (r15&7))<<3)];
      #pragma unroll
      for(int nt=0;nt<8;nt++){
        int col = (w*8+nt)*16 + r15;
        acc[nt] = __builtin_amdgcn_mfma_f32_16x16x32_bf16(a, *(const bf16x8*)&Wff2T[(size_t)col*256 + ks*32 + hi*8], acc[nt], 0,0,0);
      }
    }
    #pragma unroll
    for(int nt=0;nt<8;nt++){
      int col = (w*8+nt)*16 + r15;
      #pragma unroll
      for(int i2=0;i2<4;i2++){ int p = hi*4+i2; if(p<12) U0[p*SRDF + col] = acc[nt][i2] + U1[p*SRDF + col]; }
    }
  }
  __syncthreads();
  ln_rows(U0, g2, b2n, tid);     // U in U0
  __syncthreads();

  for(int i=tid;i<6144;i+=TPB){
    int r=i>>9, c=i&511;
    U1[r*SRDF+c] = U0[r*SRDF+c] + U1[r*SRDF+c] + xeg[r*512+c];
  }
  __syncthreads();
  for(int i=tid;i<4608;i+=TPB) U0[i] = Wrp[i];
  __syncthreads();
  #pragma unroll
  for(int j=0;j<3;j++){
    int i4 = tid + j*TPB;
    int c = i4/12, tq = i4%12; int t0 = tq*4;
    float4 acc = *(const float4*)&brp[t0];
    for(int t96=0;t96<96;t96++){
      int f = c*96 + t96;
      float a = U1[(f>>9)*SRDF + (f&511)];
      float4 w4 = *(const float4*)&U0[t96*48 + t0];
      FMA4(acc, a, w4);
    }
    size_t rb = (((size_t)b*Cc+c)*Nn + n)*Tin + 6 + t0;
    acc.x += resid[rb+0]; acc.y += resid[rb+1]; acc.z += resid[rb+2]; acc.w += resid[rb+3];
    *(float4*)&y[(((size_t)b*Cc+c)*Nn + n)*Tout + t0] = acc;
  }
}

// ---------------- batchnorm ----------------
__global__ __launch_bounds__(TPB) void k_bnstats(const float* __restrict__ y, float* __restrict__ stats){
  int c = blockIdx.x; int tid = threadIdx.x;
  float s=0.f,s2=0.f;
  const int per = Nn*Tout;   // 9936
  for(int idx=tid; idx<Bx*per; idx+=TPB){
    int b = idx/per, r = idx%per;
    float v = y[((size_t)b*Cc+c)*per + r];
    s+=v; s2+=v*v;
  }
  __shared__ float rs[TPB], rs2[TPB];
  rs[tid]=s; rs2[tid]=s2; __syncthreads();
  for(int off=TPB/2; off; off>>=1){ if(tid<off){ rs[tid]+=rs[tid+off]; rs2[tid]+=rs2[tid+off]; } __syncthreads(); }
  if(tid==0){
    float m = rs[0]/(float)(Bx*per);
    float var = rs2[0]/(float)(Bx*per) - m*m;
    stats[c]=m; stats[64+c]=rsqrtf(fmaxf(var,0.f)+EPSF);
  }
}
__global__ __launch_bounds__(TPB) void k_bnout(const float* __restrict__ y, const float* __restrict__ stats,
                                               const float* __restrict__ gbn, const float* __restrict__ bbn,
                                               float* __restrict__ out){
  size_t i = (size_t)blockIdx.x*TPB + threadIdx.x;
  if(i >= (size_t)Bx*Cc*Nn*Tout) return;
  int c = (int)((i/(Nn*Tout))%Cc);
  out[i] = (y[i]-stats[c])*stats[64+c]*gbn[c] + bbn[c];
}

// ---------------- launch ----------------
extern "C" void kernel_launch(void* const* d_in, const int* in_sizes, int n_in,
                              void* d_out, int out_size, void* d_ws, size_t ws_size,
                              hipStream_t stream) {
  const float* x      = (const float*)d_in[0];
  const float* adj    = (const float*)d_in[1];
  const float* Wconv1 = (const float*)d_in[2];
  const float* bconv1 = (const float*)d_in[3];
  const float* gT     = (const float*)d_in[4];
  const float* bT     = (const float*)d_in[5];
  const float* gS     = (const float*)d_in[6];
  const float* bS     = (const float*)d_in[7];
  const float* Wtime  = (const float*)d_in[8];
  const float* btime  = (const float*)d_in[9];
  const float* wq1    = (const float*)d_in[10];
  const float* wv1    = (const float*)d_in[11];
  const float* bias1  = (const float*)d_in[12];
  const float* wq2    = (const float*)d_in[13];
  const float* wv2    = (const float*)d_in[14];
  const float* bias2  = (const float*)d_in[15];
  const float* Wmlp   = (const float*)d_in[16];
  const float* bmlp   = (const float*)d_in[17];
  const float* embT   = (const float*)d_in[18];
  const float* Wq     = (const float*)d_in[19];
  const float* bq     = (const float*)d_in[20];
  const float* Wk     = (const float*)d_in[21];
  const float* bk     = (const float*)d_in[22];
  const float* Wv     = (const float*)d_in[23];
  const float* bv     = (const float*)d_in[24];
  const float* Wfc    = (const float*)d_in[25];
  const float* bfc    = (const float*)d_in[26];
  const float* g1     = (const float*)d_in[27];
  const float* b1n    = (const float*)d_in[28];
  const float* g2     = (const float*)d_in[29];
  const float* b2n    = (const float*)d_in[30];
  const float* Wff1   = (const float*)d_in[31];
  const float* bff1   = (const float*)d_in[32];
  const float* Wff2   = (const float*)d_in[33];
  const float* bff2   = (const float*)d_in[34];
  const float* Wrp    = (const float*)d_in[35];
  const float* brp    = (const float*)d_in[36];
  const float* gbn    = (const float*)d_in[37];
  const float* bbn    = (const float*)d_in[38];

  float* ws = (float*)d_ws;
  float* RESID = ws + O_RESID;
  float* LNTM  = ws + O_LNTM;
  float* LNTR  = ws + O_LNTR;
  float* LNSM  = ws + O_LNSM;
  float* LNSR  = ws + O_LNSR;
  float* XCAT  = ws + O_XCAT;
  float* RA    = ws + O_XCAT;    // overlays XCAT after it is consumed
  float* RB    = ws + O_RB;
  float* H     = ws + O_H;
  float* GACC  = ws + O_GACC;
  float* GG    = ws + O_GG;
  float* Y     = ws + O_GG;      // overlays GG after xe built
  float* XE    = ws + O_XE;
  float* WTM   = ws + O_WTM;
  float* BNST  = ws + O_BNST;
  ushort* WTB  = (ushort*)(ws + O_WTB);
  ushort* HT   = (ushort*)(ws + O_HT);
  ushort* WQ1B = (ushort*)(ws + O_WQ1B);
  ushort* WV1B = (ushort*)(ws + O_WV1B);
  ushort* WQ2B = (ushort*)(ws + O_WQ2B);
  ushort* WV2B = (ushort*)(ws + O_WV2B);
  ushort* RBT  = (ushort*)(ws + O_RBT);
  ushort* WQT  = (ushort*)(ws + O_WQT);
  ushort* WKT  = (ushort*)(ws + O_WKT);
  ushort* WVT  = (ushort*)(ws + O_WVT);
  ushort* WFCT = (ushort*)(ws + O_WFCT);
  ushort* WF1T = (ushort*)(ws + O_WF1T);
  ushort* WF2T = (ushort*)(ws + O_WF2T);

  k_residual<<<dim3(Nn,Bx),TPB,0,stream>>>(x, Wconv1, bconv1, RESID);
  k_lnT<<<(Bx*Cc*Nn)/TPB,TPB,0,stream>>>(RESID, LNTM, LNTR);
  k_lnS<<<(Bx*Cc*Tin)/TPB,TPB,0,stream>>>(RESID, LNSM, LNSR);
  k_xcat<<<(Bx*192*Nn*Tin)/TPB,TPB,0,stream>>>(RESID, LNTM, LNTR, LNSM, LNSR, gT,bT,gS,bS, XCAT);
  k_wtb<<<(128*576+TPB-1)/TPB,TPB,0,stream>>>(Wtime, WTB);
  k_wt<<<(128*384*3+TPB-1)/TPB,TPB,0,stream>>>(Wmlp,  WTM, 128, 384);
  k_timeconv_mfma<<<dim3(Nn,Bx),TPB,0,stream>>>(XCAT, WTB, btime, H);

  // bf16 weight converts (into dead XCAT tail -- must be after timeconv)
  k_wcvt<<<(24*64*64+TPB-1)/TPB,TPB,0,stream>>>(wq1, WQ1B, 24, 64, 64);
  k_wcvt<<<(24*64*64+TPB-1)/TPB,TPB,0,stream>>>(wv1, WV1B, 24, 64, 64);
  k_wcvt<<<(24*64*128+TPB-1)/TPB,TPB,0,stream>>>(wq2, WQ2B, 24, 64, 128);
  k_wcvt<<<(24*64*128+TPB-1)/TPB,TPB,0,stream>>>(wv2, WV2B, 24, 64, 128);
  k_wtr<<<(64*64+TPB-1)/TPB,TPB,0,stream>>>(Wq, WQT, 64, 64);
  k_wtr<<<(64*64+TPB-1)/TPB,TPB,0,stream>>>(Wk, WKT, 64, 64);
  k_wtr<<<(64*64+TPB-1)/TPB,TPB,0,stream>>>(Wv, WVT, 64, 64);
  k_wtr<<<(512*512+TPB-1)/TPB,TPB,0,stream>>>(Wfc, WFCT, 512, 512);
  k_wtr<<<(512*256+TPB-1)/TPB,TPB,0,stream>>>(Wff1, WF1T, 512, 256);
  k_wtr<<<(256*512+TPB-1)/TPB,TPB,0,stream>>>(Wff2, WF2T, 256, 512);
  k_t2bf<64><<<dim3(169,Bx),TPB,0,stream>>>(H, HT);

  for(int i=0;i<3;i++){
    k_gcs_mfma<64><<<dim3(169,1,Bx),TPB,0,stream>>>(HT, WQ1B+(size_t)i*8*64*64, WV1B+(size_t)i*8*64*64, RA);
    k_agg<1><<<dim3(64,Bx),TPB,0,stream>>>(RA, adj+(size_t)i*Nn*Nn, bias1+(size_t)i*64,  RB, 64);
    k_t2bf<64><<<dim3(169,Bx),TPB,0,stream>>>(RB, RBT);
    k_gcs_mfma<128><<<dim3(169,2,Bx),TPB,0,stream>>>(RBT, WQ2B+(size_t)i*8*128*64, WV2B+(size_t)i*8*128*64, RA);
    k_agg<0><<<dim3(128,Bx),TPB,0,stream>>>(RA, adj+(size_t)i*Nn*Nn, bias2+(size_t)i*128, RB, 128);
    k_mlpacc<<<dim3(Nn,Bx),TPB,0,stream>>>(RB, WTM, GACC, i);
  }
  k_glu2<<<(Bx*Cc*Nn*Tout)/TPB,TPB,0,stream>>>(GACC, bmlp, GG);
  k_xe<<<(Bx*1271808)/TPB,TPB,0,stream>>>(GG, embT, XE);
  k_attn<<<dim3(Nn,Bx),TPB,0,stream>>>(XE, RESID, WQT,bq, WKT,bk, WVT,bv, WFCT,bfc,
                                       g1,b1n,g2,b2n, WF1T,bff1, WF2T,bff2, Wrp,brp, Y);
  k_bnstats<<<64,TPB,0,stream>>>(Y, BNST);
  k_bnout<<<(Bx*Cc*Nn*Tout)/TPB,TPB,0,stream>>>(Y, BNST, gbn, bbn, (float*)d_out);
}

// Round 8
// 1611.558 us; speedup vs baseline: 2.8243x; 1.5307x over previous
//
#include <hip/hip_runtime.h>
#include <hip/hip_bf16.h>

#define TPB 256

constexpr int Bx = 8, Cc = 64, Nn = 207, Tin = 54, Kb = 8;
constexpr int LP = 52, NP = Nn * LP;     // time padded 50->52, flattened node*time positions
constexpr int NPa = 10816;               // NP rounded up to 169*64 for MFMA tiles
constexpr int L50 = 50, Tout = 48;
constexpr int Ee = 512, Pn = 12;
constexpr float EPSF = 1e-5f;
constexpr int SRDF = 520;                // padded row stride for 512-wide f32 LDS rows

// ---------------- workspace layout (floats) ----------------
// ws_size is 256 MiB = 67,108,864 floats; peak usage below = 65,457,536 floats (audited).
constexpr size_t O_RESID = 0;                                   // [B][64][207][54]
constexpr size_t O_LNTM  = O_RESID + (size_t)Bx*Cc*Nn*Tin;
constexpr size_t O_LNTR  = O_LNTM  + (size_t)Bx*Cc*Nn;
constexpr size_t O_LNSM  = O_LNTR  + (size_t)Bx*Cc*Nn;
constexpr size_t O_LNSR  = O_LNSM  + (size_t)Bx*Cc*Tin;
constexpr size_t O_XCAT  = O_LNSR  + (size_t)Bx*Cc*Tin;         // [B][192][207][54]; later reused as RA + bf16 tail
constexpr size_t O_RB    = O_XCAT  + (size_t)Bx*192*Nn*Tin;     // [B][128][NP]
constexpr size_t O_H     = O_RB    + (size_t)Bx*128*NP;         // [B][64][NP]
constexpr size_t O_GACC  = O_H     + (size_t)Bx*64*NP;          // [B][128][207][48]
constexpr size_t O_GG    = O_GACC  + (size_t)Bx*128*Nn*Tout;    // [B][64][207][48]; later reused as Y
constexpr size_t O_XE    = O_GG    + (size_t)Bx*64*Nn*Tout;     // [B][207][12][512]; ALSO ST bf16 scratch during GCN loop
constexpr size_t O_WTT   = O_XE    + (size_t)Bx*Nn*Pn*Ee;       // (unused now) 128*192*3
constexpr size_t O_WTM   = O_WTT   + (size_t)128*192*3;         // transposed W_mlp 128*384*3
constexpr size_t O_BNST  = O_WTM   + (size_t)128*384*3;         // 128
constexpr size_t O_WTB   = O_BNST + 128;                        // ushort[128][576] time-conv bf16 weights
constexpr size_t O_ADJT  = O_WTB  + (size_t)128*576/2;          // ushort[3][208][224] adj^T bf16 padded
// bf16 buffers aliased into the dead tail of XCAT (XCAT dead after timeconv; RA uses first Bx*128*NP floats)
constexpr size_t O_HT    = O_XCAT + (size_t)Bx*128*NP;          // ushort[Bx][NPa][64]
constexpr size_t O_WQ1B  = O_HT   + (size_t)Bx*NPa*64/2;        // ushort[24][64][64]
constexpr size_t O_WV1B  = O_WQ1B + (size_t)24*64*64/2;
constexpr size_t O_WQ2B  = O_WV1B + (size_t)24*64*64/2;         // ushort[24][128][64]
constexpr size_t O_WV2B  = O_WQ2B + (size_t)24*128*64/2;
constexpr size_t O_RBT   = O_WV2B + (size_t)24*128*64/2;        // ushort[Bx][NPa][64]
constexpr size_t O_WQT   = O_RBT  + (size_t)Bx*NPa*64/2;        // ushort[64][64]
constexpr size_t O_WKT   = O_WQT  + 2048;
constexpr size_t O_WVT   = O_WKT  + 2048;
constexpr size_t O_WFCT  = O_WVT  + 2048;                       // ushort[512][512]
constexpr size_t O_WF1T  = O_WFCT + 131072;                     // ushort[256][512]
constexpr size_t O_WF2T  = O_WF1T + 65536;                      // ushort[512][256]

#define FMA4(acc, sA_, vB_) { (acc).x += (sA_)*(vB_).x; (acc).y += (sA_)*(vB_).y; (acc).z += (sA_)*(vB_).z; (acc).w += (sA_)*(vB_).w; }

typedef __attribute__((ext_vector_type(8))) short bf16x8;
typedef __attribute__((ext_vector_type(4))) float f32x4;

__device__ __forceinline__ float sigm(float x){ return 1.0f/(1.0f+__expf(-x)); }
__device__ __forceinline__ ushort f2bf(float x){ __hip_bfloat16 h = __float2bfloat16(x); return *(ushort*)&h; }

// ---------------- residual = W_conv1 @ x + b ----------------
__global__ __launch_bounds__(TPB) void k_residual(const float* __restrict__ x, const float* __restrict__ W,
                                                  const float* __restrict__ bias, float* __restrict__ out){
  int n = blockIdx.x, b = blockIdx.y;
  __shared__ __align__(16) float sX[Cc][Tin];
  __shared__ __align__(16) float sW[Cc*Cc];
  int tid = threadIdx.x;
  for(int i=tid;i<Cc*Tin;i+=TPB){ int c=i/Tin, l=i%Tin; sX[c][l] = x[((size_t)(b*Cc+c)*Nn+n)*Tin+l]; }
  for(int i=tid;i<Cc*Cc;i+=TPB) sW[i]=W[i];
  __syncthreads();
  for(int i=tid;i<Cc*Tin;i+=TPB){
    int o=i/Tin, l=i%Tin; float acc=bias[o];
    #pragma unroll 8
    for(int c=0;c<Cc;c++) acc += sW[o*Cc+c]*sX[c][l];
    out[((size_t)(b*Cc+o)*Nn+n)*Tin+l]=acc;
  }
}

// ---------------- LN stats ----------------
__global__ __launch_bounds__(TPB) void k_lnT(const float* __restrict__ r, float* __restrict__ mean, float* __restrict__ rstd){
  int row = blockIdx.x*TPB + threadIdx.x;
  if(row >= Bx*Cc*Nn) return;
  const float* p = r + (size_t)row*Tin;
  float s=0.f,s2=0.f;
  for(int l=0;l<Tin;l++){ float v=p[l]; s+=v; s2+=v*v; }
  float m=s*(1.f/Tin); float var=s2*(1.f/Tin)-m*m;
  mean[row]=m; rstd[row]=rsqrtf(fmaxf(var,0.f)+EPSF);
}
__global__ __launch_bounds__(TPB) void k_lnS(const float* __restrict__ r, float* __restrict__ mean, float* __restrict__ rstd){
  int row = blockIdx.x*TPB + threadIdx.x;       // (b*Cc+c)*Tin + l
  if(row >= Bx*Cc*Tin) return;
  int l = row % Tin; int bc = row / Tin;
  const float* p = r + (size_t)bc*Nn*Tin + l;
  float s=0.f,s2=0.f;
  for(int n=0;n<Nn;n++){ float v=p[(size_t)n*Tin]; s+=v; s2+=v*v; }
  float m=s*(1.f/Nn); float var=s2*(1.f/Nn)-m*m;
  mean[row]=m; rstd[row]=rsqrtf(fmaxf(var,0.f)+EPSF);
}

// ---------------- xcat = [resid, LN_T, LN_S] ----------------
__global__ __launch_bounds__(TPB) void k_xcat(const float* __restrict__ r, const float* __restrict__ tm, const float* __restrict__ tr,
                                              const float* __restrict__ sm, const float* __restrict__ sr,
                                              const float* __restrict__ gT, const float* __restrict__ bT,
                                              const float* __restrict__ gS, const float* __restrict__ bS,
                                              float* __restrict__ out){
  size_t i = (size_t)blockIdx.x*TPB + threadIdx.x;
  if(i >= (size_t)Bx*192*Nn*Tin) return;
  int l = (int)(i % Tin); size_t r1 = i / Tin; int n = (int)(r1 % Nn); size_t r2 = r1 / Nn;
  int ci = (int)(r2 % 192); int b = (int)(r2 / 192);
  int c = ci & 63; int grp = ci >> 6;
  float v = r[((size_t)(b*Cc+c)*Nn+n)*Tin+l];
  float o;
  if(grp==0) o = v;
  else if(grp==1){ int row=(b*Cc+c)*Nn+n; o = (v-tm[row])*tr[row]*gT[l] + bT[l]; }
  else { int row=(b*Cc+c)*Tin+l; o = (v-sm[row])*sr[row]*gS[n] + bS[n]; }
  out[i]=o;
}

// ---------------- weight transpose: W[o][ci][3] -> WT[(ci*3+kt)*O + o] (for W_mlp) ----------------
__global__ __launch_bounds__(TPB) void k_wt(const float* __restrict__ W, float* __restrict__ WT, int O, int CI){
  int idx = blockIdx.x*TPB + threadIdx.x;
  int total = O*CI*3;
  if(idx>=total) return;
  int kt = idx%3; int r = idx/3; int ci = r%CI; int o = r/CI;
  WT[(size_t)(ci*3+kt)*O + o] = W[idx];
}

// ---------------- time-conv weight convert: W[o][ci][kt] f32 -> WTb[o][kt*192+ci] bf16 ----------------
__global__ __launch_bounds__(TPB) void k_wtb(const float* __restrict__ W, ushort* __restrict__ WTb){
  int i = blockIdx.x*TPB + threadIdx.x;
  if(i >= 128*576) return;
  int o = i/576, r = i%576, kt = r/192, ci = r%192;
  WTb[i] = f2bf(W[(size_t)(o*192+ci)*3 + kt]);
}

// ---------------- adj transpose convert: adjT[s][k2][n] = bf16(adj[s][n][k2]), zero-padded ----------------
__global__ __launch_bounds__(TPB) void k_wadj(const float* __restrict__ adj, ushort* __restrict__ adjT){
  int i = blockIdx.x*TPB + threadIdx.x;
  if(i >= 3*208*224) return;
  int n = i % 224; int r = i / 224; int k2 = r % 208; int s = r / 208;
  float v = (k2 < Nn && n < Nn) ? adj[((size_t)s*Nn + n)*Nn + k2] : 0.f;
  adjT[i] = f2bf(v);
}

// ---------------- gcn weight convert: W[slk][C][D] f32 -> WT[slk][D][C] bf16 ----------------
__global__ __launch_bounds__(TPB) void k_wcvt(const float* __restrict__ W, ushort* __restrict__ WT,
                                              int SLK, int C, int D){
  int i = blockIdx.x*TPB + threadIdx.x;
  if(i >= SLK*C*D) return;
  int d = i % D; int r = i / D; int c = r % C; int slk = r / C;
  WT[((size_t)slk*D + d)*C + c] = f2bf(W[i]);
}

// ---------------- generic transpose convert: W f32 [R][C] -> WT bf16 [C][R] ----------------
__global__ __launch_bounds__(TPB) void k_wtr(const float* __restrict__ W, ushort* __restrict__ WT, int R, int C){
  int i = blockIdx.x*TPB + threadIdx.x;
  if(i >= R*C) return;
  int c = i % C, r = i / C;
  WT[(size_t)c*R + r] = f2bf(W[i]);
}

// ---------------- activation transpose+convert: X f32 [b][C][NP] -> XT bf16 [b][NPa][C] ----------------
template<int C>
__global__ __launch_bounds__(TPB) void k_t2bf(const float* __restrict__ X, ushort* __restrict__ XT){
  int p0 = blockIdx.x*64, b = blockIdx.y;
  int tid = threadIdx.x;
  __shared__ __align__(16) float sT[64][65];
  for(int cc=0; cc<C; cc+=64){
    if(cc) __syncthreads();
    for(int i=tid;i<4096;i+=TPB){ int c=i>>6, col=i&63; int p=p0+col;
      sT[c][col] = (p<NP) ? X[((size_t)(b*C+cc+c))*NP + p] : 0.f; }
    __syncthreads();
    for(int i=tid;i<512;i+=TPB){
      int row=i>>3, c8=(i&7)<<3;
      ushort u[8];
      #pragma unroll
      for(int j=0;j<8;j++) u[j] = f2bf(sT[c8+j][row]);
      *(uint4*)&XT[((size_t)b*NPa + p0 + row)*C + cc + c8] = *(uint4*)u;
    }
  }
}

// ---------------- S transpose: S f32 [bd][n][l] -> ST bf16 [bd][l][224] (n-padded) ----------------
__global__ __launch_bounds__(TPB) void k_st(const float* __restrict__ S, ushort* __restrict__ ST, int D){
  int d = blockIdx.x, b = blockIdx.y;
  int bd = b*D + d;
  __shared__ __align__(16) float sT[64][53];
  int tid = threadIdx.x;
  const float* Sp = S + (size_t)bd*NP;
  ushort* STp = ST + (size_t)bd*52*224;
  for(int ch=0; ch<4; ch++){
    int n0 = ch*64;
    int cs = (207 - n0 < 64) ? (207 - n0) : 64;   // 64,64,64,15
    if(ch) __syncthreads();
    for(int i=tid; i<cs*52; i+=TPB) sT[i/52][i%52] = Sp[(size_t)n0*52 + i];
    __syncthreads();
    for(int j=tid; j<52*64; j+=TPB){
      int l = j>>6, nn = j&63; int n = n0+nn;
      if(n < 224){
        float v = 0.f;
        if(nn < cs) v = sT[nn][l];
        STp[(size_t)l*224 + n] = f2bf(v);
      }
    }
  }
}

// ---------------- dilated time conv (dil=2) + GLU via MFMA -> h [B][64][NP] ----------------
__global__ __launch_bounds__(TPB) void k_timeconv_mfma(const float* __restrict__ xcat,
    const ushort* __restrict__ WTb, const float* __restrict__ bias, float* __restrict__ h){
  int n = blockIdx.x, b = blockIdx.y;
  constexpr int XS = 200;
  __shared__ __align__(16) ushort sXT[68*XS];
  int tid = threadIdx.x;
  for(int i=tid; i<14*XS; i+=TPB) sXT[54*XS + i] = 0;
  for(int i=tid; i<192*54; i+=TPB){
    int c = i/54, l = i%54;
    float v = xcat[((size_t)(b*192+c)*Nn + n)*Tin + l];
    sXT[l*XS + c] = f2bf(v);
  }
  __syncthreads();
  int lane = tid & 63, w = tid >> 6;
  int r15 = lane & 15, hi = lane >> 4;
  float b0 = bias[w*16 + r15], b1 = bias[w*16 + 64 + r15];
  f32x4 acc0[4], acc1[4];
  #pragma unroll
  for(int tt=0;tt<4;tt++){
    acc0[tt][0]=b0; acc0[tt][1]=b0; acc0[tt][2]=b0; acc0[tt][3]=b0;
    acc1[tt][0]=b1; acc1[tt][1]=b1; acc1[tt][2]=b1; acc1[tt][3]=b1;
  }
  const ushort* wp0 = WTb + (size_t)(w*16 + r15)*576;
  const ushort* wp1 = WTb + (size_t)(w*16 + 64 + r15)*576;
  #pragma unroll 2
  for(int ks=0; ks<18; ks++){
    int k0 = ks*32 + hi*8;
    int kt = k0/192, ci0 = k0 - kt*192;
    bf16x8 bw0 = *(const bf16x8*)&wp0[k0];
    bf16x8 bw1 = *(const bf16x8*)&wp1[k0];
    #pragma unroll
    for(int tt=0;tt<4;tt++){
      bf16x8 ax = *(const bf16x8*)&sXT[(tt*16 + r15 + 2*kt)*XS + ci0];
      acc0[tt] = __builtin_amdgcn_mfma_f32_16x16x32_bf16(ax, bw0, acc0[tt], 0,0,0);
      acc1[tt] = __builtin_amdgcn_mfma_f32_16x16x32_bf16(ax, bw1, acc1[tt], 0,0,0);
    }
  }
  float* hp = h + (size_t)b*Cc*NP + (size_t)n*LP;
  int c = w*16 + r15;
  #pragma unroll
  for(int tt=0;tt<4;tt++){
    int t0 = tt*16 + hi*4;
    #pragma unroll
    for(int i=0;i<4;i++){
      int t = t0 + i;
      if(t < L50) hp[(size_t)c*NP + t] = tanhf(acc0[tt][i])*sigm(acc1[tt][i]);
    }
  }
  if(tid < 128){ int cz = tid >> 1, tz = 50 + (tid & 1); hp[(size_t)cz*NP + tz] = 0.f; }
}

// ---------------- gated multi-basis GCN einsum via MFMA ----------------
template<int D>
__global__ __launch_bounds__(TPB) void k_gcs_mfma(const ushort* __restrict__ XT,
    const ushort* __restrict__ wqT, const ushort* __restrict__ wvT,
    float* __restrict__ S){
  int p0 = blockIdx.x*64;
  int b = blockIdx.z;
  int tid = threadIdx.x;
  int lane = tid & 63;
  int d0 = blockIdx.y*64 + ((tid>>6)<<4);
  __shared__ __align__(16) ushort sX[64*64];
  for(int i=tid;i<512;i+=TPB){
    int row=i>>3, c8=(i&7)<<3;
    uint4 v = *(const uint4*)&XT[((size_t)b*NPa + p0 + row)*64 + c8];
    *(uint4*)&sX[row*64 + (c8 ^ ((row&7)<<3))] = v;
  }
  __syncthreads();
  int r15 = lane & 15, hi = lane >> 4;
  bf16x8 bf[4][2];
  #pragma unroll
  for(int pt=0;pt<4;pt++){
    int row = pt*16 + r15;
    int sw = (row&7)<<3;
    int cu0 = hi*8;
    bf[pt][0] = *(const bf16x8*)&sX[row*64 + (cu0 ^ sw)];
    bf[pt][1] = *(const bf16x8*)&sX[row*64 + ((cu0+32) ^ sw)];
  }
  f32x4 acc[4];
  #pragma unroll
  for(int pt=0;pt<4;pt++){ acc[pt][0]=0.f; acc[pt][1]=0.f; acc[pt][2]=0.f; acc[pt][3]=0.f; }
  const ushort* wqp = wqT + ((size_t)(d0 + r15))*64 + hi*8;
  const ushort* wvp = wvT + ((size_t)(d0 + r15))*64 + hi*8;
  for(int k=0;k<Kb;k++){
    bf16x8 aq0 = *(const bf16x8*)&wqp[0];
    bf16x8 aq1 = *(const bf16x8*)&wqp[32];
    bf16x8 av0 = *(const bf16x8*)&wvp[0];
    bf16x8 av1 = *(const bf16x8*)&wvp[32];
    wqp += (size_t)D*64; wvp += (size_t)D*64;
    #pragma unroll
    for(int pt=0;pt<4;pt++){
      f32x4 q; q[0]=0.f;q[1]=0.f;q[2]=0.f;q[3]=0.f;
      f32x4 v; v[0]=0.f;v[1]=0.f;v[2]=0.f;v[3]=0.f;
      q = __builtin_amdgcn_mfma_f32_16x16x32_bf16(aq0, bf[pt][0], q, 0,0,0);
      q = __builtin_amdgcn_mfma_f32_16x16x32_bf16(aq1, bf[pt][1], q, 0,0,0);
      v = __builtin_amdgcn_mfma_f32_16x16x32_bf16(av0, bf[pt][0], v, 0,0,0);
      v = __builtin_amdgcn_mfma_f32_16x16x32_bf16(av1, bf[pt][1], v, 0,0,0);
      #pragma unroll
      for(int i=0;i<4;i++) acc[pt][i] += v[i]*sigm(q[i]);
    }
  }
  #pragma unroll
  for(int pt=0;pt<4;pt++){
    int p = p0 + pt*16 + r15;
    if(p < NP){
      #pragma unroll
      for(int i=0;i<4;i++){
        int d = d0 + hi*4 + i;
        S[((size_t)b*D + d)*NP + p] = acc[pt][i];
      }
    }
  }
}

// ---------------- adjacency aggregation via MFMA ----------------
// out[bd][k2][l] = act( sum_n adjT[k2][n] * ST[bd][l][n] + bias[d] )
template<int RELU>
__global__ __launch_bounds__(TPB) void k_agg_mfma(const ushort* __restrict__ ST, const ushort* __restrict__ adjT,
                                                  const float* __restrict__ bias, float* __restrict__ Out, int D){
  int d = blockIdx.x, b = blockIdx.y;
  int bd = b*D + d;
  constexpr int SST = 232;                      // row stride (ushorts), 16B-aligned, 2-way bank pattern
  __shared__ __align__(16) ushort sB[64*SST];
  int tid = threadIdx.x;
  for(int i=tid; i<12*SST; i+=TPB) sB[52*SST + i] = 0;
  const ushort* STp = ST + (size_t)bd*52*224;
  for(int i=tid; i<1456; i+=TPB){
    int l = i/28, n8 = (i%28)*8;
    *(uint4*)&sB[l*SST + n8] = *(const uint4*)&STp[(size_t)l*224 + n8];
  }
  __syncthreads();
  int lane = tid & 63, w = tid >> 6;
  int r15 = lane & 15, hi = lane >> 4;
  float bb = bias[d];
  float* Op = Out + (size_t)bd*NP;
  for(int k2t = w; k2t < 13; k2t += 4){
    f32x4 acc[4];
    #pragma unroll
    for(int lt=0;lt<4;lt++){ acc[lt][0]=0;acc[lt][1]=0;acc[lt][2]=0;acc[lt][3]=0; }
    #pragma unroll
    for(int ks=0; ks<7; ks++){
      bf16x8 a = *(const bf16x8*)&adjT[(size_t)(k2t*16+r15)*224 + ks*32 + hi*8];
      #pragma unroll
      for(int lt=0;lt<4;lt++){
        bf16x8 bfr = *(const bf16x8*)&sB[(lt*16+r15)*SST + ks*32 + hi*8];
        acc[lt] = __builtin_amdgcn_mfma_f32_16x16x32_bf16(a, bfr, acc[lt], 0,0,0);
      }
    }
    #pragma unroll
    for(int lt=0;lt<4;lt++){
      #pragma unroll
      for(int i2=0;i2<4;i2++){
        int k2 = k2t*16 + hi*4 + i2;
        int l  = lt*16 + r15;
        if(k2 < Nn && l < LP){
          float v = acc[lt][i2] + bb;
          if(RELU) v = fmaxf(v, 0.f);
          Op[(size_t)k2*LP + l] = v;
        }
      }
    }
  }
}

// ---------------- MLP conv accumulate (dil=1), per layer ----------------
__global__ __launch_bounds__(TPB) void k_mlpacc(const float* __restrict__ Outs, const float* __restrict__ WT,
                                                float* __restrict__ gacc, int layer){
  int n = blockIdx.x, b = blockIdx.y;
  __shared__ __align__(16) float sO[128][52];
  int tid = threadIdx.x;
  for(int i=tid;i<128*52;i+=TPB){ int c=i/52, l=i%52;
    sO[c][l] = Outs[(((size_t)b*128+c)*Nn + n)*LP + l]; }
  __syncthreads();
  int o = tid & 127, half = tid >> 7;
  int t0 = half*24;
  float acc[24];
  #pragma unroll
  for(int j=0;j<24;j++) acc[j]=0.f;
  const float* wt = WT + (size_t)layer*128*3*128;
  for(int ci=0;ci<128;ci++){
    float w0 = wt[(size_t)(ci*3+0)*128+o];
    float w1 = wt[(size_t)(ci*3+1)*128+o];
    float w2 = wt[(size_t)(ci*3+2)*128+o];
    float sv[26];
    #pragma unroll
    for(int m=0;m<26;m++) sv[m]=sO[ci][t0+m];
    #pragma unroll
    for(int j=0;j<24;j++) acc[j] += w0*sv[j] + w1*sv[j+1] + w2*sv[j+2];
  }
  size_t base = (((size_t)b*128+o)*Nn + n)*Tout + t0;
  if(layer==0){ for(int j=0;j<24;j++) gacc[base+j] = acc[j]; }
  else       { for(int j=0;j<24;j++) gacc[base+j] += acc[j]; }
}

// ---------------- GLU over accumulated MLP conv ----------------
__global__ __launch_bounds__(TPB) void k_glu2(const float* __restrict__ gacc, const float* __restrict__ bm, float* __restrict__ gg){
  size_t i = (size_t)blockIdx.x*TPB + threadIdx.x;
  if(i >= (size_t)Bx*Cc*Nn*Tout) return;
  int t = (int)(i % Tout); size_t r = i / Tout; int n = (int)(r % Nn); size_t r2 = r / Nn;
  int c = (int)(r2 % Cc); int b = (int)(r2 / Cc);
  size_t i1 = (((size_t)b*128+c)*Nn+n)*Tout + t;
  size_t i2 = (((size_t)b*128+c+64)*Nn+n)*Tout + t;
  float a = gacc[i1]+bm[c], b2 = gacc[i2]+bm[c+64];
  gg[i] = tanhf(a)*sigm(b2);
}

// ---------------- patch scramble + emb ----------------
__global__ __launch_bounds__(TPB) void k_xe(const float* __restrict__ gg, const float* __restrict__ emb, float* __restrict__ xe){
  size_t i = (size_t)blockIdx.x*TPB + threadIdx.x;
  if(i >= (size_t)Bx*1271808) return;
  int b = (int)(i / 1271808);
  int off = (int)(i % 1271808);
  int c = off / 19872; int r = off % 19872;
  int n = r / 96; int r2 = r % 96;
  int p = r2 >> 3; int j = r2 & 7;
  int t = p*4 + j;
  float v = 0.f;
  if(t < Tout) v = gg[(((size_t)b*Cc+c)*Nn + n)*Tout + t];
  int e = off & 511; int p2 = (off >> 9) % 12;
  xe[i] = v + emb[(size_t)p2*Ee + e];
}

// ---------------- per-row LN helper (rows of 512, stride SRDF, in LDS) ----------------
__device__ __forceinline__ void ln_rows(float* buf, const float* __restrict__ g, const float* __restrict__ be, int tid){
  int lane = tid & 63, wv = tid >> 6;
  for(int r = wv; r < 12; r += 4){
    float s=0.f, s2=0.f;
    #pragma unroll
    for(int j=0;j<8;j++){ float v = buf[r*SRDF + j*64 + lane]; s+=v; s2+=v*v; }
    #pragma unroll
    for(int off=32; off; off>>=1){ s += __shfl_xor(s,off); s2 += __shfl_xor(s2,off); }
    float m = s*(1.f/512.f);
    float rstd = rsqrtf(fmaxf(s2*(1.f/512.f)-m*m, 0.f)+EPSF);
    #pragma unroll
    for(int j=0;j<8;j++){ int e = j*64+lane; float v = buf[r*SRDF+e];
      buf[r*SRDF+e] = (v-m)*rstd*g[e] + be[e]; }
  }
}

// ---------------- fused per-(b,n) transformer, MFMA GEMM phases ----------------
__global__ __launch_bounds__(TPB,2) void k_attn(
    const float* __restrict__ xe, const float* __restrict__ resid,
    const ushort* __restrict__ WqT, const float* __restrict__ bq,
    const ushort* __restrict__ WkT, const float* __restrict__ bk,
    const ushort* __restrict__ WvT, const float* __restrict__ bv,
    const ushort* __restrict__ WfcT, const float* __restrict__ bfc,
    const float* __restrict__ g1, const float* __restrict__ b1n,
    const float* __restrict__ g2, const float* __restrict__ b2n,
    const ushort* __restrict__ Wff1T, const float* __restrict__ bff1,
    const ushort* __restrict__ Wff2T, const float* __restrict__ bff2,
    const float* __restrict__ Wrp, const float* __restrict__ brp,
    float* __restrict__ y)
{
  int n = blockIdx.x, b = blockIdx.y;
  __shared__ __align__(16) ushort SbX[16*512];
  __shared__ __align__(16) ushort Mb[16*256];
  __shared__ __align__(16) float U0[12*SRDF];
  __shared__ __align__(16) float U1[12*SRDF];
  __shared__ __align__(16) float sS[1160];
  int tid = threadIdx.x;
  int lane = tid & 63, w = tid >> 6;
  int r15 = lane & 15, hi = lane >> 4;
  const float* __restrict__ xeg = xe + ((size_t)b*Nn + n)*6144;

  for(int i=tid;i<1024;i+=TPB){
    int r = i>>6, ch = i&63;
    ushort u[8];
    if(r<12){
      const float* s = &xeg[r*512 + ch*8];
      #pragma unroll
      for(int j=0;j<8;j++) u[j] = f2bf(s[j]);
    } else {
      #pragma unroll
      for(int j=0;j<8;j++) u[j] = 0;
    }
    *(uint4*)&SbX[r*512 + ((ch ^ (r&7))<<3)] = *(uint4*)u;
  }
  for(int i=tid;i<128;i+=TPB){
    int r = 12 + (i>>5), ch = i&31;
    uint4 z; z.x=0;z.y=0;z.z=0;z.w=0;
    *(uint4*)&Mb[r*256 + ch*8] = z;
  }
  __syncthreads();

  f32x4 vfrag[2][4];
  #pragma unroll
  for(int h2=0;h2<2;h2++){
    int head = w*2 + h2;
    bf16x8 a0, a1;
    { int ch0 = head*8 + hi, ch1 = head*8 + 4 + hi;
      a0 = *(const bf16x8*)&SbX[r15*512 + ((ch0 ^ (r15&7))<<3)];
      a1 = *(const bf16x8*)&SbX[r15*512 + ((ch1 ^ (r15&7))<<3)]; }
    #pragma unroll
    for(int nt=0;nt<4;nt++){
      int col = nt*16 + r15;
      float bb = bq[col];
      f32x4 acc; acc[0]=bb;acc[1]=bb;acc[2]=bb;acc[3]=bb;
      acc = __builtin_amdgcn_mfma_f32_16x16x32_bf16(a0, *(const bf16x8*)&WqT[(size_t)col*64 + hi*8], acc, 0,0,0);
      acc = __builtin_amdgcn_mfma_f32_16x16x32_bf16(a1, *(const bf16x8*)&WqT[(size_t)col*64 + 32 + hi*8], acc, 0,0,0);
      #pragma unroll
      for(int i2=0;i2<4;i2++){ int p = hi*4+i2; if(p<12) U0[p*SRDF + head*64 + col] = acc[i2]; }
    }
    #pragma unroll
    for(int nt=0;nt<4;nt++){
      int col = nt*16 + r15;
      float bb = bk[col];
      f32x4 acc; acc[0]=bb;acc[1]=bb;acc[2]=bb;acc[3]=bb;
      acc = __builtin_amdgcn_mfma_f32_16x16x32_bf16(a0, *(const bf16x8*)&WkT[(size_t)col*64 + hi*8], acc, 0,0,0);
      acc = __builtin_amdgcn_mfma_f32_16x16x32_bf16(a1, *(const bf16x8*)&WkT[(size_t)col*64 + 32 + hi*8], acc, 0,0,0);
      #pragma unroll
      for(int i2=0;i2<4;i2++){ int p = hi*4+i2; if(p<12) U1[p*SRDF + head*64 + col] = acc[i2]; }
    }
    #pragma unroll
    for(int nt=0;nt<4;nt++){
      int col = nt*16 + r15;
      float bb = bv[col];
      f32x4 acc; acc[0]=bb;acc[1]=bb;acc[2]=bb;acc[3]=bb;
      acc = __builtin_amdgcn_mfma_f32_16x16x32_bf16(a0, *(const bf16x8*)&WvT[(size_t)col*64 + hi*8], acc, 0,0,0);
      acc = __builtin_amdgcn_mfma_f32_16x16x32_bf16(a1, *(const bf16x8*)&WvT[(size_t)col*64 + 32 + hi*8], acc, 0,0,0);
      vfrag[h2][nt] = acc;
    }
  }
  __syncthreads();

  const float scale = 0.04419417382415922f;   // 1/sqrt(512)
  for(int i=tid;i<1152;i+=TPB){
    int q = i%12, kh = i/12; int h2 = kh&7, k2 = kh>>3;
    const float* qp = &U0[q*SRDF + h2*64];
    const float* kp = &U1[k2*SRDF + h2*64];
    float s=0.f;
    #pragma unroll
    for(int d4=0; d4<16; d4++){
      float4 a4 = *(const float4*)&qp[d4*4];
      float4 b4 = *(const float4*)&kp[d4*4];
      s += a4.x*b4.x + a4.y*b4.y + a4.z*b4.z + a4.w*b4.w;
    }
    sS[i] = s*scale;
  }
  __syncthreads();
  #pragma unroll
  for(int h2=0;h2<2;h2++){
    int head = w*2 + h2;
    #pragma unroll
    for(int nt=0;nt<4;nt++){
      int col = nt*16 + r15;
      #pragma unroll
      for(int i2=0;i2<4;i2++){ int p = hi*4+i2; if(p<12) U0[p*SRDF + head*64 + col] = vfrag[h2][nt][i2]; }
    }
  }
  if(tid<96){
    float mx=-1e30f;
    for(int q=0;q<12;q++) mx = fmaxf(mx, sS[tid*12+q]);
    float sm=0.f;
    for(int q=0;q<12;q++){ float e = __expf(sS[tid*12+q]-mx); sS[tid*12+q]=e; sm+=e; }
    float inv = 1.f/sm;
    for(int q=0;q<12;q++) sS[tid*12+q] *= inv;
  }
  __syncthreads();

  for(int i=tid;i<6144;i+=TPB){
    int q=i>>9, h2=(i>>6)&7, d=i&63;
    float s=0.f;
    #pragma unroll
    for(int k2=0;k2<12;k2++) s += sS[(k2*8+h2)*12+q]*U0[k2*SRDF+h2*64+d];
    int kk = i & 511;
    SbX[q*512 + (((kk>>3) ^ (q&7))<<3) + (kk&7)] = f2bf(s);
  }
  __syncthreads();

  {
    f32x4 acc[8];
    #pragma unroll
    for(int nt=0;nt<8;nt++){ float bb = bfc[(w*8+nt)*16 + r15]; acc[nt][0]=bb;acc[nt][1]=bb;acc[nt][2]=bb;acc[nt][3]=bb; }
    for(int ks=0;ks<16;ks++){
      int ch = ks*4 + hi;
      bf16x8 a = *(const bf16x8*)&SbX[r15*512 + ((ch ^ (r15&7))<<3)];
      #pragma unroll
      for(int nt=0;nt<8;nt++){
        int col = (w*8+nt)*16 + r15;
        acc[nt] = __builtin_amdgcn_mfma_f32_16x16x32_bf16(a, *(const bf16x8*)&WfcT[(size_t)col*512 + ks*32 + hi*8], acc[nt], 0,0,0);
      }
    }
    #pragma unroll
    for(int nt=0;nt<8;nt++){
      int col = (w*8+nt)*16 + r15;
      #pragma unroll
      for(int i2=0;i2<4;i2++){ int p = hi*4+i2; if(p<12) U1[p*SRDF + col] = acc[nt][i2] + xeg[p*512 + col]; }
    }
  }
  __syncthreads();
  ln_rows(U1, g1, b1n, tid);     // M in U1
  __syncthreads();

  for(int i=tid;i<6144;i+=TPB){
    int r=i>>9, kk=i&511;
    SbX[r*512 + (((kk>>3) ^ (r&7))<<3) + (kk&7)] = f2bf(U1[r*SRDF + kk]);
  }
  __syncthreads();

  {
    f32x4 acc[4];
    #pragma unroll
    for(int nt=0;nt<4;nt++){ float bb = bff1[(w*4+nt)*16 + r15]; acc[nt][0]=bb;acc[nt][1]=bb;acc[nt][2]=bb;acc[nt][3]=bb; }
    for(int ks=0;ks<16;ks++){
      int ch = ks*4 + hi;
      bf16x8 a = *(const bf16x8*)&SbX[r15*512 + ((ch ^ (r15&7))<<3)];
      #pragma unroll
      for(int nt=0;nt<4;nt++){
        int col = (w*4+nt)*16 + r15;
        acc[nt] = __builtin_amdgcn_mfma_f32_16x16x32_bf16(a, *(const bf16x8*)&Wff1T[(size_t)col*512 + ks*32 + hi*8], acc[nt], 0,0,0);
      }
    }
    #pragma unroll
    for(int nt=0;nt<4;nt++){
      int u = (w*4+nt)*16 + r15;
      #pragma unroll
      for(int i2=0;i2<4;i2++){
        int p = hi*4+i2;
        if(p<12) Mb[p*256 + (((u>>3) ^ (p&7))<<3) + (u&7)] = f2bf(fmaxf(acc[nt][i2], 0.f));
      }
    }
  }
  __syncthreads();

  {
    f32x4 acc[8];
    #pragma unroll
    for(int nt=0;nt<8;nt++){ float bb = bff2[(w*8+nt)*16 + r15]; acc[nt][0]=bb;acc[nt][1]=bb;acc[nt][2]=bb;acc[nt][3]=bb; }
    for(int ks=0;ks<8;ks++){
      int ch = ks*4 + hi;
      bf16x8 a = *(const bf16x8*)&Mb[r15*256 + ((ch ^ (r15&7))<<3)];
      #pragma unroll
      for(int nt=0;nt<8;nt++){
        int col = (w*8+nt)*16 + r15;
        acc[nt] = __builtin_amdgcn_mfma_f32_16x16x32_bf16(a, *(const bf16x8*)&Wff2T[(size_t)col*256 + ks*32 + hi*8], acc[nt], 0,0,0);
      }
    }
    #pragma unroll
    for(int nt=0;nt<8;nt++){
      int col = (w*8+nt)*16 + r15;
      #pragma unroll
      for(int i2=0;i2<4;i2++){ int p = hi*4+i2; if(p<12) U0[p*SRDF + col] = acc[nt][i2] + U1[p*SRDF + col]; }
    }
  }
  __syncthreads();
  ln_rows(U0, g2, b2n, tid);     // U in U0
  __syncthreads();

  for(int i=tid;i<6144;i+=TPB){
    int r=i>>9, c=i&511;
    U1[r*SRDF+c] = U0[r*SRDF+c] + U1[r*SRDF+c] + xeg[r*512+c];
  }
  __syncthreads();
  for(int i=tid;i<4608;i+=TPB) U0[i] = Wrp[i];
  __syncthreads();
  #pragma unroll
  for(int j=0;j<3;j++){
    int i4 = tid + j*TPB;
    int c = i4/12, tq = i4%12; int t0 = tq*4;
    float4 acc = *(const float4*)&brp[t0];
    for(int t96=0;t96<96;t96++){
      int f = c*96 + t96;
      float a = U1[(f>>9)*SRDF + (f&511)];
      float4 w4 = *(const float4*)&U0[t96*48 + t0];
      FMA4(acc, a, w4);
    }
    size_t rb = (((size_t)b*Cc+c)*Nn + n)*Tin + 6 + t0;
    acc.x += resid[rb+0]; acc.y += resid[rb+1]; acc.z += resid[rb+2]; acc.w += resid[rb+3];
    *(float4*)&y[(((size_t)b*Cc+c)*Nn + n)*Tout + t0] = acc;
  }
}

// ---------------- batchnorm ----------------
__global__ __launch_bounds__(TPB) void k_bnstats(const float* __restrict__ y, float* __restrict__ stats){
  int c = blockIdx.x; int tid = threadIdx.x;
  float s=0.f,s2=0.f;
  const int per = Nn*Tout;   // 9936
  for(int idx=tid; idx<Bx*per; idx+=TPB){
    int b = idx/per, r = idx%per;
    float v = y[((size_t)b*Cc+c)*per + r];
    s+=v; s2+=v*v;
  }
  __shared__ float rs[TPB], rs2[TPB];
  rs[tid]=s; rs2[tid]=s2; __syncthreads();
  for(int off=TPB/2; off; off>>=1){ if(tid<off){ rs[tid]+=rs[tid+off]; rs2[tid]+=rs2[tid+off]; } __syncthreads(); }
  if(tid==0){
    float m = rs[0]/(float)(Bx*per);
    float var = rs2[0]/(float)(Bx*per) - m*m;
    stats[c]=m; stats[64+c]=rsqrtf(fmaxf(var,0.f)+EPSF);
  }
}
__global__ __launch_bounds__(TPB) void k_bnout(const float* __restrict__ y, const float* __restrict__ stats,
                                               const float* __restrict__ gbn, const float* __restrict__ bbn,
                                               float* __restrict__ out){
  size_t i = (size_t)blockIdx.x*TPB + threadIdx.x;
  if(i >= (size_t)Bx*Cc*Nn*Tout) return;
  int c = (int)((i/(Nn*Tout))%Cc);
  out[i] = (y[i]-stats[c])*stats[64+c]*gbn[c] + bbn[c];
}

// ---------------- launch ----------------
extern "C" void kernel_launch(void* const* d_in, const int* in_sizes, int n_in,
                              void* d_out, int out_size, void* d_ws, size_t ws_size,
                              hipStream_t stream) {
  const float* x      = (const float*)d_in[0];
  const float* adj    = (const float*)d_in[1];
  const float* Wconv1 = (const float*)d_in[2];
  const float* bconv1 = (const float*)d_in[3];
  const float* gT     = (const float*)d_in[4];
  const float* bT     = (const float*)d_in[5];
  const float* gS     = (const float*)d_in[6];
  const float* bS     = (const float*)d_in[7];
  const float* Wtime  = (const float*)d_in[8];
  const float* btime  = (const float*)d_in[9];
  const float* wq1    = (const float*)d_in[10];
  const float* wv1    = (const float*)d_in[11];
  const float* bias1  = (const float*)d_in[12];
  const float* wq2    = (const float*)d_in[13];
  const float* wv2    = (const float*)d_in[14];
  const float* bias2  = (const float*)d_in[15];
  const float* Wmlp   = (const float*)d_in[16];
  const float* bmlp   = (const float*)d_in[17];
  const float* embT   = (const float*)d_in[18];
  const float* Wq     = (const float*)d_in[19];
  const float* bq     = (const float*)d_in[20];
  const float* Wk     = (const float*)d_in[21];
  const float* bk     = (const float*)d_in[22];
  const float* Wv     = (const float*)d_in[23];
  const float* bv     = (const float*)d_in[24];
  const float* Wfc    = (const float*)d_in[25];
  const float* bfc    = (const float*)d_in[26];
  const float* g1     = (const float*)d_in[27];
  const float* b1n    = (const float*)d_in[28];
  const float* g2     = (const float*)d_in[29];
  const float* b2n    = (const float*)d_in[30];
  const float* Wff1   = (const float*)d_in[31];
  const float* bff1   = (const float*)d_in[32];
  const float* Wff2   = (const float*)d_in[33];
  const float* bff2   = (const float*)d_in[34];
  const float* Wrp    = (const float*)d_in[35];
  const float* brp    = (const float*)d_in[36];
  const float* gbn    = (const float*)d_in[37];
  const float* bbn    = (const float*)d_in[38];

  float* ws = (float*)d_ws;
  float* RESID = ws + O_RESID;
  float* LNTM  = ws + O_LNTM;
  float* LNTR  = ws + O_LNTR;
  float* LNSM  = ws + O_LNSM;
  float* LNSR  = ws + O_LNSR;
  float* XCAT  = ws + O_XCAT;
  float* RA    = ws + O_XCAT;    // overlays XCAT after it is consumed
  float* RB    = ws + O_RB;
  float* H     = ws + O_H;
  float* GACC  = ws + O_GACC;
  float* GG    = ws + O_GG;
  float* Y     = ws + O_GG;      // overlays GG after xe built
  float* XE    = ws + O_XE;
  float* WTM   = ws + O_WTM;
  float* BNST  = ws + O_BNST;
  ushort* WTB  = (ushort*)(ws + O_WTB);
  ushort* ADJT = (ushort*)(ws + O_ADJT);
  ushort* STb  = (ushort*)(ws + O_XE);   // ST scratch aliases XE region (free until k_xe)
  ushort* HT   = (ushort*)(ws + O_HT);
  ushort* WQ1B = (ushort*)(ws + O_WQ1B);
  ushort* WV1B = (ushort*)(ws + O_WV1B);
  ushort* WQ2B = (ushort*)(ws + O_WQ2B);
  ushort* WV2B = (ushort*)(ws + O_WV2B);
  ushort* RBT  = (ushort*)(ws + O_RBT);
  ushort* WQT  = (ushort*)(ws + O_WQT);
  ushort* WKT  = (ushort*)(ws + O_WKT);
  ushort* WVT  = (ushort*)(ws + O_WVT);
  ushort* WFCT = (ushort*)(ws + O_WFCT);
  ushort* WF1T = (ushort*)(ws + O_WF1T);
  ushort* WF2T = (ushort*)(ws + O_WF2T);

  k_residual<<<dim3(Nn,Bx),TPB,0,stream>>>(x, Wconv1, bconv1, RESID);
  k_lnT<<<(Bx*Cc*Nn)/TPB,TPB,0,stream>>>(RESID, LNTM, LNTR);
  k_lnS<<<(Bx*Cc*Tin)/TPB,TPB,0,stream>>>(RESID, LNSM, LNSR);
  k_xcat<<<(Bx*192*Nn*Tin)/TPB,TPB,0,stream>>>(RESID, LNTM, LNTR, LNSM, LNSR, gT,bT,gS,bS, XCAT);
  k_wtb<<<(128*576+TPB-1)/TPB,TPB,0,stream>>>(Wtime, WTB);
  k_wt<<<(128*384*3+TPB-1)/TPB,TPB,0,stream>>>(Wmlp,  WTM, 128, 384);
  k_wadj<<<(3*208*224+TPB-1)/TPB,TPB,0,stream>>>(adj, ADJT);
  k_timeconv_mfma<<<dim3(Nn,Bx),TPB,0,stream>>>(XCAT, WTB, btime, H);

  // bf16 weight converts (into dead XCAT tail -- must be after timeconv)
  k_wcvt<<<(24*64*64+TPB-1)/TPB,TPB,0,stream>>>(wq1, WQ1B, 24, 64, 64);
  k_wcvt<<<(24*64*64+TPB-1)/TPB,TPB,0,stream>>>(wv1, WV1B, 24, 64, 64);
  k_wcvt<<<(24*64*128+TPB-1)/TPB,TPB,0,stream>>>(wq2, WQ2B, 24, 64, 128);
  k_wcvt<<<(24*64*128+TPB-1)/TPB,TPB,0,stream>>>(wv2, WV2B, 24, 64, 128);
  k_wtr<<<(64*64+TPB-1)/TPB,TPB,0,stream>>>(Wq, WQT, 64, 64);
  k_wtr<<<(64*64+TPB-1)/TPB,TPB,0,stream>>>(Wk, WKT, 64, 64);
  k_wtr<<<(64*64+TPB-1)/TPB,TPB,0,stream>>>(Wv, WVT, 64, 64);
  k_wtr<<<(512*512+TPB-1)/TPB,TPB,0,stream>>>(Wfc, WFCT, 512, 512);
  k_wtr<<<(512*256+TPB-1)/TPB,TPB,0,stream>>>(Wff1, WF1T, 512, 256);
  k_wtr<<<(256*512+TPB-1)/TPB,TPB,0,stream>>>(Wff2, WF2T, 256, 512);
  k_t2bf<64><<<dim3(169,Bx),TPB,0,stream>>>(H, HT);

  for(int i=0;i<3;i++){
    k_gcs_mfma<64><<<dim3(169,1,Bx),TPB,0,stream>>>(HT, WQ1B+(size_t)i*8*64*64, WV1B+(size_t)i*8*64*64, RA);
    k_st<<<dim3(64,Bx),TPB,0,stream>>>(RA, STb, 64);
    k_agg_mfma<1><<<dim3(64,Bx),TPB,0,stream>>>(STb, ADJT+(size_t)i*208*224, bias1+(size_t)i*64, RB, 64);
    k_t2bf<64><<<dim3(169,Bx),TPB,0,stream>>>(RB, RBT);
    k_gcs_mfma<128><<<dim3(169,2,Bx),TPB,0,stream>>>(RBT, WQ2B+(size_t)i*8*128*64, WV2B+(size_t)i*8*128*64, RA);
    k_st<<<dim3(128,Bx),TPB,0,stream>>>(RA, STb, 128);
    k_agg_mfma<0><<<dim3(128,Bx),TPB,0,stream>>>(STb, ADJT+(size_t)i*208*224, bias2+(size_t)i*128, RB, 128);
    k_mlpacc<<<dim3(Nn,Bx),TPB,0,stream>>>(RB, WTM, GACC, i);
  }
  k_glu2<<<(Bx*Cc*Nn*Tout)/TPB,TPB,0,stream>>>(GACC, bmlp, GG);
  k_xe<<<(Bx*1271808)/TPB,TPB,0,stream>>>(GG, embT, XE);
  k_attn<<<dim3(Nn,Bx),TPB,0,stream>>>(XE, RESID, WQT,bq, WKT,bk, WVT,bv, WFCT,bfc,
                                       g1,b1n,g2,b2n, WF1T,bff1, WF2T,bff2, Wrp,brp, Y);
  k_bnstats<<<64,TPB,0,stream>>>(Y, BNST);
  k_bnout<<<(Bx*Cc*Nn*Tout)/TPB,TPB,0,stream>>>(Y, BNST, gbn, bbn, (float*)d_out);
}

// Round 9
// 1470.023 us; speedup vs baseline: 3.0962x; 1.0963x over previous
//
#include <hip/hip_runtime.h>
#include <hip/hip_bf16.h>

#define TPB 256

constexpr int Bx = 8, Cc = 64, Nn = 207, Tin = 54, Kb = 8;
constexpr int LP = 52, NP = Nn * LP;     // time padded 50->52, flattened node*time positions
constexpr int NPa = 10816;               // NP rounded up to 169*64 for MFMA tiles
constexpr int L50 = 50, Tout = 48;
constexpr int Ee = 512, Pn = 12;
constexpr float EPSF = 1e-5f;
constexpr int SRDF = 516;                // padded row stride for 512-wide f32 LDS rows (2-way bank pattern)

// ---------------- workspace layout (floats) ----------------
// ws_size is 256 MiB = 67,108,864 floats; peak usage below = 65,457,536 floats (audited; all
// fragment-order buffers are size-identical to their round-8 predecessors).
constexpr size_t O_RESID = 0;                                   // [B][64][207][54]
constexpr size_t O_LNTM  = O_RESID + (size_t)Bx*Cc*Nn*Tin;
constexpr size_t O_LNTR  = O_LNTM  + (size_t)Bx*Cc*Nn;
constexpr size_t O_LNSM  = O_LNTR  + (size_t)Bx*Cc*Nn;
constexpr size_t O_LNSR  = O_LNSM  + (size_t)Bx*Cc*Tin;
constexpr size_t O_XCAT  = O_LNSR  + (size_t)Bx*Cc*Tin;         // [B][192][207][54]; later reused as RA + bf16 tail
constexpr size_t O_RB    = O_XCAT  + (size_t)Bx*192*Nn*Tin;     // [B][128][NP]
constexpr size_t O_H     = O_RB    + (size_t)Bx*128*NP;         // [B][64][NP]
constexpr size_t O_GACC  = O_H     + (size_t)Bx*64*NP;          // [B][128][207][48]
constexpr size_t O_GG    = O_GACC  + (size_t)Bx*128*Nn*Tout;    // [B][64][207][48]; later reused as Y
constexpr size_t O_XE    = O_GG    + (size_t)Bx*64*Nn*Tout;     // [B][207][12][512]; ALSO ST bf16 scratch during GCN loop
constexpr size_t O_WTT   = O_XE    + (size_t)Bx*Nn*Pn*Ee;       // (unused now) 128*192*3
constexpr size_t O_WTM   = O_WTT   + (size_t)128*192*3;         // transposed W_mlp 128*384*3
constexpr size_t O_BNST  = O_WTM   + (size_t)128*384*3;         // 128
constexpr size_t O_WTB   = O_BNST + 128;                        // ushort[8*18*512] time-conv bf16 frag weights
constexpr size_t O_ADJT  = O_WTB  + (size_t)128*576/2;          // ushort[3][13*7*512] adj frag bf16
// bf16 buffers aliased into the dead tail of XCAT (XCAT dead after timeconv; RA uses first Bx*128*NP floats)
constexpr size_t O_HT    = O_XCAT + (size_t)Bx*128*NP;          // ushort[Bx][NPa][64]
constexpr size_t O_WQ1B  = O_HT   + (size_t)Bx*NPa*64/2;        // ushort[24*4*2*512]
constexpr size_t O_WV1B  = O_WQ1B + (size_t)24*64*64/2;
constexpr size_t O_WQ2B  = O_WV1B + (size_t)24*64*64/2;         // ushort[24*8*2*512]
constexpr size_t O_WV2B  = O_WQ2B + (size_t)24*128*64/2;
constexpr size_t O_RBT   = O_WV2B + (size_t)24*128*64/2;        // ushort[Bx][NPa][64]
constexpr size_t O_WQT   = O_RBT  + (size_t)Bx*NPa*64/2;        // ushort[4*2*512]
constexpr size_t O_WKT   = O_WQT  + 2048;
constexpr size_t O_WVT   = O_WKT  + 2048;
constexpr size_t O_WFCT  = O_WVT  + 2048;                       // ushort[32*16*512]
constexpr size_t O_WF1T  = O_WFCT + 131072;                     // ushort[16*16*512]
constexpr size_t O_WF2T  = O_WF1T + 65536;                      // ushort[32*8*512]

#define FMA4(acc, sA_, vB_) { (acc).x += (sA_)*(vB_).x; (acc).y += (sA_)*(vB_).y; (acc).z += (sA_)*(vB_).z; (acc).w += (sA_)*(vB_).w; }

typedef __attribute__((ext_vector_type(8))) short bf16x8;
typedef __attribute__((ext_vector_type(4))) float f32x4;

__device__ __forceinline__ float sigm(float x){ return 1.0f/(1.0f+__expf(-x)); }
__device__ __forceinline__ ushort f2bf(float x){ __hip_bfloat16 h = __float2bfloat16(x); return *(ushort*)&h; }

// ---------------- residual = W_conv1 @ x + b ----------------
__global__ __launch_bounds__(TPB) void k_residual(const float* __restrict__ x, const float* __restrict__ W,
                                                  const float* __restrict__ bias, float* __restrict__ out){
  int n = blockIdx.x, b = blockIdx.y;
  __shared__ __align__(16) float sX[Cc][Tin];
  __shared__ __align__(16) float sW[Cc*Cc];
  int tid = threadIdx.x;
  for(int i=tid;i<Cc*Tin;i+=TPB){ int c=i/Tin, l=i%Tin; sX[c][l] = x[((size_t)(b*Cc+c)*Nn+n)*Tin+l]; }
  for(int i=tid;i<Cc*Cc;i+=TPB) sW[i]=W[i];
  __syncthreads();
  for(int i=tid;i<Cc*Tin;i+=TPB){
    int o=i/Tin, l=i%Tin; float acc=bias[o];
    #pragma unroll 8
    for(int c=0;c<Cc;c++) acc += sW[o*Cc+c]*sX[c][l];
    out[((size_t)(b*Cc+o)*Nn+n)*Tin+l]=acc;
  }
}

// ---------------- LN stats ----------------
__global__ __launch_bounds__(TPB) void k_lnT(const float* __restrict__ r, float* __restrict__ mean, float* __restrict__ rstd){
  int row = blockIdx.x*TPB + threadIdx.x;
  if(row >= Bx*Cc*Nn) return;
  const float* p = r + (size_t)row*Tin;
  float s=0.f,s2=0.f;
  for(int l=0;l<Tin;l++){ float v=p[l]; s+=v; s2+=v*v; }
  float m=s*(1.f/Tin); float var=s2*(1.f/Tin)-m*m;
  mean[row]=m; rstd[row]=rsqrtf(fmaxf(var,0.f)+EPSF);
}
__global__ __launch_bounds__(TPB) void k_lnS(const float* __restrict__ r, float* __restrict__ mean, float* __restrict__ rstd){
  int row = blockIdx.x*TPB + threadIdx.x;       // (b*Cc+c)*Tin + l
  if(row >= Bx*Cc*Tin) return;
  int l = row % Tin; int bc = row / Tin;
  const float* p = r + (size_t)bc*Nn*Tin + l;
  float s=0.f,s2=0.f;
  for(int n=0;n<Nn;n++){ float v=p[(size_t)n*Tin]; s+=v; s2+=v*v; }
  float m=s*(1.f/Nn); float var=s2*(1.f/Nn)-m*m;
  mean[row]=m; rstd[row]=rsqrtf(fmaxf(var,0.f)+EPSF);
}

// ---------------- xcat = [resid, LN_T, LN_S] ----------------
__global__ __launch_bounds__(TPB) void k_xcat(const float* __restrict__ r, const float* __restrict__ tm, const float* __restrict__ tr,
                                              const float* __restrict__ sm, const float* __restrict__ sr,
                                              const float* __restrict__ gT, const float* __restrict__ bT,
                                              const float* __restrict__ gS, const float* __restrict__ bS,
                                              float* __restrict__ out){
  size_t i = (size_t)blockIdx.x*TPB + threadIdx.x;
  if(i >= (size_t)Bx*192*Nn*Tin) return;
  int l = (int)(i % Tin); size_t r1 = i / Tin; int n = (int)(r1 % Nn); size_t r2 = r1 / Nn;
  int ci = (int)(r2 % 192); int b = (int)(r2 / 192);
  int c = ci & 63; int grp = ci >> 6;
  float v = r[((size_t)(b*Cc+c)*Nn+n)*Tin+l];
  float o;
  if(grp==0) o = v;
  else if(grp==1){ int row=(b*Cc+c)*Nn+n; o = (v-tm[row])*tr[row]*gT[l] + bT[l]; }
  else { int row=(b*Cc+c)*Tin+l; o = (v-sm[row])*sr[row]*gS[n] + bS[n]; }
  out[i]=o;
}

// ---------------- weight transpose: W[o][ci][3] -> WT[(ci*3+kt)*O + o] (for W_mlp) ----------------
__global__ __launch_bounds__(TPB) void k_wt(const float* __restrict__ W, float* __restrict__ WT, int O, int CI){
  int idx = blockIdx.x*TPB + threadIdx.x;
  int total = O*CI*3;
  if(idx>=total) return;
  int kt = idx%3; int r = idx/3; int ci = r%CI; int o = r/CI;
  WT[(size_t)(ci*3+kt)*O + o] = W[idx];
}

// ---------------- generic MFMA fragment-order converter ----------------
// F[((s*NT+colTile)*KS+ks)*512 + lane*8 + j] = bf16( W[s*sStride + k*N + col] ), zero-padded,
// where r15=lane&15, hi=lane>>4, k=ks*32+hi*8+j, col=colTile*16+r15.
// A wave loading F[tile*512 + lane*8] reads 1KB contiguous = fully coalesced.
__global__ __launch_bounds__(TPB) void k_wfrag(const float* __restrict__ W, ushort* __restrict__ F,
                                               int K, int N, int KS, int NT, int total, int sStride){
  int i = blockIdx.x*TPB + threadIdx.x;
  if(i >= total) return;
  int j = i & 7; int lane = (i>>3) & 63;
  int t = i >> 9;
  int ks = t % KS; int r = t / KS; int colTile = r % NT; int s = r / NT;
  int r15 = lane & 15, hi = lane >> 4;
  int k = ks*32 + hi*8 + j, col = colTile*16 + r15;
  float v = (k < K && col < N) ? W[(size_t)s*sStride + (size_t)k*N + col] : 0.f;
  F[i] = f2bf(v);
}

// ---------------- time-conv weight frag convert: Wtime[o][ci][kt] -> frag order, k=kt*192+ci ----------------
__global__ __launch_bounds__(TPB) void k_wtbF(const float* __restrict__ W, ushort* __restrict__ F){
  int i = blockIdx.x*TPB + threadIdx.x;
  if(i >= 8*18*512) return;
  int j = i & 7; int lane = (i>>3) & 63;
  int t = i >> 9;
  int ks = t % 18; int colTile = t / 18;
  int r15 = lane & 15, hi = lane >> 4;
  int k = ks*32 + hi*8 + j, o = colTile*16 + r15;
  int kt = k/192, ci = k - kt*192;
  F[i] = f2bf(W[(size_t)(o*192+ci)*3 + kt]);
}

// ---------------- activation transpose+convert: X f32 [b][C][NP] -> XT bf16 [b][NPa][C] ----------------
template<int C>
__global__ __launch_bounds__(TPB) void k_t2bf(const float* __restrict__ X, ushort* __restrict__ XT){
  int p0 = blockIdx.x*64, b = blockIdx.y;
  int tid = threadIdx.x;
  __shared__ __align__(16) float sT[64][65];
  for(int cc=0; cc<C; cc+=64){
    if(cc) __syncthreads();
    for(int i=tid;i<4096;i+=TPB){ int c=i>>6, col=i&63; int p=p0+col;
      sT[c][col] = (p<NP) ? X[((size_t)(b*C+cc+c))*NP + p] : 0.f; }
    __syncthreads();
    for(int i=tid;i<512;i+=TPB){
      int row=i>>3, c8=(i&7)<<3;
      ushort u[8];
      #pragma unroll
      for(int j=0;j<8;j++) u[j] = f2bf(sT[c8+j][row]);
      *(uint4*)&XT[((size_t)b*NPa + p0 + row)*C + cc + c8] = *(uint4*)u;
    }
  }
}

// ---------------- S transpose: S f32 [bd][n][l] -> ST bf16 [bd][l][224] (n-padded) ----------------
__global__ __launch_bounds__(TPB) void k_st(const float* __restrict__ S, ushort* __restrict__ ST, int D){
  int d = blockIdx.x, b = blockIdx.y;
  int bd = b*D + d;
  __shared__ __align__(16) float sT[64][53];
  int tid = threadIdx.x;
  const float* Sp = S + (size_t)bd*NP;
  ushort* STp = ST + (size_t)bd*52*224;
  for(int ch=0; ch<4; ch++){
    int n0 = ch*64;
    int cs = (207 - n0 < 64) ? (207 - n0) : 64;   // 64,64,64,15
    if(ch) __syncthreads();
    for(int i=tid; i<cs*52; i+=TPB) sT[i/52][i%52] = Sp[(size_t)n0*52 + i];
    __syncthreads();
    for(int j=tid; j<52*64; j+=TPB){
      int l = j>>6, nn = j&63; int n = n0+nn;
      if(n < 224){
        float v = 0.f;
        if(nn < cs) v = sT[nn][l];
        STp[(size_t)l*224 + n] = f2bf(v);
      }
    }
  }
}

// ---------------- dilated time conv (dil=2) + GLU via MFMA -> h [B][64][NP] ----------------
__global__ __launch_bounds__(TPB) void k_timeconv_mfma(const float* __restrict__ xcat,
    const ushort* __restrict__ WF, const float* __restrict__ bias, float* __restrict__ h){
  int n = blockIdx.x, b = blockIdx.y;
  constexpr int XS = 200;
  __shared__ __align__(16) ushort sXT[68*XS];
  int tid = threadIdx.x;
  for(int i=tid; i<14*XS; i+=TPB) sXT[54*XS + i] = 0;
  for(int i=tid; i<192*54; i+=TPB){
    int c = i/54, l = i%54;
    float v = xcat[((size_t)(b*192+c)*Nn + n)*Tin + l];
    sXT[l*XS + c] = f2bf(v);
  }
  __syncthreads();
  int lane = tid & 63, w = tid >> 6;
  int r15 = lane & 15, hi = lane >> 4;
  float b0 = bias[w*16 + r15], b1 = bias[w*16 + 64 + r15];
  f32x4 acc0[4], acc1[4];
  #pragma unroll
  for(int tt=0;tt<4;tt++){
    acc0[tt][0]=b0; acc0[tt][1]=b0; acc0[tt][2]=b0; acc0[tt][3]=b0;
    acc1[tt][0]=b1; acc1[tt][1]=b1; acc1[tt][2]=b1; acc1[tt][3]=b1;
  }
  const ushort* wp0 = WF + ((size_t)w*18)*512 + lane*8;        // colTile = w
  const ushort* wp1 = WF + ((size_t)(w+4)*18)*512 + lane*8;    // colTile = w+4 (o+64)
  #pragma unroll 2
  for(int ks=0; ks<18; ks++){
    int k0 = ks*32 + hi*8;
    int kt = k0/192, ci0 = k0 - kt*192;
    bf16x8 bw0 = *(const bf16x8*)&wp0[(size_t)ks*512];
    bf16x8 bw1 = *(const bf16x8*)&wp1[(size_t)ks*512];
    #pragma unroll
    for(int tt=0;tt<4;tt++){
      bf16x8 ax = *(const bf16x8*)&sXT[(tt*16 + r15 + 2*kt)*XS + ci0];
      acc0[tt] = __builtin_amdgcn_mfma_f32_16x16x32_bf16(ax, bw0, acc0[tt], 0,0,0);
      acc1[tt] = __builtin_amdgcn_mfma_f32_16x16x32_bf16(ax, bw1, acc1[tt], 0,0,0);
    }
  }
  float* hp = h + (size_t)b*Cc*NP + (size_t)n*LP;
  int c = w*16 + r15;
  #pragma unroll
  for(int tt=0;tt<4;tt++){
    int t0 = tt*16 + hi*4;
    #pragma unroll
    for(int i=0;i<4;i++){
      int t = t0 + i;
      if(t < L50) hp[(size_t)c*NP + t] = tanhf(acc0[tt][i])*sigm(acc1[tt][i]);
    }
  }
  if(tid < 128){ int cz = tid >> 1, tz = 50 + (tid & 1); hp[(size_t)cz*NP + tz] = 0.f; }
}

// ---------------- gated multi-basis GCN einsum via MFMA ----------------
// weights in fragment order: F[((k*Dt + dTile)*2 + kk)*512 + lane*8]
template<int D>
__global__ __launch_bounds__(TPB) void k_gcs_mfma(const ushort* __restrict__ XT,
    const ushort* __restrict__ wqF, const ushort* __restrict__ wvF,
    float* __restrict__ S){
  constexpr int Dt = D/16;
  int p0 = blockIdx.x*64;
  int b = blockIdx.z;
  int tid = threadIdx.x;
  int lane = tid & 63, w = tid >> 6;
  int d0 = blockIdx.y*64 + (w<<4);
  int dTile = blockIdx.y*4 + w;
  __shared__ __align__(16) ushort sX[64*64];
  for(int i=tid;i<512;i+=TPB){
    int row=i>>3, c8=(i&7)<<3;
    uint4 v = *(const uint4*)&XT[((size_t)b*NPa + p0 + row)*64 + c8];
    *(uint4*)&sX[row*64 + (c8 ^ ((row&7)<<3))] = v;
  }
  __syncthreads();
  int r15 = lane & 15, hi = lane >> 4;
  bf16x8 bf[4][2];
  #pragma unroll
  for(int pt=0;pt<4;pt++){
    int row = pt*16 + r15;
    int sw = (row&7)<<3;
    int cu0 = hi*8;
    bf[pt][0] = *(const bf16x8*)&sX[row*64 + (cu0 ^ sw)];
    bf[pt][1] = *(const bf16x8*)&sX[row*64 + ((cu0+32) ^ sw)];
  }
  f32x4 acc[4];
  #pragma unroll
  for(int pt=0;pt<4;pt++){ acc[pt][0]=0.f; acc[pt][1]=0.f; acc[pt][2]=0.f; acc[pt][3]=0.f; }
  const ushort* wqp = wqF + ((size_t)dTile*2)*512 + lane*8;
  const ushort* wvp = wvF + ((size_t)dTile*2)*512 + lane*8;
  for(int k=0;k<Kb;k++){
    bf16x8 aq0 = *(const bf16x8*)&wqp[0];
    bf16x8 aq1 = *(const bf16x8*)&wqp[512];
    bf16x8 av0 = *(const bf16x8*)&wvp[0];
    bf16x8 av1 = *(const bf16x8*)&wvp[512];
    wqp += (size_t)Dt*2*512; wvp += (size_t)Dt*2*512;
    #pragma unroll
    for(int pt=0;pt<4;pt++){
      f32x4 q; q[0]=0.f;q[1]=0.f;q[2]=0.f;q[3]=0.f;
      f32x4 v; v[0]=0.f;v[1]=0.f;v[2]=0.f;v[3]=0.f;
      q = __builtin_amdgcn_mfma_f32_16x16x32_bf16(aq0, bf[pt][0], q, 0,0,0);
      q = __builtin_amdgcn_mfma_f32_16x16x32_bf16(aq1, bf[pt][1], q, 0,0,0);
      v = __builtin_amdgcn_mfma_f32_16x16x32_bf16(av0, bf[pt][0], v, 0,0,0);
      v = __builtin_amdgcn_mfma_f32_16x16x32_bf16(av1, bf[pt][1], v, 0,0,0);
      #pragma unroll
      for(int i=0;i<4;i++) acc[pt][i] += v[i]*sigm(q[i]);
    }
  }
  #pragma unroll
  for(int pt=0;pt<4;pt++){
    int p = p0 + pt*16 + r15;
    if(p < NP){
      #pragma unroll
      for(int i=0;i<4;i++){
        int d = d0 + hi*4 + i;
        S[((size_t)b*D + d)*NP + p] = acc[pt][i];
      }
    }
  }
}

// ---------------- adjacency aggregation via MFMA ----------------
// adjF fragment order: F[(k2t*7 + ks)*512 + lane*8]
template<int RELU>
__global__ __launch_bounds__(TPB) void k_agg_mfma(const ushort* __restrict__ ST, const ushort* __restrict__ adjF,
                                                  const float* __restrict__ bias, float* __restrict__ Out, int D){
  int d = blockIdx.x, b = blockIdx.y;
  int bd = b*D + d;
  constexpr int SST = 232;
  __shared__ __align__(16) ushort sB[64*SST];
  int tid = threadIdx.x;
  for(int i=tid; i<12*SST; i+=TPB) sB[52*SST + i] = 0;
  const ushort* STp = ST + (size_t)bd*52*224;
  for(int i=tid; i<1456; i+=TPB){
    int l = i/28, n8 = (i%28)*8;
    *(uint4*)&sB[l*SST + n8] = *(const uint4*)&STp[(size_t)l*224 + n8];
  }
  __syncthreads();
  int lane = tid & 63, w = tid >> 6;
  int r15 = lane & 15, hi = lane >> 4;
  float bb = bias[d];
  float* Op = Out + (size_t)bd*NP;
  for(int k2t = w; k2t < 13; k2t += 4){
    f32x4 acc[4];
    #pragma unroll
    for(int lt=0;lt<4;lt++){ acc[lt][0]=0;acc[lt][1]=0;acc[lt][2]=0;acc[lt][3]=0; }
    #pragma unroll
    for(int ks=0; ks<7; ks++){
      bf16x8 a = *(const bf16x8*)&adjF[((size_t)(k2t*7 + ks))*512 + lane*8];
      #pragma unroll
      for(int lt=0;lt<4;lt++){
        bf16x8 bfr = *(const bf16x8*)&sB[(lt*16+r15)*SST + ks*32 + hi*8];
        acc[lt] = __builtin_amdgcn_mfma_f32_16x16x32_bf16(a, bfr, acc[lt], 0,0,0);
      }
    }
    #pragma unroll
    for(int lt=0;lt<4;lt++){
      #pragma unroll
      for(int i2=0;i2<4;i2++){
        int k2 = k2t*16 + hi*4 + i2;
        int l  = lt*16 + r15;
        if(k2 < Nn && l < LP){
          float v = acc[lt][i2] + bb;
          if(RELU) v = fmaxf(v, 0.f);
          Op[(size_t)k2*LP + l] = v;
        }
      }
    }
  }
}

// ---------------- MLP conv accumulate (dil=1), per layer ----------------
__global__ __launch_bounds__(TPB) void k_mlpacc(const float* __restrict__ Outs, const float* __restrict__ WT,
                                                float* __restrict__ gacc, int layer){
  int n = blockIdx.x, b = blockIdx.y;
  __shared__ __align__(16) float sO[128][52];
  int tid = threadIdx.x;
  for(int i=tid;i<128*52;i+=TPB){ int c=i/52, l=i%52;
    sO[c][l] = Outs[(((size_t)b*128+c)*Nn + n)*LP + l]; }
  __syncthreads();
  int o = tid & 127, half = tid >> 7;
  int t0 = half*24;
  float acc[24];
  #pragma unroll
  for(int j=0;j<24;j++) acc[j]=0.f;
  const float* wt = WT + (size_t)layer*128*3*128;
  for(int ci=0;ci<128;ci++){
    float w0 = wt[(size_t)(ci*3+0)*128+o];
    float w1 = wt[(size_t)(ci*3+1)*128+o];
    float w2 = wt[(size_t)(ci*3+2)*128+o];
    float sv[26];
    #pragma unroll
    for(int m=0;m<26;m++) sv[m]=sO[ci][t0+m];
    #pragma unroll
    for(int j=0;j<24;j++) acc[j] += w0*sv[j] + w1*sv[j+1] + w2*sv[j+2];
  }
  size_t base = (((size_t)b*128+o)*Nn + n)*Tout + t0;
  if(layer==0){ for(int j=0;j<24;j++) gacc[base+j] = acc[j]; }
  else       { for(int j=0;j<24;j++) gacc[base+j] += acc[j]; }
}

// ---------------- GLU over accumulated MLP conv ----------------
__global__ __launch_bounds__(TPB) void k_glu2(const float* __restrict__ gacc, const float* __restrict__ bm, float* __restrict__ gg){
  size_t i = (size_t)blockIdx.x*TPB + threadIdx.x;
  if(i >= (size_t)Bx*Cc*Nn*Tout) return;
  int t = (int)(i % Tout); size_t r = i / Tout; int n = (int)(r % Nn); size_t r2 = r / Nn;
  int c = (int)(r2 % Cc); int b = (int)(r2 / Cc);
  size_t i1 = (((size_t)b*128+c)*Nn+n)*Tout + t;
  size_t i2 = (((size_t)b*128+c+64)*Nn+n)*Tout + t;
  float a = gacc[i1]+bm[c], b2 = gacc[i2]+bm[c+64];
  gg[i] = tanhf(a)*sigm(b2);
}

// ---------------- patch scramble + emb ----------------
__global__ __launch_bounds__(TPB) void k_xe(const float* __restrict__ gg, const float* __restrict__ emb, float* __restrict__ xe){
  size_t i = (size_t)blockIdx.x*TPB + threadIdx.x;
  if(i >= (size_t)Bx*1271808) return;
  int b = (int)(i / 1271808);
  int off = (int)(i % 1271808);
  int c = off / 19872; int r = off % 19872;
  int n = r / 96; int r2 = r % 96;
  int p = r2 >> 3; int j = r2 & 7;
  int t = p*4 + j;
  float v = 0.f;
  if(t < Tout) v = gg[(((size_t)b*Cc+c)*Nn + n)*Tout + t];
  int e = off & 511; int p2 = (off >> 9) % 12;
  xe[i] = v + emb[(size_t)p2*Ee + e];
}

// ---------------- per-row LN helper (rows of 512, stride SRDF, in LDS) ----------------
__device__ __forceinline__ void ln_rows(float* buf, const float* __restrict__ g, const float* __restrict__ be, int tid){
  int lane = tid & 63, wv = tid >> 6;
  for(int r = wv; r < 12; r += 4){
    float s=0.f, s2=0.f;
    #pragma unroll
    for(int j=0;j<8;j++){ float v = buf[r*SRDF + j*64 + lane]; s+=v; s2+=v*v; }
    #pragma unroll
    for(int off=32; off; off>>=1){ s += __shfl_xor(s,off); s2 += __shfl_xor(s2,off); }
    float m = s*(1.f/512.f);
    float rstd = rsqrtf(fmaxf(s2*(1.f/512.f)-m*m, 0.f)+EPSF);
    #pragma unroll
    for(int j=0;j<8;j++){ int e = j*64+lane; float v = buf[r*SRDF+e];
      buf[r*SRDF+e] = (v-m)*rstd*g[e] + be[e]; }
  }
}

// ---------------- fused per-(b,n) transformer, MFMA GEMM phases ----------------
__global__ __launch_bounds__(TPB,2) void k_attn(
    const float* __restrict__ xe, const float* __restrict__ resid,
    const ushort* __restrict__ WqF, const float* __restrict__ bq,
    const ushort* __restrict__ WkF, const float* __restrict__ bk,
    const ushort* __restrict__ WvF, const float* __restrict__ bv,
    const ushort* __restrict__ WfcF, const float* __restrict__ bfc,
    const float* __restrict__ g1, const float* __restrict__ b1n,
    const float* __restrict__ g2, const float* __restrict__ b2n,
    const ushort* __restrict__ Wff1F, const float* __restrict__ bff1,
    const ushort* __restrict__ Wff2F, const float* __restrict__ bff2,
    const float* __restrict__ Wrp, const float* __restrict__ brp,
    float* __restrict__ y)
{
  int n = blockIdx.x, b = blockIdx.y;
  __shared__ __align__(16) ushort SbX[16*512];
  __shared__ __align__(16) ushort Mb[16*256];
  __shared__ __align__(16) float U0[12*SRDF];
  __shared__ __align__(16) float U1[12*SRDF];
  __shared__ __align__(16) float sS[1160];
  int tid = threadIdx.x;
  int lane = tid & 63, w = tid >> 6;
  int r15 = lane & 15, hi = lane >> 4;
  const float* __restrict__ xeg = xe + ((size_t)b*Nn + n)*6144;

  for(int i=tid;i<1024;i+=TPB){
    int r = i>>6, ch = i&63;
    ushort u[8];
    if(r<12){
      const float* s = &xeg[r*512 + ch*8];
      #pragma unroll
      for(int j=0;j<8;j++) u[j] = f2bf(s[j]);
    } else {
      #pragma unroll
      for(int j=0;j<8;j++) u[j] = 0;
    }
    *(uint4*)&SbX[r*512 + ((ch ^ (r&7))<<3)] = *(uint4*)u;
  }
  for(int i=tid;i<128;i+=TPB){
    int r = 12 + (i>>5), ch = i&31;
    uint4 z; z.x=0;z.y=0;z.z=0;z.w=0;
    *(uint4*)&Mb[r*256 + ch*8] = z;
  }
  __syncthreads();

  f32x4 vfrag[2][4];
  #pragma unroll
  for(int h2=0;h2<2;h2++){
    int head = w*2 + h2;
    bf16x8 a0, a1;
    { int ch0 = head*8 + hi, ch1 = head*8 + 4 + hi;
      a0 = *(const bf16x8*)&SbX[r15*512 + ((ch0 ^ (r15&7))<<3)];
      a1 = *(const bf16x8*)&SbX[r15*512 + ((ch1 ^ (r15&7))<<3)]; }
    #pragma unroll
    for(int nt=0;nt<4;nt++){
      int col = nt*16 + r15;
      float bb = bq[col];
      f32x4 acc; acc[0]=bb;acc[1]=bb;acc[2]=bb;acc[3]=bb;
      acc = __builtin_amdgcn_mfma_f32_16x16x32_bf16(a0, *(const bf16x8*)&WqF[(size_t)(nt*2+0)*512 + lane*8], acc, 0,0,0);
      acc = __builtin_amdgcn_mfma_f32_16x16x32_bf16(a1, *(const bf16x8*)&WqF[(size_t)(nt*2+1)*512 + lane*8], acc, 0,0,0);
      #pragma unroll
      for(int i2=0;i2<4;i2++){ int p = hi*4+i2; if(p<12) U0[p*SRDF + head*64 + col] = acc[i2]; }
    }
    #pragma unroll
    for(int nt=0;nt<4;nt++){
      int col = nt*16 + r15;
      float bb = bk[col];
      f32x4 acc; acc[0]=bb;acc[1]=bb;acc[2]=bb;acc[3]=bb;
      acc = __builtin_amdgcn_mfma_f32_16x16x32_bf16(a0, *(const bf16x8*)&WkF[(size_t)(nt*2+0)*512 + lane*8], acc, 0,0,0);
      acc = __builtin_amdgcn_mfma_f32_16x16x32_bf16(a1, *(const bf16x8*)&WkF[(size_t)(nt*2+1)*512 + lane*8], acc, 0,0,0);
      #pragma unroll
      for(int i2=0;i2<4;i2++){ int p = hi*4+i2; if(p<12) U1[p*SRDF + head*64 + col] = acc[i2]; }
    }
    #pragma unroll
    for(int nt=0;nt<4;nt++){
      int col = nt*16 + r15;
      float bb = bv[col];
      f32x4 acc; acc[0]=bb;acc[1]=bb;acc[2]=bb;acc[3]=bb;
      acc = __builtin_amdgcn_mfma_f32_16x16x32_bf16(a0, *(const bf16x8*)&WvF[(size_t)(nt*2+0)*512 + lane*8], acc, 0,0,0);
      acc = __builtin_amdgcn_mfma_f32_16x16x32_bf16(a1, *(const bf16x8*)&WvF[(size_t)(nt*2+1)*512 + lane*8], acc, 0,0,0);
      vfrag[h2][nt] = acc;
    }
  }
  __syncthreads();

  const float scale = 0.04419417382415922f;   // 1/sqrt(512)
  for(int i=tid;i<1152;i+=TPB){
    int q = i%12, kh = i/12; int h2 = kh&7, k2 = kh>>3;
    const float* qp = &U0[q*SRDF + h2*64];
    const float* kp = &U1[k2*SRDF + h2*64];
    float s=0.f;
    #pragma unroll
    for(int d4=0; d4<16; d4++){
      float4 a4 = *(const float4*)&qp[d4*4];
      float4 b4 = *(const float4*)&kp[d4*4];
      s += a4.x*b4.x + a4.y*b4.y + a4.z*b4.z + a4.w*b4.w;
    }
    sS[i] = s*scale;
  }
  __syncthreads();
  #pragma unroll
  for(int h2=0;h2<2;h2++){
    int head = w*2 + h2;
    #pragma unroll
    for(int nt=0;nt<4;nt++){
      int col = nt*16 + r15;
      #pragma unroll
      for(int i2=0;i2<4;i2++){ int p = hi*4+i2; if(p<12) U0[p*SRDF + head*64 + col] = vfrag[h2][nt][i2]; }
    }
  }
  if(tid<96){
    float mx=-1e30f;
    for(int q=0;q<12;q++) mx = fmaxf(mx, sS[tid*12+q]);
    float sm=0.f;
    for(int q=0;q<12;q++){ float e = __expf(sS[tid*12+q]-mx); sS[tid*12+q]=e; sm+=e; }
    float inv = 1.f/sm;
    for(int q=0;q<12;q++) sS[tid*12+q] *= inv;
  }
  __syncthreads();

  for(int i=tid;i<6144;i+=TPB){
    int q=i>>9, h2=(i>>6)&7, d=i&63;
    float s=0.f;
    #pragma unroll
    for(int k2=0;k2<12;k2++) s += sS[(k2*8+h2)*12+q]*U0[k2*SRDF+h2*64+d];
    int kk = i & 511;
    SbX[q*512 + (((kk>>3) ^ (q&7))<<3) + (kk&7)] = f2bf(s);
  }
  __syncthreads();

  {
    f32x4 acc[8];
    #pragma unroll
    for(int nt=0;nt<8;nt++){ float bb = bfc[(w*8+nt)*16 + r15]; acc[nt][0]=bb;acc[nt][1]=bb;acc[nt][2]=bb;acc[nt][3]=bb; }
    for(int ks=0;ks<16;ks++){
      int ch = ks*4 + hi;
      bf16x8 a = *(const bf16x8*)&SbX[r15*512 + ((ch ^ (r15&7))<<3)];
      #pragma unroll
      for(int nt=0;nt<8;nt++){
        acc[nt] = __builtin_amdgcn_mfma_f32_16x16x32_bf16(a, *(const bf16x8*)&WfcF[(size_t)((w*8+nt)*16 + ks)*512 + lane*8], acc[nt], 0,0,0);
      }
    }
    #pragma unroll
    for(int nt=0;nt<8;nt++){
      int col = (w*8+nt)*16 + r15;
      #pragma unroll
      for(int i2=0;i2<4;i2++){ int p = hi*4+i2; if(p<12) U1[p*SRDF + col] = acc[nt][i2] + xeg[p*512 + col]; }
    }
  }
  __syncthreads();
  ln_rows(U1, g1, b1n, tid);     // M in U1
  __syncthreads();

  for(int i=tid;i<6144;i+=TPB){
    int r=i>>9, kk=i&511;
    SbX[r*512 + (((kk>>3) ^ (r&7))<<3) + (kk&7)] = f2bf(U1[r*SRDF + kk]);
  }
  __syncthreads();

  {
    f32x4 acc[4];
    #pragma unroll
    for(int nt=0;nt<4;nt++){ float bb = bff1[(w*4+nt)*16 + r15]; acc[nt][0]=bb;acc[nt][1]=bb;acc[nt][2]=bb;acc[nt][3]=bb; }
    for(int ks=0;ks<16;ks++){
      int ch = ks*4 + hi;
      bf16x8 a = *(const bf16x8*)&SbX[r15*512 + ((ch ^ (r15&7))<<3)];
      #pragma unroll
      for(int nt=0;nt<4;nt++){
        acc[nt] = __builtin_amdgcn_mfma_f32_16x16x32_bf16(a, *(const bf16x8*)&Wff1F[(size_t)((w*4+nt)*16 + ks)*512 + lane*8], acc[nt], 0,0,0);
      }
    }
    #pragma unroll
    for(int nt=0;nt<4;nt++){
      int u = (w*4+nt)*16 + r15;
      #pragma unroll
      for(int i2=0;i2<4;i2++){
        int p = hi*4+i2;
        if(p<12) Mb[p*256 + (((u>>3) ^ (p&7))<<3) + (u&7)] = f2bf(fmaxf(acc[nt][i2], 0.f));
      }
    }
  }
  __syncthreads();

  {
    f32x4 acc[8];
    #pragma unroll
    for(int nt=0;nt<8;nt++){ float bb = bff2[(w*8+nt)*16 + r15]; acc[nt][0]=bb;acc[nt][1]=bb;acc[nt][2]=bb;acc[nt][3]=bb; }
    for(int ks=0;ks<8;ks++){
      int ch = ks*4 + hi;
      bf16x8 a = *(const bf16x8*)&Mb[r15*256 + ((ch ^ (r15&7))<<3)];
      #pragma unroll
      for(int nt=0;nt<8;nt++){
        acc[nt] = __builtin_amdgcn_mfma_f32_16x16x32_bf16(a, *(const bf16x8*)&Wff2F[(size_t)((w*8+nt)*8 + ks)*512 + lane*8], acc[nt], 0,0,0);
      }
    }
    #pragma unroll
    for(int nt=0;nt<8;nt++){
      int col = (w*8+nt)*16 + r15;
      #pragma unroll
      for(int i2=0;i2<4;i2++){ int p = hi*4+i2; if(p<12) U0[p*SRDF + col] = acc[nt][i2] + U1[p*SRDF + col]; }
    }
  }
  __syncthreads();
  ln_rows(U0, g2, b2n, tid);     // U in U0
  __syncthreads();

  for(int i=tid;i<6144;i+=TPB){
    int r=i>>9, c=i&511;
    U1[r*SRDF+c] = U0[r*SRDF+c] + U1[r*SRDF+c] + xeg[r*512+c];
  }
  __syncthreads();
  for(int i=tid;i<4608;i+=TPB) U0[i] = Wrp[i];
  __syncthreads();
  #pragma unroll
  for(int j=0;j<3;j++){
    int i4 = tid + j*TPB;
    int c = i4/12, tq = i4%12; int t0 = tq*4;
    float4 acc = *(const float4*)&brp[t0];
    for(int t96=0;t96<96;t96++){
      int f = c*96 + t96;
      float a = U1[(f>>9)*SRDF + (f&511)];
      float4 w4 = *(const float4*)&U0[t96*48 + t0];
      FMA4(acc, a, w4);
    }
    size_t rb = (((size_t)b*Cc+c)*Nn + n)*Tin + 6 + t0;
    acc.x += resid[rb+0]; acc.y += resid[rb+1]; acc.z += resid[rb+2]; acc.w += resid[rb+3];
    *(float4*)&y[(((size_t)b*Cc+c)*Nn + n)*Tout + t0] = acc;
  }
}

// ---------------- batchnorm ----------------
__global__ __launch_bounds__(TPB) void k_bnstats(const float* __restrict__ y, float* __restrict__ stats){
  int c = blockIdx.x; int tid = threadIdx.x;
  float s=0.f,s2=0.f;
  const int per = Nn*Tout;   // 9936
  for(int idx=tid; idx<Bx*per; idx+=TPB){
    int b = idx/per, r = idx%per;
    float v = y[((size_t)b*Cc+c)*per + r];
    s+=v; s2+=v*v;
  }
  __shared__ float rs[TPB], rs2[TPB];
  rs[tid]=s; rs2[tid]=s2; __syncthreads();
  for(int off=TPB/2; off; off>>=1){ if(tid<off){ rs[tid]+=rs[tid+off]; rs2[tid]+=rs2[tid+off]; } __syncthreads(); }
  if(tid==0){
    float m = rs[0]/(float)(Bx*per);
    float var = rs2[0]/(float)(Bx*per) - m*m;
    stats[c]=m; stats[64+c]=rsqrtf(fmaxf(var,0.f)+EPSF);
  }
}
__global__ __launch_bounds__(TPB) void k_bnout(const float* __restrict__ y, const float* __restrict__ stats,
                                               const float* __restrict__ gbn, const float* __restrict__ bbn,
                                               float* __restrict__ out){
  size_t i = (size_t)blockIdx.x*TPB + threadIdx.x;
  if(i >= (size_t)Bx*Cc*Nn*Tout) return;
  int c = (int)((i/(Nn*Tout))%Cc);
  out[i] = (y[i]-stats[c])*stats[64+c]*gbn[c] + bbn[c];
}

// ---------------- launch ----------------
extern "C" void kernel_launch(void* const* d_in, const int* in_sizes, int n_in,
                              void* d_out, int out_size, void* d_ws, size_t ws_size,
                              hipStream_t stream) {
  const float* x      = (const float*)d_in[0];
  const float* adj    = (const float*)d_in[1];
  const float* Wconv1 = (const float*)d_in[2];
  const float* bconv1 = (const float*)d_in[3];
  const float* gT     = (const float*)d_in[4];
  const float* bT     = (const float*)d_in[5];
  const float* gS     = (const float*)d_in[6];
  const float* bS     = (const float*)d_in[7];
  const float* Wtime  = (const float*)d_in[8];
  const float* btime  = (const float*)d_in[9];
  const float* wq1    = (const float*)d_in[10];
  const float* wv1    = (const float*)d_in[11];
  const float* bias1  = (const float*)d_in[12];
  const float* wq2    = (const float*)d_in[13];
  const float* wv2    = (const float*)d_in[14];
  const float* bias2  = (const float*)d_in[15];
  const float* Wmlp   = (const float*)d_in[16];
  const float* bmlp   = (const float*)d_in[17];
  const float* embT   = (const float*)d_in[18];
  const float* Wq     = (const float*)d_in[19];
  const float* bq     = (const float*)d_in[20];
  const float* Wk     = (const float*)d_in[21];
  const float* bk     = (const float*)d_in[22];
  const float* Wv     = (const float*)d_in[23];
  const float* bv     = (const float*)d_in[24];
  const float* Wfc    = (const float*)d_in[25];
  const float* bfc    = (const float*)d_in[26];
  const float* g1     = (const float*)d_in[27];
  const float* b1n    = (const float*)d_in[28];
  const float* g2     = (const float*)d_in[29];
  const float* b2n    = (const float*)d_in[30];
  const float* Wff1   = (const float*)d_in[31];
  const float* bff1   = (const float*)d_in[32];
  const float* Wff2   = (const float*)d_in[33];
  const float* bff2   = (const float*)d_in[34];
  const float* Wrp    = (const float*)d_in[35];
  const float* brp    = (const float*)d_in[36];
  const float* gbn    = (const float*)d_in[37];
  const float* bbn    = (const float*)d_in[38];

  float* ws = (float*)d_ws;
  float* RESID = ws + O_RESID;
  float* LNTM  = ws + O_LNTM;
  float* LNTR  = ws + O_LNTR;
  float* LNSM  = ws + O_LNSM;
  float* LNSR  = ws + O_LNSR;
  float* XCAT  = ws + O_XCAT;
  float* RA    = ws + O_XCAT;    // overlays XCAT after it is consumed
  float* RB    = ws + O_RB;
  float* H     = ws + O_H;
  float* GACC  = ws + O_GACC;
  float* GG    = ws + O_GG;
  float* Y     = ws + O_GG;      // overlays GG after xe built
  float* XE    = ws + O_XE;
  float* WTM   = ws + O_WTM;
  float* BNST  = ws + O_BNST;
  ushort* WTB  = (ushort*)(ws + O_WTB);
  ushort* ADJT = (ushort*)(ws + O_ADJT);
  ushort* STb  = (ushort*)(ws + O_XE);   // ST scratch aliases XE region (free until k_xe)
  ushort* HT   = (ushort*)(ws + O_HT);
  ushort* WQ1B = (ushort*)(ws + O_WQ1B);
  ushort* WV1B = (ushort*)(ws + O_WV1B);
  ushort* WQ2B = (ushort*)(ws + O_WQ2B);
  ushort* WV2B = (ushort*)(ws + O_WV2B);
  ushort* RBT  = (ushort*)(ws + O_RBT);
  ushort* WQT  = (ushort*)(ws + O_WQT);
  ushort* WKT  = (ushort*)(ws + O_WKT);
  ushort* WVT  = (ushort*)(ws + O_WVT);
  ushort* WFCT = (ushort*)(ws + O_WFCT);
  ushort* WF1T = (ushort*)(ws + O_WF1T);
  ushort* WF2T = (ushort*)(ws + O_WF2T);

  k_residual<<<dim3(Nn,Bx),TPB,0,stream>>>(x, Wconv1, bconv1, RESID);
  k_lnT<<<(Bx*Cc*Nn)/TPB,TPB,0,stream>>>(RESID, LNTM, LNTR);
  k_lnS<<<(Bx*Cc*Tin)/TPB,TPB,0,stream>>>(RESID, LNSM, LNSR);
  k_xcat<<<(Bx*192*Nn*Tin)/TPB,TPB,0,stream>>>(RESID, LNTM, LNTR, LNSM, LNSR, gT,bT,gS,bS, XCAT);
  k_wtbF<<<(8*18*512+TPB-1)/TPB,TPB,0,stream>>>(Wtime, WTB);
  k_wt<<<(128*384*3+TPB-1)/TPB,TPB,0,stream>>>(Wmlp,  WTM, 128, 384);
  // adj -> fragment order: K=207(n), N=207(k2), KS=7, NT=13, 3 slices of stride 207*207
  k_wfrag<<<(3*13*7*512+TPB-1)/TPB,TPB,0,stream>>>(adj, ADJT, 207, 207, 7, 13, 3*13*7*512, Nn*Nn);
  k_timeconv_mfma<<<dim3(Nn,Bx),TPB,0,stream>>>(XCAT, WTB, btime, H);

  // fragment-order weight converts (into dead XCAT tail -- must be after timeconv)
  k_wfrag<<<(24*4*2*512+TPB-1)/TPB,TPB,0,stream>>>(wq1, WQ1B, 64, 64, 2, 4, 24*4*2*512, 64*64);
  k_wfrag<<<(24*4*2*512+TPB-1)/TPB,TPB,0,stream>>>(wv1, WV1B, 64, 64, 2, 4, 24*4*2*512, 64*64);
  k_wfrag<<<(24*8*2*512+TPB-1)/TPB,TPB,0,stream>>>(wq2, WQ2B, 64, 128, 2, 8, 24*8*2*512, 64*128);
  k_wfrag<<<(24*8*2*512+TPB-1)/TPB,TPB,0,stream>>>(wv2, WV2B, 64, 128, 2, 8, 24*8*2*512, 64*128);
  k_wfrag<<<(4*2*512+TPB-1)/TPB,TPB,0,stream>>>(Wq, WQT, 64, 64, 2, 4, 4*2*512, 64*64);
  k_wfrag<<<(4*2*512+TPB-1)/TPB,TPB,0,stream>>>(Wk, WKT, 64, 64, 2, 4, 4*2*512, 64*64);
  k_wfrag<<<(4*2*512+TPB-1)/TPB,TPB,0,stream>>>(Wv, WVT, 64, 64, 2, 4, 4*2*512, 64*64);
  k_wfrag<<<(32*16*512+TPB-1)/TPB,TPB,0,stream>>>(Wfc, WFCT, 512, 512, 16, 32, 32*16*512, 512*512);
  k_wfrag<<<(16*16*512+TPB-1)/TPB,TPB,0,stream>>>(Wff1, WF1T, 512, 256, 16, 16, 16*16*512, 512*256);
  k_wfrag<<<(32*8*512+TPB-1)/TPB,TPB,0,stream>>>(Wff2, WF2T, 256, 512, 8, 32, 32*8*512, 256*512);
  k_t2bf<64><<<dim3(169,Bx),TPB,0,stream>>>(H, HT);

  for(int i=0;i<3;i++){
    k_gcs_mfma<64><<<dim3(169,1,Bx),TPB,0,stream>>>(HT, WQ1B+(size_t)i*8*4*2*512, WV1B+(size_t)i*8*4*2*512, RA);
    k_st<<<dim3(64,Bx),TPB,0,stream>>>(RA, STb, 64);
    k_agg_mfma<1><<<dim3(64,Bx),TPB,0,stream>>>(STb, ADJT+(size_t)i*13*7*512, bias1+(size_t)i*64, RB, 64);
    k_t2bf<64><<<dim3(169,Bx),TPB,0,stream>>>(RB, RBT);
    k_gcs_mfma<128><<<dim3(169,2,Bx),TPB,0,stream>>>(RBT, WQ2B+(size_t)i*8*8*2*512, WV2B+(size_t)i*8*8*2*512, RA);
    k_st<<<dim3(128,Bx),TPB,0,stream>>>(RA, STb, 128);
    k_agg_mfma<0><<<dim3(128,Bx),TPB,0,stream>>>(STb, ADJT+(size_t)i*13*7*512, bias2+(size_t)i*128, RB, 128);
    k_mlpacc<<<dim3(Nn,Bx),TPB,0,stream>>>(RB, WTM, GACC, i);
  }
  k_glu2<<<(Bx*Cc*Nn*Tout)/TPB,TPB,0,stream>>>(GACC, bmlp, GG);
  k_xe<<<(Bx*1271808)/TPB,TPB,0,stream>>>(GG, embT, XE);
  k_attn<<<dim3(Nn,Bx),TPB,0,stream>>>(XE, RESID, WQT,bq, WKT,bk, WVT,bv, WFCT,bfc,
                                       g1,b1n,g2,b2n, WF1T,bff1, WF2T,bff2, Wrp,brp, Y);
  k_bnstats<<<64,TPB,0,stream>>>(Y, BNST);
  k_bnout<<<(Bx*Cc*Nn*Tout)/TPB,TPB,0,stream>>>(Y, BNST, gbn, bbn, (float*)d_out);
}

// Round 10
// 1132.700 us; speedup vs baseline: 4.0183x; 1.2978x over previous
//
#include <hip/hip_runtime.h>
#include <hip/hip_bf16.h>

#define TPB 256

constexpr int Bx = 8, Cc = 64, Nn = 207, Tin = 54, Kb = 8;
constexpr int LP = 52, NP = Nn * LP;     // time padded 50->52, flattened node*time positions
constexpr int NPa = 10816;               // NP rounded up to 169*64 for MFMA tiles
constexpr int L50 = 50, Tout = 48;
constexpr int Ee = 512, Pn = 12;
constexpr float EPSF = 1e-5f;
constexpr int SRDF = 516;                // padded row stride for 512-wide f32 LDS rows (2-way bank pattern)

// ---------------- workspace layout (floats) ----------------
// ws_size is 256 MiB = 67,108,864 floats; peak usage below = 65,457,536 floats (audited).
constexpr size_t O_RESID = 0;                                   // [B][64][207][54]
constexpr size_t O_LNTM  = O_RESID + (size_t)Bx*Cc*Nn*Tin;
constexpr size_t O_LNTR  = O_LNTM  + (size_t)Bx*Cc*Nn;
constexpr size_t O_LNSM  = O_LNTR  + (size_t)Bx*Cc*Nn;
constexpr size_t O_LNSR  = O_LNSM  + (size_t)Bx*Cc*Tin;
constexpr size_t O_XCAT  = O_LNSR  + (size_t)Bx*Cc*Tin;         // [B][192][207][54]; later reused as RA + bf16 tail
constexpr size_t O_RB    = O_XCAT  + (size_t)Bx*192*Nn*Tin;     // [B][128][NP]
constexpr size_t O_H     = O_RB    + (size_t)Bx*128*NP;         // [B][64][NP]
constexpr size_t O_GACC  = O_H     + (size_t)Bx*64*NP;          // [B][n][48][128] (relaid out)
constexpr size_t O_GG    = O_GACC  + (size_t)Bx*128*Nn*Tout;    // [B][64][207][48]; later reused as Y
constexpr size_t O_XE    = O_GG    + (size_t)Bx*64*Nn*Tout;     // [B][207][12][512]; ALSO ST bf16 scratch during GCN loop
constexpr size_t O_WTT   = O_XE    + (size_t)Bx*Nn*Pn*Ee;       // (unused now) 128*192*3
constexpr size_t O_WTM   = O_WTT   + (size_t)128*192*3;         // ushort[3*8*12*512] W_mlp frag bf16 (region holds 147456 floats)
constexpr size_t O_BNST  = O_WTM   + (size_t)128*384*3;         // 128
constexpr size_t O_WTB   = O_BNST + 128;                        // ushort[8*18*512] time-conv bf16 frag weights
constexpr size_t O_ADJT  = O_WTB  + (size_t)128*576/2;          // ushort[3][13*7*512] adj frag bf16
// bf16 buffers aliased into the dead tail of XCAT (XCAT dead after timeconv; RA uses first Bx*128*NP floats)
constexpr size_t O_HT    = O_XCAT + (size_t)Bx*128*NP;          // ushort[Bx][NPa][64]
constexpr size_t O_WQ1B  = O_HT   + (size_t)Bx*NPa*64/2;        // ushort[24*4*2*512]
constexpr size_t O_WV1B  = O_WQ1B + (size_t)24*64*64/2;
constexpr size_t O_WQ2B  = O_WV1B + (size_t)24*64*64/2;         // ushort[24*8*2*512]
constexpr size_t O_WV2B  = O_WQ2B + (size_t)24*128*64/2;
constexpr size_t O_RBT   = O_WV2B + (size_t)24*128*64/2;        // ushort[Bx][NPa][64]
constexpr size_t O_WQT   = O_RBT  + (size_t)Bx*NPa*64/2;        // ushort[4*2*512]
constexpr size_t O_WKT   = O_WQT  + 2048;
constexpr size_t O_WVT   = O_WKT  + 2048;
constexpr size_t O_WFCT  = O_WVT  + 2048;                       // ushort[32*16*512]
constexpr size_t O_WF1T  = O_WFCT + 131072;                     // ushort[16*16*512]
constexpr size_t O_WF2T  = O_WF1T + 65536;                      // ushort[32*8*512]

#define FMA4(acc, sA_, vB_) { (acc).x += (sA_)*(vB_).x; (acc).y += (sA_)*(vB_).y; (acc).z += (sA_)*(vB_).z; (acc).w += (sA_)*(vB_).w; }

typedef __attribute__((ext_vector_type(8))) short bf16x8;
typedef __attribute__((ext_vector_type(4))) float f32x4;

__device__ __forceinline__ float sigm(float x){ return 1.0f/(1.0f+__expf(-x)); }
__device__ __forceinline__ ushort f2bf(float x){ __hip_bfloat16 h = __float2bfloat16(x); return *(ushort*)&h; }

// ---------------- residual = W_conv1 @ x + b ----------------
__global__ __launch_bounds__(TPB) void k_residual(const float* __restrict__ x, const float* __restrict__ W,
                                                  const float* __restrict__ bias, float* __restrict__ out){
  int n = blockIdx.x, b = blockIdx.y;
  __shared__ __align__(16) float sX[Cc][Tin];
  __shared__ __align__(16) float sW[Cc*Cc];
  int tid = threadIdx.x;
  for(int i=tid;i<Cc*Tin;i+=TPB){ int c=i/Tin, l=i%Tin; sX[c][l] = x[((size_t)(b*Cc+c)*Nn+n)*Tin+l]; }
  for(int i=tid;i<Cc*Cc;i+=TPB) sW[i]=W[i];
  __syncthreads();
  for(int i=tid;i<Cc*Tin;i+=TPB){
    int o=i/Tin, l=i%Tin; float acc=bias[o];
    #pragma unroll 8
    for(int c=0;c<Cc;c++) acc += sW[o*Cc+c]*sX[c][l];
    out[((size_t)(b*Cc+o)*Nn+n)*Tin+l]=acc;
  }
}

// ---------------- LN stats ----------------
__global__ __launch_bounds__(TPB) void k_lnT(const float* __restrict__ r, float* __restrict__ mean, float* __restrict__ rstd){
  int row = blockIdx.x*TPB + threadIdx.x;
  if(row >= Bx*Cc*Nn) return;
  const float* p = r + (size_t)row*Tin;
  float s=0.f,s2=0.f;
  for(int l=0;l<Tin;l++){ float v=p[l]; s+=v; s2+=v*v; }
  float m=s*(1.f/Tin); float var=s2*(1.f/Tin)-m*m;
  mean[row]=m; rstd[row]=rsqrtf(fmaxf(var,0.f)+EPSF);
}
__global__ __launch_bounds__(TPB) void k_lnS(const float* __restrict__ r, float* __restrict__ mean, float* __restrict__ rstd){
  int row = blockIdx.x*TPB + threadIdx.x;       // (b*Cc+c)*Tin + l
  if(row >= Bx*Cc*Tin) return;
  int l = row % Tin; int bc = row / Tin;
  const float* p = r + (size_t)bc*Nn*Tin + l;
  float s=0.f,s2=0.f;
  for(int n=0;n<Nn;n++){ float v=p[(size_t)n*Tin]; s+=v; s2+=v*v; }
  float m=s*(1.f/Nn); float var=s2*(1.f/Nn)-m*m;
  mean[row]=m; rstd[row]=rsqrtf(fmaxf(var,0.f)+EPSF);
}

// ---------------- xcat = [resid, LN_T, LN_S] ----------------
__global__ __launch_bounds__(TPB) void k_xcat(const float* __restrict__ r, const float* __restrict__ tm, const float* __restrict__ tr,
                                              const float* __restrict__ sm, const float* __restrict__ sr,
                                              const float* __restrict__ gT, const float* __restrict__ bT,
                                              const float* __restrict__ gS, const float* __restrict__ bS,
                                              float* __restrict__ out){
  size_t i = (size_t)blockIdx.x*TPB + threadIdx.x;
  if(i >= (size_t)Bx*192*Nn*Tin) return;
  int l = (int)(i % Tin); size_t r1 = i / Tin; int n = (int)(r1 % Nn); size_t r2 = r1 / Nn;
  int ci = (int)(r2 % 192); int b = (int)(r2 / 192);
  int c = ci & 63; int grp = ci >> 6;
  float v = r[((size_t)(b*Cc+c)*Nn+n)*Tin+l];
  float o;
  if(grp==0) o = v;
  else if(grp==1){ int row=(b*Cc+c)*Nn+n; o = (v-tm[row])*tr[row]*gT[l] + bT[l]; }
  else { int row=(b*Cc+c)*Tin+l; o = (v-sm[row])*sr[row]*gS[n] + bS[n]; }
  out[i]=o;
}

// ---------------- generic MFMA fragment-order converter ----------------
// F[((s*NT+colTile)*KS+ks)*512 + lane*8 + j] = bf16( W[s*sStride + k*N + col] ), zero-padded,
// where r15=lane&15, hi=lane>>4, k=ks*32+hi*8+j, col=colTile*16+r15.
__global__ __launch_bounds__(TPB) void k_wfrag(const float* __restrict__ W, ushort* __restrict__ F,
                                               int K, int N, int KS, int NT, int total, int sStride){
  int i = blockIdx.x*TPB + threadIdx.x;
  if(i >= total) return;
  int j = i & 7; int lane = (i>>3) & 63;
  int t = i >> 9;
  int ks = t % KS; int r = t / KS; int colTile = r % NT; int s = r / NT;
  int r15 = lane & 15, hi = lane >> 4;
  int k = ks*32 + hi*8 + j, col = colTile*16 + r15;
  float v = (k < K && col < N) ? W[(size_t)s*sStride + (size_t)k*N + col] : 0.f;
  F[i] = f2bf(v);
}

// ---------------- time-conv weight frag convert: Wtime[o][ci][kt] -> frag order, k=kt*192+ci ----------------
__global__ __launch_bounds__(TPB) void k_wtbF(const float* __restrict__ W, ushort* __restrict__ F){
  int i = blockIdx.x*TPB + threadIdx.x;
  if(i >= 8*18*512) return;
  int j = i & 7; int lane = (i>>3) & 63;
  int t = i >> 9;
  int ks = t % 18; int colTile = t / 18;
  int r15 = lane & 15, hi = lane >> 4;
  int k = ks*32 + hi*8 + j, o = colTile*16 + r15;
  int kt = k/192, ci = k - kt*192;
  F[i] = f2bf(W[(size_t)(o*192+ci)*3 + kt]);
}

// ---------------- mlp-conv weight frag convert: Wmlp[o][384][3] -> frag order per layer, k=kt*128+ci ----------------
__global__ __launch_bounds__(TPB) void k_wmlpF(const float* __restrict__ W, ushort* __restrict__ F){
  int i = blockIdx.x*TPB + threadIdx.x;
  if(i >= 3*8*12*512) return;
  int j = i & 7; int lane = (i>>3) & 63;
  int t = i >> 9;
  int ks = t % 12; int r = t / 12; int colTile = r & 7; int layer = r >> 3;
  int r15 = lane & 15, hi = lane >> 4;
  int k = ks*32 + hi*8 + j;
  int kt = k >> 7, ci = k & 127;
  int o = colTile*16 + r15;
  F[i] = f2bf(W[(size_t)(o*384 + layer*128 + ci)*3 + kt]);
}

// ---------------- activation transpose+convert: X f32 [b][C][NP] -> XT bf16 [b][NPa][C] ----------------
template<int C>
__global__ __launch_bounds__(TPB) void k_t2bf(const float* __restrict__ X, ushort* __restrict__ XT){
  int p0 = blockIdx.x*64, b = blockIdx.y;
  int tid = threadIdx.x;
  __shared__ __align__(16) float sT[64][65];
  for(int cc=0; cc<C; cc+=64){
    if(cc) __syncthreads();
    for(int i=tid;i<4096;i+=TPB){ int c=i>>6, col=i&63; int p=p0+col;
      sT[c][col] = (p<NP) ? X[((size_t)(b*C+cc+c))*NP + p] : 0.f; }
    __syncthreads();
    for(int i=tid;i<512;i+=TPB){
      int row=i>>3, c8=(i&7)<<3;
      ushort u[8];
      #pragma unroll
      for(int j=0;j<8;j++) u[j] = f2bf(sT[c8+j][row]);
      *(uint4*)&XT[((size_t)b*NPa + p0 + row)*C + cc + c8] = *(uint4*)u;
    }
  }
}

// ---------------- S transpose: S f32 [bd][n][l] -> ST bf16 [bd][l][224] (n-padded) ----------------
__global__ __launch_bounds__(TPB) void k_st(const float* __restrict__ S, ushort* __restrict__ ST, int D){
  int d = blockIdx.x, b = blockIdx.y;
  int bd = b*D + d;
  __shared__ __align__(16) float sT[64][53];
  int tid = threadIdx.x;
  const float* Sp = S + (size_t)bd*NP;
  ushort* STp = ST + (size_t)bd*52*224;
  for(int ch=0; ch<4; ch++){
    int n0 = ch*64;
    int cs = (207 - n0 < 64) ? (207 - n0) : 64;   // 64,64,64,15
    if(ch) __syncthreads();
    for(int i=tid; i<cs*52; i+=TPB) sT[i/52][i%52] = Sp[(size_t)n0*52 + i];
    __syncthreads();
    for(int j=tid; j<52*64; j+=TPB){
      int l = j>>6, nn = j&63; int n = n0+nn;
      if(n < 224){
        float v = 0.f;
        if(nn < cs) v = sT[nn][l];
        STp[(size_t)l*224 + n] = f2bf(v);
      }
    }
  }
}

// ---------------- dilated time conv (dil=2) + GLU via MFMA -> h [B][64][NP] ----------------
__global__ __launch_bounds__(TPB) void k_timeconv_mfma(const float* __restrict__ xcat,
    const ushort* __restrict__ WF, const float* __restrict__ bias, float* __restrict__ h){
  int n = blockIdx.x, b = blockIdx.y;
  constexpr int XS = 200;
  __shared__ __align__(16) ushort sXT[68*XS];
  int tid = threadIdx.x;
  for(int i=tid; i<14*XS; i+=TPB) sXT[54*XS + i] = 0;
  for(int i=tid; i<192*54; i+=TPB){
    int c = i/54, l = i%54;
    float v = xcat[((size_t)(b*192+c)*Nn + n)*Tin + l];
    sXT[l*XS + c] = f2bf(v);
  }
  __syncthreads();
  int lane = tid & 63, w = tid >> 6;
  int r15 = lane & 15, hi = lane >> 4;
  float b0 = bias[w*16 + r15], b1 = bias[w*16 + 64 + r15];
  f32x4 acc0[4], acc1[4];
  #pragma unroll
  for(int tt=0;tt<4;tt++){
    acc0[tt][0]=b0; acc0[tt][1]=b0; acc0[tt][2]=b0; acc0[tt][3]=b0;
    acc1[tt][0]=b1; acc1[tt][1]=b1; acc1[tt][2]=b1; acc1[tt][3]=b1;
  }
  const ushort* wp0 = WF + ((size_t)w*18)*512 + lane*8;        // colTile = w
  const ushort* wp1 = WF + ((size_t)(w+4)*18)*512 + lane*8;    // colTile = w+4 (o+64)
  #pragma unroll 2
  for(int ks=0; ks<18; ks++){
    int k0 = ks*32 + hi*8;
    int kt = k0/192, ci0 = k0 - kt*192;
    bf16x8 bw0 = *(const bf16x8*)&wp0[(size_t)ks*512];
    bf16x8 bw1 = *(const bf16x8*)&wp1[(size_t)ks*512];
    #pragma unroll
    for(int tt=0;tt<4;tt++){
      bf16x8 ax = *(const bf16x8*)&sXT[(tt*16 + r15 + 2*kt)*XS + ci0];
      acc0[tt] = __builtin_amdgcn_mfma_f32_16x16x32_bf16(ax, bw0, acc0[tt], 0,0,0);
      acc1[tt] = __builtin_amdgcn_mfma_f32_16x16x32_bf16(ax, bw1, acc1[tt], 0,0,0);
    }
  }
  float* hp = h + (size_t)b*Cc*NP + (size_t)n*LP;
  int c = w*16 + r15;
  #pragma unroll
  for(int tt=0;tt<4;tt++){
    int t0 = tt*16 + hi*4;
    #pragma unroll
    for(int i=0;i<4;i++){
      int t = t0 + i;
      if(t < L50) hp[(size_t)c*NP + t] = tanhf(acc0[tt][i])*sigm(acc1[tt][i]);
    }
  }
  if(tid < 128){ int cz = tid >> 1, tz = 50 + (tid & 1); hp[(size_t)cz*NP + tz] = 0.f; }
}

// ---------------- gated multi-basis GCN einsum via MFMA ----------------
template<int D>
__global__ __launch_bounds__(TPB) void k_gcs_mfma(const ushort* __restrict__ XT,
    const ushort* __restrict__ wqF, const ushort* __restrict__ wvF,
    float* __restrict__ S){
  constexpr int Dt = D/16;
  int p0 = blockIdx.x*64;
  int b = blockIdx.z;
  int tid = threadIdx.x;
  int lane = tid & 63, w = tid >> 6;
  int d0 = blockIdx.y*64 + (w<<4);
  int dTile = blockIdx.y*4 + w;
  __shared__ __align__(16) ushort sX[64*64];
  for(int i=tid;i<512;i+=TPB){
    int row=i>>3, c8=(i&7)<<3;
    uint4 v = *(const uint4*)&XT[((size_t)b*NPa + p0 + row)*64 + c8];
    *(uint4*)&sX[row*64 + (c8 ^ ((row&7)<<3))] = v;
  }
  __syncthreads();
  int r15 = lane & 15, hi = lane >> 4;
  bf16x8 bf[4][2];
  #pragma unroll
  for(int pt=0;pt<4;pt++){
    int row = pt*16 + r15;
    int sw = (row&7)<<3;
    int cu0 = hi*8;
    bf[pt][0] = *(const bf16x8*)&sX[row*64 + (cu0 ^ sw)];
    bf[pt][1] = *(const bf16x8*)&sX[row*64 + ((cu0+32) ^ sw)];
  }
  f32x4 acc[4];
  #pragma unroll
  for(int pt=0;pt<4;pt++){ acc[pt][0]=0.f; acc[pt][1]=0.f; acc[pt][2]=0.f; acc[pt][3]=0.f; }
  const ushort* wqp = wqF + ((size_t)dTile*2)*512 + lane*8;
  const ushort* wvp = wvF + ((size_t)dTile*2)*512 + lane*8;
  for(int k=0;k<Kb;k++){
    bf16x8 aq0 = *(const bf16x8*)&wqp[0];
    bf16x8 aq1 = *(const bf16x8*)&wqp[512];
    bf16x8 av0 = *(const bf16x8*)&wvp[0];
    bf16x8 av1 = *(const bf16x8*)&wvp[512];
    wqp += (size_t)Dt*2*512; wvp += (size_t)Dt*2*512;
    #pragma unroll
    for(int pt=0;pt<4;pt++){
      f32x4 q; q[0]=0.f;q[1]=0.f;q[2]=0.f;q[3]=0.f;
      f32x4 v; v[0]=0.f;v[1]=0.f;v[2]=0.f;v[3]=0.f;
      q = __builtin_amdgcn_mfma_f32_16x16x32_bf16(aq0, bf[pt][0], q, 0,0,0);
      q = __builtin_amdgcn_mfma_f32_16x16x32_bf16(aq1, bf[pt][1], q, 0,0,0);
      v = __builtin_amdgcn_mfma_f32_16x16x32_bf16(av0, bf[pt][0], v, 0,0,0);
      v = __builtin_amdgcn_mfma_f32_16x16x32_bf16(av1, bf[pt][1], v, 0,0,0);
      #pragma unroll
      for(int i=0;i<4;i++) acc[pt][i] += v[i]*sigm(q[i]);
    }
  }
  #pragma unroll
  for(int pt=0;pt<4;pt++){
    int p = p0 + pt*16 + r15;
    if(p < NP){
      #pragma unroll
      for(int i=0;i<4;i++){
        int d = d0 + hi*4 + i;
        S[((size_t)b*D + d)*NP + p] = acc[pt][i];
      }
    }
  }
}

// ---------------- adjacency aggregation via MFMA ----------------
// adjF fragment order: F[(k2t*7 + ks)*512 + lane*8]
template<int RELU>
__global__ __launch_bounds__(TPB) void k_agg_mfma(const ushort* __restrict__ ST, const ushort* __restrict__ adjF,
                                                  const float* __restrict__ bias, float* __restrict__ Out, int D){
  int d = blockIdx.x, b = blockIdx.y;
  int bd = b*D + d;
  constexpr int SST = 232;
  __shared__ __align__(16) ushort sB[64*SST];
  int tid = threadIdx.x;
  for(int i=tid; i<12*SST; i+=TPB) sB[52*SST + i] = 0;
  const ushort* STp = ST + (size_t)bd*52*224;
  for(int i=tid; i<1456; i+=TPB){
    int l = i/28, n8 = (i%28)*8;
    *(uint4*)&sB[l*SST + n8] = *(const uint4*)&STp[(size_t)l*224 + n8];
  }
  __syncthreads();
  int lane = tid & 63, w = tid >> 6;
  int r15 = lane & 15, hi = lane >> 4;
  float bb = bias[d];
  float* Op = Out + (size_t)bd*NP;
  for(int k2t = w; k2t < 13; k2t += 4){
    f32x4 acc[4];
    #pragma unroll
    for(int lt=0;lt<4;lt++){ acc[lt][0]=0;acc[lt][1]=0;acc[lt][2]=0;acc[lt][3]=0; }
    #pragma unroll
    for(int ks=0; ks<7; ks++){
      bf16x8 a = *(const bf16x8*)&adjF[((size_t)(k2t*7 + ks))*512 + lane*8];
      #pragma unroll
      for(int lt=0;lt<4;lt++){
        bf16x8 bfr = *(const bf16x8*)&sB[(lt*16+r15)*SST + ks*32 + hi*8];
        acc[lt] = __builtin_amdgcn_mfma_f32_16x16x32_bf16(a, bfr, acc[lt], 0,0,0);
      }
    }
    #pragma unroll
    for(int lt=0;lt<4;lt++){
      #pragma unroll
      for(int i2=0;i2<4;i2++){
        int k2 = k2t*16 + hi*4 + i2;
        int l  = lt*16 + r15;
        if(k2 < Nn && l < LP){
          float v = acc[lt][i2] + bb;
          if(RELU) v = fmaxf(v, 0.f);
          Op[(size_t)k2*LP + l] = v;
        }
      }
    }
  }
}

// ---------------- MLP conv (dil=1) via MFMA, per layer ----------------
// P[t][o] = sum_{ci,kt} RB[b][ci][n][t+kt] * Wmlp[o][layer*128+ci][kt], k=kt*128+ci (K=384).
// M=48 = exactly 3 t-tiles. Wave w owns o-cols {w*16..+15, +64} so GLU pair is in-register.
// MODE 0: gacc = P; MODE 1: gacc += P; MODE 2: gg = tanh(gacc+P+bm_lo)*sigm(...hi) (GLU fused).
template<int MODE>
__global__ __launch_bounds__(TPB) void k_mlpacc_mfma(const float* __restrict__ RB, const ushort* __restrict__ WF,
                                                     float* __restrict__ gacc, const float* __restrict__ bm,
                                                     float* __restrict__ gg){
  int n = blockIdx.x, b = blockIdx.y;
  constexpr int CS = 136;                       // row stride (ushorts): 16B-aligned, 2-way bank pattern
  __shared__ __align__(16) ushort sLT[52*CS];   // [l][ci] bf16
  int tid = threadIdx.x;
  for(int i=tid;i<6656;i+=TPB){
    int c = i/52, l = i%52;
    sLT[l*CS + c] = f2bf(RB[(((size_t)b*128+c)*Nn + n)*LP + l]);
  }
  __syncthreads();
  int lane = tid & 63, w = tid >> 6;
  int r15 = lane & 15, hi = lane >> 4;
  f32x4 acc0[3], acc1[3];
  #pragma unroll
  for(int tt=0;tt<3;tt++){
    acc0[tt][0]=0;acc0[tt][1]=0;acc0[tt][2]=0;acc0[tt][3]=0;
    acc1[tt][0]=0;acc1[tt][1]=0;acc1[tt][2]=0;acc1[tt][3]=0;
  }
  const ushort* wp0 = WF + ((size_t)w*12)*512 + lane*8;        // colTile = w     (o in [0,64))
  const ushort* wp1 = WF + ((size_t)(w+4)*12)*512 + lane*8;    // colTile = w+4   (o+64)
  #pragma unroll 3
  for(int ks=0; ks<12; ks++){
    int kt = ks>>2, ci0 = (ks&3)*32 + hi*8;     // 32|128 so kt constant within a k-step
    bf16x8 bw0 = *(const bf16x8*)&wp0[(size_t)ks*512];
    bf16x8 bw1 = *(const bf16x8*)&wp1[(size_t)ks*512];
    #pragma unroll
    for(int tt=0;tt<3;tt++){
      bf16x8 ax = *(const bf16x8*)&sLT[(tt*16 + r15 + kt)*CS + ci0];
      acc0[tt] = __builtin_amdgcn_mfma_f32_16x16x32_bf16(ax, bw0, acc0[tt], 0,0,0);
      acc1[tt] = __builtin_amdgcn_mfma_f32_16x16x32_bf16(ax, bw1, acc1[tt], 0,0,0);
    }
  }
  int o = w*16 + r15;
  if(MODE < 2){
    float* gp = gacc + ((size_t)b*Nn + n)*48*128;
    #pragma unroll
    for(int tt=0;tt<3;tt++){
      #pragma unroll
      for(int i2=0;i2<4;i2++){
        int tq = tt*16 + hi*4 + i2;
        size_t a0 = (size_t)tq*128 + o;
        if(MODE==0){ gp[a0] = acc0[tt][i2]; gp[a0+64] = acc1[tt][i2]; }
        else       { gp[a0] += acc0[tt][i2]; gp[a0+64] += acc1[tt][i2]; }
      }
    }
  } else {
    const float* gp = gacc + ((size_t)b*Nn + n)*48*128;
    float b0 = bm[o], b1 = bm[o+64];
    float* ggp = gg + (((size_t)b*Cc + o)*Nn + n)*(size_t)Tout;
    #pragma unroll
    for(int tt=0;tt<3;tt++){
      #pragma unroll
      for(int i2=0;i2<4;i2++){
        int tq = tt*16 + hi*4 + i2;
        size_t a0 = (size_t)tq*128 + o;
        float a  = gp[a0]    + acc0[tt][i2] + b0;
        float g2 = gp[a0+64] + acc1[tt][i2] + b1;
        ggp[tq] = tanhf(a)*sigm(g2);
      }
    }
  }
}

// ---------------- patch scramble + emb ----------------
__global__ __launch_bounds__(TPB) void k_xe(const float* __restrict__ gg, const float* __restrict__ emb, float* __restrict__ xe){
  size_t i = (size_t)blockIdx.x*TPB + threadIdx.x;
  if(i >= (size_t)Bx*1271808) return;
  int b = (int)(i / 1271808);
  int off = (int)(i % 1271808);
  int c = off / 19872; int r = off % 19872;
  int n = r / 96; int r2 = r % 96;
  int p = r2 >> 3; int j = r2 & 7;
  int t = p*4 + j;
  float v = 0.f;
  if(t < Tout) v = gg[(((size_t)b*Cc+c)*Nn + n)*Tout + t];
  int e = off & 511; int p2 = (off >> 9) % 12;
  xe[i] = v + emb[(size_t)p2*Ee + e];
}

// ---------------- per-row LN helper (rows of 512, stride SRDF, in LDS) ----------------
__device__ __forceinline__ void ln_rows(float* buf, const float* __restrict__ g, const float* __restrict__ be, int tid){
  int lane = tid & 63, wv = tid >> 6;
  for(int r = wv; r < 12; r += 4){
    float s=0.f, s2=0.f;
    #pragma unroll
    for(int j=0;j<8;j++){ float v = buf[r*SRDF + j*64 + lane]; s+=v; s2+=v*v; }
    #pragma unroll
    for(int off=32; off; off>>=1){ s += __shfl_xor(s,off); s2 += __shfl_xor(s2,off); }
    float m = s*(1.f/512.f);
    float rstd = rsqrtf(fmaxf(s2*(1.f/512.f)-m*m, 0.f)+EPSF);
    #pragma unroll
    for(int j=0;j<8;j++){ int e = j*64+lane; float v = buf[r*SRDF+e];
      buf[r*SRDF+e] = (v-m)*rstd*g[e] + be[e]; }
  }
}

// ---------------- fused per-(b,n) transformer, MFMA GEMM phases ----------------
__global__ __launch_bounds__(TPB,2) void k_attn(
    const float* __restrict__ xe, const float* __restrict__ resid,
    const ushort* __restrict__ WqF, const float* __restrict__ bq,
    const ushort* __restrict__ WkF, const float* __restrict__ bk,
    const ushort* __restrict__ WvF, const float* __restrict__ bv,
    const ushort* __restrict__ WfcF, const float* __restrict__ bfc,
    const float* __restrict__ g1, const float* __restrict__ b1n,
    const float* __restrict__ g2, const float* __restrict__ b2n,
    const ushort* __restrict__ Wff1F, const float* __restrict__ bff1,
    const ushort* __restrict__ Wff2F, const float* __restrict__ bff2,
    const float* __restrict__ Wrp, const float* __restrict__ brp,
    float* __restrict__ y)
{
  int n = blockIdx.x, b = blockIdx.y;
  __shared__ __align__(16) ushort SbX[16*512];
  __shared__ __align__(16) ushort Mb[16*256];
  __shared__ __align__(16) float U0[12*SRDF];
  __shared__ __align__(16) float U1[12*SRDF];
  __shared__ __align__(16) float sS[1160];
  int tid = threadIdx.x;
  int lane = tid & 63, w = tid >> 6;
  int r15 = lane & 15, hi = lane >> 4;
  const float* __restrict__ xeg = xe + ((size_t)b*Nn + n)*6144;

  for(int i=tid;i<1024;i+=TPB){
    int r = i>>6, ch = i&63;
    ushort u[8];
    if(r<12){
      const float* s = &xeg[r*512 + ch*8];
      #pragma unroll
      for(int j=0;j<8;j++) u[j] = f2bf(s[j]);
    } else {
      #pragma unroll
      for(int j=0;j<8;j++) u[j] = 0;
    }
    *(uint4*)&SbX[r*512 + ((ch ^ (r&7))<<3)] = *(uint4*)u;
  }
  for(int i=tid;i<128;i+=TPB){
    int r = 12 + (i>>5), ch = i&31;
    uint4 z; z.x=0;z.y=0;z.z=0;z.w=0;
    *(uint4*)&Mb[r*256 + ch*8] = z;
  }
  __syncthreads();

  f32x4 vfrag[2][4];
  #pragma unroll
  for(int h2=0;h2<2;h2++){
    int head = w*2 + h2;
    bf16x8 a0, a1;
    { int ch0 = head*8 + hi, ch1 = head*8 + 4 + hi;
      a0 = *(const bf16x8*)&SbX[r15*512 + ((ch0 ^ (r15&7))<<3)];
      a1 = *(const bf16x8*)&SbX[r15*512 + ((ch1 ^ (r15&7))<<3)]; }
    #pragma unroll
    for(int nt=0;nt<4;nt++){
      int col = nt*16 + r15;
      float bb = bq[col];
      f32x4 acc; acc[0]=bb;acc[1]=bb;acc[2]=bb;acc[3]=bb;
      acc = __builtin_amdgcn_mfma_f32_16x16x32_bf16(a0, *(const bf16x8*)&WqF[(size_t)(nt*2+0)*512 + lane*8], acc, 0,0,0);
      acc = __builtin_amdgcn_mfma_f32_16x16x32_bf16(a1, *(const bf16x8*)&WqF[(size_t)(nt*2+1)*512 + lane*8], acc, 0,0,0);
      #pragma unroll
      for(int i2=0;i2<4;i2++){ int p = hi*4+i2; if(p<12) U0[p*SRDF + head*64 + col] = acc[i2]; }
    }
    #pragma unroll
    for(int nt=0;nt<4;nt++){
      int col = nt*16 + r15;
      float bb = bk[col];
      f32x4 acc; acc[0]=bb;acc[1]=bb;acc[2]=bb;acc[3]=bb;
      acc = __builtin_amdgcn_mfma_f32_16x16x32_bf16(a0, *(const bf16x8*)&WkF[(size_t)(nt*2+0)*512 + lane*8], acc, 0,0,0);
      acc = __builtin_amdgcn_mfma_f32_16x16x32_bf16(a1, *(const bf16x8*)&WkF[(size_t)(nt*2+1)*512 + lane*8], acc, 0,0,0);
      #pragma unroll
      for(int i2=0;i2<4;i2++){ int p = hi*4+i2; if(p<12) U1[p*SRDF + head*64 + col] = acc[i2]; }
    }
    #pragma unroll
    for(int nt=0;nt<4;nt++){
      int col = nt*16 + r15;
      float bb = bv[col];
      f32x4 acc; acc[0]=bb;acc[1]=bb;acc[2]=bb;acc[3]=bb;
      acc = __builtin_amdgcn_mfma_f32_16x16x32_bf16(a0, *(const bf16x8*)&WvF[(size_t)(nt*2+0)*512 + lane*8], acc, 0,0,0);
      acc = __builtin_amdgcn_mfma_f32_16x16x32_bf16(a1, *(const bf16x8*)&WvF[(size_t)(nt*2+1)*512 + lane*8], acc, 0,0,0);
      vfrag[h2][nt] = acc;
    }
  }
  __syncthreads();

  const float scale = 0.04419417382415922f;   // 1/sqrt(512)
  for(int i=tid;i<1152;i+=TPB){
    int q = i%12, kh = i/12; int h2 = kh&7, k2 = kh>>3;
    const float* qp = &U0[q*SRDF + h2*64];
    const float* kp = &U1[k2*SRDF + h2*64];
    float s=0.f;
    #pragma unroll
    for(int d4=0; d4<16; d4++){
      float4 a4 = *(const float4*)&qp[d4*4];
      float4 b4 = *(const float4*)&kp[d4*4];
      s += a4.x*b4.x + a4.y*b4.y + a4.z*b4.z + a4.w*b4.w;
    }
    sS[i] = s*scale;
  }
  __syncthreads();
  #pragma unroll
  for(int h2=0;h2<2;h2++){
    int head = w*2 + h2;
    #pragma unroll
    for(int nt=0;nt<4;nt++){
      int col = nt*16 + r15;
      #pragma unroll
      for(int i2=0;i2<4;i2++){ int p = hi*4+i2; if(p<12) U0[p*SRDF + head*64 + col] = vfrag[h2][nt][i2]; }
    }
  }
  if(tid<96){
    float mx=-1e30f;
    for(int q=0;q<12;q++) mx = fmaxf(mx, sS[tid*12+q]);
    float sm=0.f;
    for(int q=0;q<12;q++){ float e = __expf(sS[tid*12+q]-mx); sS[tid*12+q]=e; sm+=e; }
    float inv = 1.f/sm;
    for(int q=0;q<12;q++) sS[tid*12+q] *= inv;
  }
  __syncthreads();

  for(int i=tid;i<6144;i+=TPB){
    int q=i>>9, h2=(i>>6)&7, d=i&63;
    float s=0.f;
    #pragma unroll
    for(int k2=0;k2<12;k2++) s += sS[(k2*8+h2)*12+q]*U0[k2*SRDF+h2*64+d];
    int kk = i & 511;
    SbX[q*512 + (((kk>>3) ^ (q&7))<<3) + (kk&7)] = f2bf(s);
  }
  __syncthreads();

  {
    f32x4 acc[8];
    #pragma unroll
    for(int nt=0;nt<8;nt++){ float bb = bfc[(w*8+nt)*16 + r15]; acc[nt][0]=bb;acc[nt][1]=bb;acc[nt][2]=bb;acc[nt][3]=bb; }
    for(int ks=0;ks<16;ks++){
      int ch = ks*4 + hi;
      bf16x8 a = *(const bf16x8*)&SbX[r15*512 + ((ch ^ (r15&7))<<3)];
      #pragma unroll
      for(int nt=0;nt<8;nt++){
        acc[nt] = __builtin_amdgcn_mfma_f32_16x16x32_bf16(a, *(const bf16x8*)&WfcF[(size_t)((w*8+nt)*16 + ks)*512 + lane*8], acc[nt], 0,0,0);
      }
    }
    #pragma unroll
    for(int nt=0;nt<8;nt++){
      int col = (w*8+nt)*16 + r15;
      #pragma unroll
      for(int i2=0;i2<4;i2++){ int p = hi*4+i2; if(p<12) U1[p*SRDF + col] = acc[nt][i2] + xeg[p*512 + col]; }
    }
  }
  __syncthreads();
  ln_rows(U1, g1, b1n, tid);     // M in U1
  __syncthreads();

  for(int i=tid;i<6144;i+=TPB){
    int r=i>>9, kk=i&511;
    SbX[r*512 + (((kk>>3) ^ (r&7))<<3) + (kk&7)] = f2bf(U1[r*SRDF + kk]);
  }
  __syncthreads();

  {
    f32x4 acc[4];
    #pragma unroll
    for(int nt=0;nt<4;nt++){ float bb = bff1[(w*4+nt)*16 + r15]; acc[nt][0]=bb;acc[nt][1]=bb;acc[nt][2]=bb;acc[nt][3]=bb; }
    for(int ks=0;ks<16;ks++){
      int ch = ks*4 + hi;
      bf16x8 a = *(const bf16x8*)&SbX[r15*512 + ((ch ^ (r15&7))<<3)];
      #pragma unroll
      for(int nt=0;nt<4;nt++){
        acc[nt] = __builtin_amdgcn_mfma_f32_16x16x32_bf16(a, *(const bf16x8*)&Wff1F[(size_t)((w*4+nt)*16 + ks)*512 + lane*8], acc[nt], 0,0,0);
      }
    }
    #pragma unroll
    for(int nt=0;nt<4;nt++){
      int u = (w*4+nt)*16 + r15;
      #pragma unroll
      for(int i2=0;i2<4;i2++){
        int p = hi*4+i2;
        if(p<12) Mb[p*256 + (((u>>3) ^ (p&7))<<3) + (u&7)] = f2bf(fmaxf(acc[nt][i2], 0.f));
      }
    }
  }
  __syncthreads();

  {
    f32x4 acc[8];
    #pragma unroll
    for(int nt=0;nt<8;nt++){ float bb = bff2[(w*8+nt)*16 + r15]; acc[nt][0]=bb;acc[nt][1]=bb;acc[nt][2]=bb;acc[nt][3]=bb; }
    for(int ks=0;ks<8;ks++){
      int ch = ks*4 + hi;
      bf16x8 a = *(const bf16x8*)&Mb[r15*256 + ((ch ^ (r15&7))<<3)];
      #pragma unroll
      for(int nt=0;nt<8;nt++){
        acc[nt] = __builtin_amdgcn_mfma_f32_16x16x32_bf16(a, *(const bf16x8*)&Wff2F[(size_t)((w*8+nt)*8 + ks)*512 + lane*8], acc[nt], 0,0,0);
      }
    }
    #pragma unroll
    for(int nt=0;nt<8;nt++){
      int col = (w*8+nt)*16 + r15;
      #pragma unroll
      for(int i2=0;i2<4;i2++){ int p = hi*4+i2; if(p<12) U0[p*SRDF + col] = acc[nt][i2] + U1[p*SRDF + col]; }
    }
  }
  __syncthreads();
  ln_rows(U0, g2, b2n, tid);     // U in U0
  __syncthreads();

  for(int i=tid;i<6144;i+=TPB){
    int r=i>>9, c=i&511;
    U1[r*SRDF+c] = U0[r*SRDF+c] + U1[r*SRDF+c] + xeg[r*512+c];
  }
  __syncthreads();
  for(int i=tid;i<4608;i+=TPB) U0[i] = Wrp[i];
  __syncthreads();
  #pragma unroll
  for(int j=0;j<3;j++){
    int i4 = tid + j*TPB;
    int c = i4/12, tq = i4%12; int t0 = tq*4;
    float4 acc = *(const float4*)&brp[t0];
    for(int t96=0;t96<96;t96++){
      int f = c*96 + t96;
      float a = U1[(f>>9)*SRDF + (f&511)];
      float4 w4 = *(const float4*)&U0[t96*48 + t0];
      FMA4(acc, a, w4);
    }
    size_t rb = (((size_t)b*Cc+c)*Nn + n)*Tin + 6 + t0;
    acc.x += resid[rb+0]; acc.y += resid[rb+1]; acc.z += resid[rb+2]; acc.w += resid[rb+3];
    *(float4*)&y[(((size_t)b*Cc+c)*Nn + n)*Tout + t0] = acc;
  }
}

// ---------------- batchnorm ----------------
__global__ __launch_bounds__(TPB) void k_bnstats(const float* __restrict__ y, float* __restrict__ stats){
  int c = blockIdx.x; int tid = threadIdx.x;
  float s=0.f,s2=0.f;
  const int per = Nn*Tout;   // 9936
  for(int idx=tid; idx<Bx*per; idx+=TPB){
    int b = idx/per, r = idx%per;
    float v = y[((size_t)b*Cc+c)*per + r];
    s+=v; s2+=v*v;
  }
  __shared__ float rs[TPB], rs2[TPB];
  rs[tid]=s; rs2[tid]=s2; __syncthreads();
  for(int off=TPB/2; off; off>>=1){ if(tid<off){ rs[tid]+=rs[tid+off]; rs2[tid]+=rs2[tid+off]; } __syncthreads(); }
  if(tid==0){
    float m = rs[0]/(float)(Bx*per);
    float var = rs2[0]/(float)(Bx*per) - m*m;
    stats[c]=m; stats[64+c]=rsqrtf(fmaxf(var,0.f)+EPSF);
  }
}
__global__ __launch_bounds__(TPB) void k_bnout(const float* __restrict__ y, const float* __restrict__ stats,
                                               const float* __restrict__ gbn, const float* __restrict__ bbn,
                                               float* __restrict__ out){
  size_t i = (size_t)blockIdx.x*TPB + threadIdx.x;
  if(i >= (size_t)Bx*Cc*Nn*Tout) return;
  int c = (int)((i/(Nn*Tout))%Cc);
  out[i] = (y[i]-stats[c])*stats[64+c]*gbn[c] + bbn[c];
}

// ---------------- launch ----------------
extern "C" void kernel_launch(void* const* d_in, const int* in_sizes, int n_in,
                              void* d_out, int out_size, void* d_ws, size_t ws_size,
                              hipStream_t stream) {
  const float* x      = (const float*)d_in[0];
  const float* adj    = (const float*)d_in[1];
  const float* Wconv1 = (const float*)d_in[2];
  const float* bconv1 = (const float*)d_in[3];
  const float* gT     = (const float*)d_in[4];
  const float* bT     = (const float*)d_in[5];
  const float* gS     = (const float*)d_in[6];
  const float* bS     = (const float*)d_in[7];
  const float* Wtime  = (const float*)d_in[8];
  const float* btime  = (const float*)d_in[9];
  const float* wq1    = (const float*)d_in[10];
  const float* wv1    = (const float*)d_in[11];
  const float* bias1  = (const float*)d_in[12];
  const float* wq2    = (const float*)d_in[13];
  const float* wv2    = (const float*)d_in[14];
  const float* bias2  = (const float*)d_in[15];
  const float* Wmlp   = (const float*)d_in[16];
  const float* bmlp   = (const float*)d_in[17];
  const float* embT   = (const float*)d_in[18];
  const float* Wq     = (const float*)d_in[19];
  const float* bq     = (const float*)d_in[20];
  const float* Wk     = (const float*)d_in[21];
  const float* bk     = (const float*)d_in[22];
  const float* Wv     = (const float*)d_in[23];
  const float* bv     = (const float*)d_in[24];
  const float* Wfc    = (const float*)d_in[25];
  const float* bfc    = (const float*)d_in[26];
  const float* g1     = (const float*)d_in[27];
  const float* b1n    = (const float*)d_in[28];
  const float* g2     = (const float*)d_in[29];
  const float* b2n    = (const float*)d_in[30];
  const float* Wff1   = (const float*)d_in[31];
  const float* bff1   = (const float*)d_in[32];
  const float* Wff2   = (const float*)d_in[33];
  const float* bff2   = (const float*)d_in[34];
  const float* Wrp    = (const float*)d_in[35];
  const float* brp    = (const float*)d_in[36];
  const float* gbn    = (const float*)d_in[37];
  const float* bbn    = (const float*)d_in[38];

  float* ws = (float*)d_ws;
  float* RESID = ws + O_RESID;
  float* LNTM  = ws + O_LNTM;
  float* LNTR  = ws + O_LNTR;
  float* LNSM  = ws + O_LNSM;
  float* LNSR  = ws + O_LNSR;
  float* XCAT  = ws + O_XCAT;
  float* RA    = ws + O_XCAT;    // overlays XCAT after it is consumed
  float* RB    = ws + O_RB;
  float* H     = ws + O_H;
  float* GACC  = ws + O_GACC;
  float* GG    = ws + O_GG;
  float* Y     = ws + O_GG;      // overlays GG after xe built
  float* XE    = ws + O_XE;
  float* BNST  = ws + O_BNST;
  ushort* WTMF = (ushort*)(ws + O_WTM);
  ushort* WTB  = (ushort*)(ws + O_WTB);
  ushort* ADJT = (ushort*)(ws + O_ADJT);
  ushort* STb  = (ushort*)(ws + O_XE);   // ST scratch aliases XE region (free until k_xe)
  ushort* HT   = (ushort*)(ws + O_HT);
  ushort* WQ1B = (ushort*)(ws + O_WQ1B);
  ushort* WV1B = (ushort*)(ws + O_WV1B);
  ushort* WQ2B = (ushort*)(ws + O_WQ2B);
  ushort* WV2B = (ushort*)(ws + O_WV2B);
  ushort* RBT  = (ushort*)(ws + O_RBT);
  ushort* WQT  = (ushort*)(ws + O_WQT);
  ushort* WKT  = (ushort*)(ws + O_WKT);
  ushort* WVT  = (ushort*)(ws + O_WVT);
  ushort* WFCT = (ushort*)(ws + O_WFCT);
  ushort* WF1T = (ushort*)(ws + O_WF1T);
  ushort* WF2T = (ushort*)(ws + O_WF2T);

  k_residual<<<dim3(Nn,Bx),TPB,0,stream>>>(x, Wconv1, bconv1, RESID);
  k_lnT<<<(Bx*Cc*Nn)/TPB,TPB,0,stream>>>(RESID, LNTM, LNTR);
  k_lnS<<<(Bx*Cc*Tin)/TPB,TPB,0,stream>>>(RESID, LNSM, LNSR);
  k_xcat<<<(Bx*192*Nn*Tin)/TPB,TPB,0,stream>>>(RESID, LNTM, LNTR, LNSM, LNSR, gT,bT,gS,bS, XCAT);
  k_wtbF<<<(8*18*512+TPB-1)/TPB,TPB,0,stream>>>(Wtime, WTB);
  k_wmlpF<<<(3*8*12*512+TPB-1)/TPB,TPB,0,stream>>>(Wmlp, WTMF);
  // adj -> fragment order: K=207(n), N=207(k2), KS=7, NT=13, 3 slices of stride 207*207
  k_wfrag<<<(3*13*7*512+TPB-1)/TPB,TPB,0,stream>>>(adj, ADJT, 207, 207, 7, 13, 3*13*7*512, Nn*Nn);
  k_timeconv_mfma<<<dim3(Nn,Bx),TPB,0,stream>>>(XCAT, WTB, btime, H);

  // fragment-order weight converts (into dead XCAT tail -- must be after timeconv)
  k_wfrag<<<(24*4*2*512+TPB-1)/TPB,TPB,0,stream>>>(wq1, WQ1B, 64, 64, 2, 4, 24*4*2*512, 64*64);
  k_wfrag<<<(24*4*2*512+TPB-1)/TPB,TPB,0,stream>>>(wv1, WV1B, 64, 64, 2, 4, 24*4*2*512, 64*64);
  k_wfrag<<<(24*8*2*512+TPB-1)/TPB,TPB,0,stream>>>(wq2, WQ2B, 64, 128, 2, 8, 24*8*2*512, 64*128);
  k_wfrag<<<(24*8*2*512+TPB-1)/TPB,TPB,0,stream>>>(wv2, WV2B, 64, 128, 2, 8, 24*8*2*512, 64*128);
  k_wfrag<<<(4*2*512+TPB-1)/TPB,TPB,0,stream>>>(Wq, WQT, 64, 64, 2, 4, 4*2*512, 64*64);
  k_wfrag<<<(4*2*512+TPB-1)/TPB,TPB,0,stream>>>(Wk, WKT, 64, 64, 2, 4, 4*2*512, 64*64);
  k_wfrag<<<(4*2*512+TPB-1)/TPB,TPB,0,stream>>>(Wv, WVT, 64, 64, 2, 4, 4*2*512, 64*64);
  k_wfrag<<<(32*16*512+TPB-1)/TPB,TPB,0,stream>>>(Wfc, WFCT, 512, 512, 16, 32, 32*16*512, 512*512);
  k_wfrag<<<(16*16*512+TPB-1)/TPB,TPB,0,stream>>>(Wff1, WF1T, 512, 256, 16, 16, 16*16*512, 512*256);
  k_wfrag<<<(32*8*512+TPB-1)/TPB,TPB,0,stream>>>(Wff2, WF2T, 256, 512, 8, 32, 32*8*512, 256*512);
  k_t2bf<64><<<dim3(169,Bx),TPB,0,stream>>>(H, HT);

  for(int i=0;i<3;i++){
    k_gcs_mfma<64><<<dim3(169,1,Bx),TPB,0,stream>>>(HT, WQ1B+(size_t)i*8*4*2*512, WV1B+(size_t)i*8*4*2*512, RA);
    k_st<<<dim3(64,Bx),TPB,0,stream>>>(RA, STb, 64);
    k_agg_mfma<1><<<dim3(64,Bx),TPB,0,stream>>>(STb, ADJT+(size_t)i*13*7*512, bias1+(size_t)i*64, RB, 64);
    k_t2bf<64><<<dim3(169,Bx),TPB,0,stream>>>(RB, RBT);
    k_gcs_mfma<128><<<dim3(169,2,Bx),TPB,0,stream>>>(RBT, WQ2B+(size_t)i*8*8*2*512, WV2B+(size_t)i*8*8*2*512, RA);
    k_st<<<dim3(128,Bx),TPB,0,stream>>>(RA, STb, 128);
    k_agg_mfma<0><<<dim3(128,Bx),TPB,0,stream>>>(STb, ADJT+(size_t)i*13*7*512, bias2+(size_t)i*128, RB, 128);
    if(i==0)      k_mlpacc_mfma<0><<<dim3(Nn,Bx),TPB,0,stream>>>(RB, WTMF+(size_t)i*8*12*512, GACC, bmlp, GG);
    else if(i==1) k_mlpacc_mfma<1><<<dim3(Nn,Bx),TPB,0,stream>>>(RB, WTMF+(size_t)i*8*12*512, GACC, bmlp, GG);
    else          k_mlpacc_mfma<2><<<dim3(Nn,Bx),TPB,0,stream>>>(RB, WTMF+(size_t)i*8*12*512, GACC, bmlp, GG);
  }
  k_xe<<<(Bx*1271808)/TPB,TPB,0,stream>>>(GG, embT, XE);
  k_attn<<<dim3(Nn,Bx),TPB,0,stream>>>(XE, RESID, WQT,bq, WKT,bk, WVT,bv, WFCT,bfc,
                                       g1,b1n,g2,b2n, WF1T,bff1, WF2T,bff2, Wrp,brp, Y);
  k_bnstats<<<64,TPB,0,stream>>>(Y, BNST);
  k_bnout<<<(Bx*Cc*Nn*Tout)/TPB,TPB,0,stream>>>(Y, BNST, gbn, bbn, (float*)d_out);
}